// Round 4
// baseline (1147.857 us; speedup 1.0000x reference)
//
#include <hip/hip_runtime.h>

// ---------------- problem dims (fixed by setup_inputs) ----------------
#define B_    4
#define T_    4096
#define DD_   1024
#define N_    1024
#define K3_   3072
#define M_    16384      // B_*T_
#define CL_   16         // scan chunk length (time steps)
#define SROWS_ 2048      // stripe rows (one stripe = half a batch, aligned)
#define NSTRIPE_ (M_/SROWS_)     // 8
#define CPS_  (SROWS_/CL_)       // 128 chunks per stripe
#define MEG_  1048576

// ---------------- ws layout (float offsets), total ~47.6 MiB ----------------
// rawS (24 MiB) is aliased by the sigma phase: G0 (2M f) | hiW (1M f) | loW (1M f).
// usS (8 MiB) is aliased by the sigma phase: SbfA (2M shorts) | SbfB (2M shorts).
#define OFF_RAWS  ((size_t)0)                        // 6M f   (24 MiB)
#define OFF_USS   ((size_t)6*MEG_)                   // 2M f   (8 MiB)
#define OFF_UBF   ((size_t)8*MEG_)                   // 1M f = 2M shorts (y_hat bf16)
#define OFF_WCAT  ((size_t)9*MEG_)                   // 2M f = 4M shorts (W_in rows then Wp rows)
#define OFF_WOUTB ((size_t)11*MEG_)                  // 512K f = 1M shorts
#define OFF_AGA   (OFF_WOUTB + 524288)               // 128K f
#define OFF_AGB   (OFF_AGA + 131072)
#define OFF_PRE   (OFF_AGB + 131072)                 // (unused, kept for layout)
#define OFF_CARRY (OFF_PRE + 131072)                 // 4096 f
#define OFF_V0    (OFF_CARRY + 4096)                 // 2048 f (2 z)
#define OFF_W1    (OFF_V0 + 2048)
#define OFF_W2    (OFF_W1 + 2048)
#define OFF_TR    (OFF_W2 + 2048)                    // 16 f (unused, kept for layout)
#define OFF_SCAL  (OFF_TR + 16)                      // [0]=inv_in, [1]=inv_out
#define REQ_FLOATS (OFF_SCAL + 16)

typedef short s8v __attribute__((ext_vector_type(8)));   // 8 bf16 (4 VGPRs)
typedef float f4v __attribute__((ext_vector_type(4)));   // MFMA acc
typedef unsigned short u16x4 __attribute__((ext_vector_type(4)));  // 8B bf16 pack

typedef __attribute__((address_space(3))) unsigned int       lds_u32;
typedef const __attribute__((address_space(1))) unsigned int glb_u32;

__device__ __forceinline__ void gload_lds16(const void* g, void* l)
{
    __builtin_amdgcn_global_load_lds((glb_u32*)g, (lds_u32*)l, 16, 0, 0);
}

// fp32 -> bf16 round-to-nearest-even
__device__ __forceinline__ unsigned short f2bf(float f)
{
    unsigned u = __float_as_uint(f);
    u += 0x7FFFu + ((u >> 16) & 1u);
    return (unsigned short)(u >> 16);
}
__device__ __forceinline__ float bf2f(unsigned short h)
{
    return __uint_as_float((unsigned)h << 16);
}

// ---------------- fallback: zero a float buffer ----------------
__global__ void zero_out(float* __restrict__ y, int n)
{
    int i = blockIdx.x * 256 + threadIdx.x;
    if (i < n) y[i] = 0.f;
}

// ------- one-time weight conversion to bf16 + split-bf16 hi/lo planes -------
// Wcat = bf16(W_in | Wp), Woutb = bf16(W_out);
// hi/lo: [z=0] W_in, [z=1] W_out split as w = hi + lo (residual ~2^-18 rel).
__global__ void cvt_weights(const float* __restrict__ Win, const float* __restrict__ Wp,
                            const float* __restrict__ Wout,
                            unsigned short* __restrict__ Wcat,
                            unsigned short* __restrict__ Woutb,
                            unsigned short* __restrict__ hi,
                            unsigned short* __restrict__ lo)
{
    int i = blockIdx.x * 256 + threadIdx.x;        // 0 .. 5M-1
    if (i < 1048576)       Wcat[i] = f2bf(Win[i]);
    else if (i < 4194304)  Wcat[i] = f2bf(Wp[i - 1048576]);
    else if (i < 5242880)  Woutb[i - 4194304] = f2bf(Wout[i - 4194304]);
    if (i < 2097152) {
        float wv = (i < MEG_) ? Win[i] : Wout[i - MEG_];
        unsigned short h = f2bf(wv);
        hi[i] = h;
        lo[i] = f2bf(wv - bf2f(h));                // w - hi exact in fp32
    }
}

// =====================================================================
// Split-bf16 MFMA gram: C[z] = W[z] W[z]^T computed as
//   hi.hi^T + hi.lo^T + lo.hi^T  (lo.lo dropped, ~2^-36 of diag).
// 64x64 tile (512 blocks -> occupancy), BK=32, 4 waves 2x2 x (2x2
// mfma_16x16x32). Writes fp32 C (Rayleigh quotient) AND bf16 Cb (chain seed).
// =====================================================================
__global__ __launch_bounds__(256, 4) void gram_bf16x2(
    const unsigned short* __restrict__ hi, const unsigned short* __restrict__ lo,
    float* __restrict__ C, unsigned short* __restrict__ Cb)
{
    __shared__ __align__(16) unsigned short Ah[64 * 32];
    __shared__ __align__(16) unsigned short Al[64 * 32];
    __shared__ __align__(16) unsigned short Bh[64 * 32];
    __shared__ __align__(16) unsigned short Bl[64 * 32];
    const int tid = threadIdx.x;
    const int z   = blockIdx.z;
    const int m0  = blockIdx.y * 64;
    const int n0  = blockIdx.x * 64;

    const unsigned short* hz = hi + (size_t)z * MEG_;
    const unsigned short* lz = lo + (size_t)z * MEG_;

    const int lane = tid & 63;
    const int w    = tid >> 6;
    const int wm   = (w >> 1) * 32;
    const int wn   = (w & 1) * 32;
    const int lrow = lane & 15;
    const int quad = lane >> 4;
    const int srow = lane >> 2;          // 16 rows per wave-load
    const int scol = (lane & 3) * 8;     // 4 x 16B granules per row

    const size_t arow = (size_t)(m0 + w*16 + srow) * 1024 + scol;
    const size_t brow = (size_t)(n0 + w*16 + srow) * 1024 + scol;
    unsigned short* dA = &Ah[(w*16) * 32];
    unsigned short* eA = &Al[(w*16) * 32];
    unsigned short* dB = &Bh[(w*16) * 32];
    unsigned short* eB = &Bl[(w*16) * 32];

    f4v acc[2][2];
    #pragma unroll
    for (int i = 0; i < 2; ++i)
      #pragma unroll
      for (int j = 0; j < 2; ++j) acc[i][j] = (f4v){0.f, 0.f, 0.f, 0.f};

    for (int kt = 0; kt < 1024; kt += 32) {
        __syncthreads();
        gload_lds16(hz + arow + kt, dA);
        gload_lds16(lz + arow + kt, eA);
        gload_lds16(hz + brow + kt, dB);
        gload_lds16(lz + brow + kt, eB);
        __syncthreads();

        s8v ah[2], al[2], bh[2], bl[2];
        #pragma unroll
        for (int i = 0; i < 2; ++i) {
            ah[i] = *(const s8v*)&Ah[(wm + i*16 + lrow) * 32 + quad * 8];
            al[i] = *(const s8v*)&Al[(wm + i*16 + lrow) * 32 + quad * 8];
        }
        #pragma unroll
        for (int j = 0; j < 2; ++j) {
            bh[j] = *(const s8v*)&Bh[(wn + j*16 + lrow) * 32 + quad * 8];
            bl[j] = *(const s8v*)&Bl[(wn + j*16 + lrow) * 32 + quad * 8];
        }
        #pragma unroll
        for (int i = 0; i < 2; ++i)
          #pragma unroll
          for (int j = 0; j < 2; ++j) {
              acc[i][j] = __builtin_amdgcn_mfma_f32_16x16x32_bf16(ah[i], bh[j], acc[i][j], 0, 0, 0);
              acc[i][j] = __builtin_amdgcn_mfma_f32_16x16x32_bf16(ah[i], bl[j], acc[i][j], 0, 0, 0);
              acc[i][j] = __builtin_amdgcn_mfma_f32_16x16x32_bf16(al[i], bh[j], acc[i][j], 0, 0, 0);
          }
    }

    float*          Cz  = C  + (size_t)z * MEG_;
    unsigned short* Cbz = Cb + (size_t)z * MEG_;
    #pragma unroll
    for (int i = 0; i < 2; ++i)
      #pragma unroll
      for (int j = 0; j < 2; ++j) {
        const int col = n0 + wn + j * 16 + lrow;
        #pragma unroll
        for (int r = 0; r < 4; ++r) {
            const int row = m0 + wm + i * 16 + quad * 4 + r;
            float v = acc[i][j][r];
            Cz [(size_t)row * 1024 + col] = v;
            Cbz[(size_t)row * 1024 + col] = f2bf(v);
        }
    }
}

// =====================================================================
// bf16 MFMA NT GEMM, 64x64 tile (high grid count for 1024-class shapes),
// BK=32, 4 waves 2x2, each 32x32 via 2x2 mfma_16x16x32. z-batched.
// OBF: bf16 output (zsC still in floats of the underlying buffer).
// mode: 0 plain, 1 scale by sptr[0].
// =====================================================================
template<bool OBF>
__global__ __launch_bounds__(256, 4) void gemm64_t(
    const unsigned short* __restrict__ A, const unsigned short* __restrict__ B,
    float* __restrict__ C, int K, int ldc,
    long zsA, long zsB, long zsC,
    const float* __restrict__ sptr, int mode)
{
    __shared__ __align__(16) unsigned short As[64 * 32];
    __shared__ __align__(16) unsigned short Bs[64 * 32];
    const int tid = threadIdx.x;
    const int z   = blockIdx.z;
    const int m0  = blockIdx.y * 64;
    const int n0  = blockIdx.x * 64;

    const unsigned short* Az = A + (size_t)z * zsA;
    const unsigned short* Bz = B + (size_t)z * zsB;

    const int lane = tid & 63;
    const int w    = tid >> 6;
    const int wm   = (w >> 1) * 32;
    const int wn   = (w & 1) * 32;
    const int lrow = lane & 15;
    const int quad = lane >> 4;
    const int srow = lane >> 2;
    const int scol = (lane & 3) * 8;

    const unsigned short* Agl = Az + (size_t)(m0 + w*16 + srow) * K + scol;
    const unsigned short* Bgl = Bz + (size_t)(n0 + w*16 + srow) * K + scol;
    unsigned short* lA = &As[(w*16) * 32];
    unsigned short* lB = &Bs[(w*16) * 32];

    f4v acc[2][2];
    #pragma unroll
    for (int i = 0; i < 2; ++i)
      #pragma unroll
      for (int j = 0; j < 2; ++j) acc[i][j] = (f4v){0.f, 0.f, 0.f, 0.f};

    for (int kt = 0; kt < K; kt += 32) {
        __syncthreads();
        gload_lds16(Agl + kt, lA);
        gload_lds16(Bgl + kt, lB);
        __syncthreads();

        s8v af[2], bf[2];
        #pragma unroll
        for (int i = 0; i < 2; ++i)
            af[i] = *(const s8v*)&As[(wm + i*16 + lrow) * 32 + quad * 8];
        #pragma unroll
        for (int j = 0; j < 2; ++j)
            bf[j] = *(const s8v*)&Bs[(wn + j*16 + lrow) * 32 + quad * 8];
        #pragma unroll
        for (int i = 0; i < 2; ++i)
          #pragma unroll
          for (int j = 0; j < 2; ++j)
              acc[i][j] = __builtin_amdgcn_mfma_f32_16x16x32_bf16(af[i], bf[j], acc[i][j], 0, 0, 0);
    }

    float sc = (mode == 1) ? sptr[0] : 1.0f;
    float* Cp = C + (size_t)z * zsC;

    // C/D layout: col = lane&15, row = quad*4 + reg  [m89-verified]
    #pragma unroll
    for (int i = 0; i < 2; ++i)
      #pragma unroll
      for (int j = 0; j < 2; ++j) {
        const int col = n0 + wn + j * 16 + lrow;
        #pragma unroll
        for (int r = 0; r < 4; ++r) {
            const int row = m0 + wm + i * 16 + quad * 4 + r;
            if (OBF)
                ((unsigned short*)Cp)[(size_t)row * ldc + col] = f2bf(acc[i][j][r] * sc);
            else
                Cp[(size_t)row * ldc + col] = acc[i][j][r] * sc;
        }
    }
}

// =====================================================================
// Projection GEMM with fused fp32->bf16 A conversion (replaces cvt_u +
// gemm_bf16). A is fp32 [M][K]; per K-step each wave loads its 32 rows
// as float4s, converts (RNE, identical to cvt_u), ds_write_b64 to LDS.
// B staged bf16 via global_load_lds. 128x128 tile, BK=32, 4 waves 2x2,
// each 64x64 via 4x4 mfma_16x16x32. Dual-output column split at nsplit.
// =====================================================================
__global__ __launch_bounds__(256, 2) void gemm_proj(
    const float* __restrict__ A,
    const unsigned short* __restrict__ B0, const unsigned short* __restrict__ B1,
    float* __restrict__ C0, float* __restrict__ C1,
    int K, int ldc0, int ldc1, int nsplit)
{
    __shared__ __align__(16) unsigned short As[128 * 32];
    __shared__ __align__(16) unsigned short Bs[128 * 32];
    const int tid = threadIdx.x;
    const int m0  = blockIdx.y * 128;
    const int n0g = blockIdx.x * 128;

    const unsigned short* Bsrc; float* Cp; int ldc; int c0;
    if (n0g < nsplit) {
        Bsrc = B0 + (size_t)n0g * K;
        Cp = C0; ldc = ldc0; c0 = n0g;
    } else {
        Bsrc = B1 + (size_t)(n0g - nsplit) * K;
        Cp = C1; ldc = ldc1; c0 = n0g - nsplit;
    }

    const int lane = tid & 63;
    const int w    = tid >> 6;          // wave 0..3
    const int wm   = (w >> 1) * 64;
    const int wn   = (w & 1) * 64;
    const int lrow = lane & 15;
    const int quad = lane >> 4;

    // B staging (bf16, async): wave w covers tile rows [w*32, w*32+32)
    const int srow = (lane >> 2);
    const int scol = (lane & 3) * 8;
    const unsigned short* Bgl0 = Bsrc + (size_t)(w*32 + srow) * K + scol;
    const unsigned short* Bgl1 = Bgl0 + (size_t)16 * K;
    unsigned short* lB0 = &Bs[(w*32     ) * 32];
    unsigned short* lB1 = &Bs[(w*32 + 16) * 32];

    // A staging (fp32 -> bf16 reg convert): wave w covers rows [w*32,+32).
    // lane -> row w*32 + q*8 + (lane>>3), cols (lane&7)*4 .. +3
    const int ar = (lane >> 3);          // 0..7
    const int ac = (lane & 7) * 4;       // float col granule
    const float* Ag = A + (size_t)(m0 + w*32 + ar) * K + ac;
    unsigned short* aw = &As[(w*32 + ar) * 32 + ac];

    float4 av[4];
    #pragma unroll
    for (int q = 0; q < 4; ++q)
        av[q] = *(const float4*)(Ag + (size_t)(q * 8) * K);

    f4v acc[4][4];
    #pragma unroll
    for (int i = 0; i < 4; ++i)
      #pragma unroll
      for (int j = 0; j < 4; ++j) acc[i][j] = (f4v){0.f, 0.f, 0.f, 0.f};

    for (int kt = 0; kt < K; kt += 32) {
        __syncthreads();                       // prev iter's LDS reads done
        gload_lds16(Bgl0 + kt, lB0);
        gload_lds16(Bgl1 + kt, lB1);
        #pragma unroll
        for (int q = 0; q < 4; ++q) {
            u16x4 p;
            p.x = f2bf(av[q].x); p.y = f2bf(av[q].y);
            p.z = f2bf(av[q].z); p.w = f2bf(av[q].w);
            *(u16x4*)(aw + (size_t)(q * 8) * 32) = p;
        }
        __syncthreads();                       // drains vm + lgkm
        if (kt + 32 < K) {                     // prefetch next A under MFMA
            #pragma unroll
            for (int q = 0; q < 4; ++q)
                av[q] = *(const float4*)(Ag + (size_t)(q * 8) * K + kt + 32);
        }

        s8v af[4], bf[4];
        #pragma unroll
        for (int i = 0; i < 4; ++i)
            af[i] = *(const s8v*)&As[(wm + i*16 + lrow) * 32 + quad * 8];
        #pragma unroll
        for (int j = 0; j < 4; ++j)
            bf[j] = *(const s8v*)&Bs[(wn + j*16 + lrow) * 32 + quad * 8];
        #pragma unroll
        for (int i = 0; i < 4; ++i)
          #pragma unroll
          for (int j = 0; j < 4; ++j)
              acc[i][j] = __builtin_amdgcn_mfma_f32_16x16x32_bf16(af[i], bf[j], acc[i][j], 0, 0, 0);
    }

    // C/D layout: col = lane&15, row = quad*4 + reg  [m89-verified]
    #pragma unroll
    for (int i = 0; i < 4; ++i)
      #pragma unroll
      for (int j = 0; j < 4; ++j) {
        const int col = c0 + wn + j * 16 + lrow;
        #pragma unroll
        for (int r = 0; r < 4; ++r) {
            const int row = m0 + wm + i * 16 + quad * 4 + r;
            Cp[(size_t)row * ldc + col] = acc[i][j][r];
        }
    }
}

// ---- pick column with max diagonal (dominant-eigvec seed), z=blockIdx.x ----
// Input is the bf16 S^64 from the squaring chain.
__global__ void pick_col(const unsigned short* __restrict__ Pall, float* __restrict__ vall)
{
    const unsigned short* P = Pall + (size_t)blockIdx.x * MEG_;
    float* v = vall + blockIdx.x * N_;
    __shared__ float sval[256];
    __shared__ int   sidx[256];
    __shared__ int   jstar;
    const int tid = threadIdx.x;
    float best = -1.f; int bidx = 0;
    for (int i = tid; i < N_; i += 256) {
        float d = bf2f(P[(size_t)i * (N_ + 1)]);
        if (d > best) { best = d; bidx = i; }
    }
    sval[tid] = best; sidx[tid] = bidx; __syncthreads();
    for (int off = 128; off > 0; off >>= 1) {
        if (tid < off && sval[tid + off] > sval[tid]) {
            sval[tid] = sval[tid + off]; sidx[tid] = sidx[tid + off];
        }
        __syncthreads();
    }
    if (tid == 0) jstar = sidx[0];
    __syncthreads();
    const int j = jstar;   // symmetric: row j == column j
    for (int i = tid; i < N_; i += 256) v[i] = bf2f(P[(size_t)j * N_ + i]);
}

// ---------------- w = G[z] * v[z] (one wave per row), z=blockIdx.y ----------
__global__ __launch_bounds__(256) void matvec_z(
    const float* __restrict__ Gall, const float* __restrict__ vall,
    float* __restrict__ wall)
{
    const int z = blockIdx.y;
    const float* G = Gall + (size_t)z * MEG_;
    const float* v = vall + z * N_;
    const int row  = blockIdx.x * 4 + (threadIdx.x >> 6);
    const int lane = threadIdx.x & 63;
    const float* g = G + (size_t)row * N_;
    float s = 0.f;
    for (int j = lane; j < N_; j += 64) s += g[j] * v[j];
    #pragma unroll
    for (int off = 32; off > 0; off >>= 1) s += __shfl_down(s, off, 64);
    if (lane == 0) wall[z * N_ + row] = s;
}

// ------- Rayleigh quotient -> inv_scale[z] = 1/max(sigma,1), z=blockIdx.x ----
__global__ void rq_scale(const float* __restrict__ w1a, const float* __restrict__ w2a,
                         float* __restrict__ slot)
{
    const int z = blockIdx.x;
    const float* w1 = w1a + z * N_;
    const float* w2 = w2a + z * N_;
    __shared__ float r11[256];
    __shared__ float r12[256];
    const int tid = threadIdx.x;
    float d11 = 0.f, d12 = 0.f;
    for (int i = tid; i < N_; i += 256) {
        float a = w1[i], b = w2[i];
        d11 = fmaf(a, a, d11);
        d12 = fmaf(a, b, d12);
    }
    r11[tid] = d11; r12[tid] = d12; __syncthreads();
    for (int off = 128; off > 0; off >>= 1) {
        if (tid < off) { r11[tid] += r11[tid + off]; r12[tid] += r12[tid + off]; }
        __syncthreads();
    }
    if (tid == 0) {
        float lam = r12[0] / fmaxf(r11[0], 1e-30f);
        float sig = sqrtf(fmaxf(lam, 0.f));
        slot[z] = 1.0f / fmaxf(sig, 1.0f);
    }
}

// ---------------- fast elementwise math (hw v_exp/v_log) ----------------
__device__ __forceinline__ float fast_sp(float x)   // softplus
{
    return fmaxf(x, 0.f) + __logf(1.0f + __expf(-fabsf(x)));
}
__device__ __forceinline__ float fast_tanh(float x)
{
    float e = __expf(2.0f * fabsf(x));
    float t = 1.0f - 2.0f / (e + 1.0f);
    return copysignf(t, x);
}

__device__ __forceinline__ void abc_math(
    float dr, float br, float cr, float uval,
    float alpha, float db, float sgain,
    float* pa, float* pbu, float* pc)
{
    float delta = fast_sp(dr + db);
    float a = fminf(__expf(-delta * alpha), 1.0f - 1e-4f);
    float b = fast_tanh(br);
    float c = fast_tanh(cr);
    float p = fmaf(a, a, c * c);
    float r = b * b;
    float q = a * b;
    float pr = p - r;
    float disc = fmaf(pr, pr, 4.0f * q * q);
    float lam = 0.5f * (p + r + sqrtf(disc + 1e-12f));
    float sig = sqrtf(lam + 1e-12f);
    float inv = 1.0f / fmaxf(sig, 1.0f);
    a *= inv; b *= inv; c *= inv;
    *pa = a; *pc = c; *pbu = b * (sgain * uval);
}

// --------- scan phase 1 (per stripe): per-chunk composite (CL=16) ---------
__global__ __launch_bounds__(256) void scan_phase1(
    const float* __restrict__ rawS, const float* __restrict__ usS,
    const float* __restrict__ bp, const float* __restrict__ dbias,
    const float* __restrict__ alog, const float* __restrict__ lgam,
    const float* __restrict__ inv_sin,
    float* __restrict__ agg_a, float* __restrict__ agg_b)
{
    const int gid = blockIdx.x * 256 + threadIdx.x;   // [0, CPS_*N_)
    const int n   = gid & (N_ - 1);
    const int cl  = gid >> 10;                        // local chunk 0..127

    const float alpha = fast_sp(alog[n]);
    const float db    = dbias[n];
    const float bpd   = bp[n];
    const float bpb   = bp[N_ + n];
    const float bpc   = bp[2*N_ + n];
    const float sgain = __expf(lgam[0]) * inv_sin[0];

    float Ap = 1.f, Bc = 0.f;
    size_t base  = (size_t)(cl * CL_) * K3_ + n;      // stripe-local
    size_t ubase = (size_t)(cl * CL_) * N_  + n;
    #pragma unroll 4
    for (int j = 0; j < CL_; ++j) {
        float dr = rawS[base]        + bpd;
        float br = rawS[base + N_]   + bpb;
        float cr = rawS[base + 2*N_] + bpc;
        float uv = usS[ubase];
        float a, bu, cv;
        abc_math(dr, br, cr, uv, alpha, db, sgain, &a, &bu, &cv);
        Bc = fmaf(a, Bc, bu);
        Ap *= a;
        base += K3_; ubase += N_;
    }
    agg_a[(size_t)cl * N_ + n] = Ap;
    agg_b[(size_t)cl * N_ + n] = Bc;
}

// --------- scan phase 3 (per stripe): self-fold prefix + replay ---------
// Folds predecessor chunk aggregates (identical fmaf order to the old
// phase2, bit-identical z0), replays the 16 steps, writes y_hat bf16.
// Carry for the next stripe is written only on even stripes (use_carry=0);
// odd stripes are the last of their batch, so their carry is dead —
// this also avoids any same-dispatch read/write race on carry.
__global__ __launch_bounds__(256) void scan_phase3f(
    const float* __restrict__ rawS, const float* __restrict__ usS,
    const float* __restrict__ bp, const float* __restrict__ dbias,
    const float* __restrict__ alog, const float* __restrict__ lgam,
    const float* __restrict__ inv_sin,
    const float* __restrict__ agg_a, const float* __restrict__ agg_b,
    float* __restrict__ carry, unsigned short* __restrict__ yh,
    int bidx, int use_carry)
{
    const int gid = blockIdx.x * 256 + threadIdx.x;
    const int n   = gid & (N_ - 1);
    const int cl  = gid >> 10;

    const float alpha = fast_sp(alog[n]);
    const float db    = dbias[n];
    const float bpd   = bp[n];
    const float bpb   = bp[N_ + n];
    const float bpc   = bp[2*N_ + n];
    const float sgain = __expf(lgam[0]) * inv_sin[0];

    // fold predecessor chunks (coalesced, L2-resident aggregates)
    float z = use_carry ? carry[bidx * N_ + n] : 0.f;
    for (int c = 0; c < cl; ++c)
        z = fmaf(agg_a[(size_t)c * N_ + n], z, agg_b[(size_t)c * N_ + n]);

    size_t base  = (size_t)(cl * CL_) * K3_ + n;
    size_t ubase = (size_t)(cl * CL_) * N_  + n;
    #pragma unroll 4
    for (int j = 0; j < CL_; ++j) {
        float dr = rawS[base]        + bpd;
        float br = rawS[base + N_]   + bpb;
        float cr = rawS[base + 2*N_] + bpc;
        float uv = usS[ubase];
        float a, bu, cv;
        abc_math(dr, br, cr, uv, alpha, db, sgain, &a, &bu, &cv);
        yh[ubase] = f2bf(cv * z);          // y_hat[t] uses pre-update state
        z = fmaf(a, z, bu);
        base += K3_; ubase += N_;
    }
    if (!use_carry && cl == CPS_ - 1) carry[bidx * N_ + n] = z;
}

// =====================================================================
extern "C" void kernel_launch(void* const* d_in, const int* in_sizes, int n_in,
                              void* d_out, int out_size, void* d_ws, size_t ws_size,
                              hipStream_t stream)
{
    (void)in_sizes; (void)n_in;
    const float* u     = (const float*)d_in[0];
    const float* W_in  = (const float*)d_in[1];
    const float* W_out = (const float*)d_in[2];
    const float* Wp    = (const float*)d_in[3];
    const float* bp    = (const float*)d_in[4];
    const float* alog  = (const float*)d_in[5];
    const float* dbias = (const float*)d_in[6];
    const float* lgam  = (const float*)d_in[7];
    float* y = (float*)d_out;

    if (ws_size < (size_t)REQ_FLOATS * sizeof(float)) {
        zero_out<<<(out_size + 255) / 256, dim3(256), 0, stream>>>(y, out_size);
        return;
    }

    float* ws = (float*)d_ws;
    float*          rawS  = ws + OFF_RAWS;
    float*          usS   = ws + OFF_USS;
    unsigned short* ubf   = (unsigned short*)(ws + OFF_UBF);
    unsigned short* Wcat  = (unsigned short*)(ws + OFF_WCAT);
    unsigned short* Woutb = (unsigned short*)(ws + OFF_WOUTB);
    float* agg_a = ws + OFF_AGA;
    float* agg_b = ws + OFF_AGB;
    float* carry = ws + OFF_CARRY;
    float* v0    = ws + OFF_V0;
    float* w1    = ws + OFF_W1;
    float* w2    = ws + OFF_W2;
    float* scal  = ws + OFF_SCAL;
    // sigma-phase aliases (live only before stripe processing)
    float*          G0   = rawS;                               // 2 x 1M f
    unsigned short* hiW  = (unsigned short*)(rawS + 2*MEG_);   // 2 x 1M shorts
    unsigned short* loW  = (unsigned short*)(rawS + 3*MEG_);   // 2 x 1M shorts
    unsigned short* SbfA = (unsigned short*)usS;               // 2 x 1M shorts
    unsigned short* SbfB = SbfA + 2*MEG_;                      // 2 x 1M shorts

    const dim3 blk(256);

    cvt_weights<<<20480, blk, 0, stream>>>(W_in, Wp, W_out, Wcat, Woutb, hiW, loW);

    // ---- spectral norms: split-bf16 MFMA gram (z=2), 6 bf16 squarings
    //      (unnormalized: bf16 exponent range covers lambda^64 ~ 4e13),
    //      then fp32 Rayleigh quotient on the MFMA-accurate G0. ----
    gram_bf16x2<<<dim3(16, 16, 2), blk, 0, stream>>>(hiW, loW, G0, SbfA);
    unsigned short* Sc = SbfA;
    unsigned short* Sn = SbfB;
    for (int r = 0; r < 6; ++r) {
        gemm64_t<true><<<dim3(16, 16, 2), blk, 0, stream>>>(
            Sc, Sc, (float*)Sn, 1024, 1024, MEG_, MEG_, MEG_ / 2, nullptr, 0);
        unsigned short* t = Sc; Sc = Sn; Sn = t;
    }
    pick_col<<<2, blk, 0, stream>>>(Sc, v0);     // Sc == SbfA after 6 swaps
    matvec_z<<<dim3(256, 2), blk, 0, stream>>>(G0, v0, w1);
    matvec_z<<<dim3(256, 2), blk, 0, stream>>>(G0, w1, w2);
    rq_scale<<<2, blk, 0, stream>>>(w1, w2, scal);   // scal[0]=inv_in, scal[1]=inv_out

    // ---- single pass over stripes (sequential carry) ----
    for (int s = 0; s < NSTRIPE_; ++s) {
        const int r0 = s * SROWS_;
        // fused fp32->bf16 + (W_in | Wp) gemm: cols<1024 -> usS, else rawS
        gemm_proj<<<dim3(32, 16), blk, 0, stream>>>(
            u + (size_t)r0 * DD_, Wcat, Wcat + (size_t)1024 * 1024, usS, rawS,
            1024, N_, K3_, 1024);
        scan_phase1<<<512, blk, 0, stream>>>(rawS, usS, bp, dbias, alog, lgam,
                                             scal, agg_a, agg_b);
        scan_phase3f<<<512, blk, 0, stream>>>(rawS, usS, bp, dbias, alog, lgam,
                                              scal, agg_a, agg_b, carry, ubf,
                                              s >> 1, s & 1);
        gemm64_t<false><<<dim3(16, 32, 1), blk, 0, stream>>>(
            ubf, Woutb, y + (size_t)r0 * N_, 1024, 1024,
            0, 0, 0, scal + 1, 1);
    }
}

// Round 5
// 1070.184 us; speedup vs baseline: 1.0726x; 1.0726x over previous
//
#include <hip/hip_runtime.h>

// ---------------- problem dims (fixed by setup_inputs) ----------------
#define B_    4
#define T_    4096
#define DD_   1024
#define N_    1024
#define K3_   3072
#define M_    16384      // B_*T_
#define CL_   16         // scan chunk length (time steps)
#define SROWS_ 2048      // stripe rows (one stripe = half a batch, aligned)
#define NSTRIPE_ (M_/SROWS_)     // 8
#define CPS_  (SROWS_/CL_)       // 128 chunks per stripe
#define MEG_  1048576

// ---------------- ws layout (float offsets), total ~47.6 MiB ----------------
// rawS (24 MiB) is aliased by the sigma phase: G0 (2M f) | hiW (1M f) | loW (1M f).
// usS (8 MiB) is aliased by the sigma phase: SbfA (2M shorts) | SbfB (2M shorts).
#define OFF_RAWS  ((size_t)0)                        // 6M f   (24 MiB)
#define OFF_USS   ((size_t)6*MEG_)                   // 2M f   (8 MiB)
#define OFF_UBF   ((size_t)8*MEG_)                   // 1M f = 2M shorts (u stripe bf16; later y_hat bf16)
#define OFF_WCAT  ((size_t)9*MEG_)                   // 2M f = 4M shorts (W_in rows then Wp rows)
#define OFF_WOUTB ((size_t)11*MEG_)                  // 512K f = 1M shorts
#define OFF_AGA   (OFF_WOUTB + 524288)               // 128K f
#define OFF_AGB   (OFF_AGA + 131072)
#define OFF_PRE   (OFF_AGB + 131072)                 // (unused, kept for layout)
#define OFF_CARRY (OFF_PRE + 131072)                 // 4096 f
#define OFF_V0    (OFF_CARRY + 4096)                 // 2048 f (2 z)
#define OFF_W1    (OFF_V0 + 2048)
#define OFF_W2    (OFF_W1 + 2048)
#define OFF_TR    (OFF_W2 + 2048)                    // 16 f (unused, kept for layout)
#define OFF_SCAL  (OFF_TR + 16)                      // [0]=inv_in, [1]=inv_out
#define REQ_FLOATS (OFF_SCAL + 16)

typedef short s8v __attribute__((ext_vector_type(8)));   // 8 bf16 (4 VGPRs)
typedef float f4v __attribute__((ext_vector_type(4)));   // MFMA acc

typedef __attribute__((address_space(3))) unsigned int       lds_u32;
typedef const __attribute__((address_space(1))) unsigned int glb_u32;

__device__ __forceinline__ void gload_lds16(const void* g, void* l)
{
    __builtin_amdgcn_global_load_lds((glb_u32*)g, (lds_u32*)l, 16, 0, 0);
}

// fp32 -> bf16 round-to-nearest-even
__device__ __forceinline__ unsigned short f2bf(float f)
{
    unsigned u = __float_as_uint(f);
    u += 0x7FFFu + ((u >> 16) & 1u);
    return (unsigned short)(u >> 16);
}
__device__ __forceinline__ float bf2f(unsigned short h)
{
    return __uint_as_float((unsigned)h << 16);
}

// ---------------- fallback: zero a float buffer ----------------
__global__ void zero_out(float* __restrict__ y, int n)
{
    int i = blockIdx.x * 256 + threadIdx.x;
    if (i < n) y[i] = 0.f;
}

// ------- one-time weight conversion to bf16 + split-bf16 hi/lo planes -------
// Wcat = bf16(W_in | Wp), Woutb = bf16(W_out);
// hi/lo: [z=0] W_in, [z=1] W_out split as w = hi + lo (residual ~2^-18 rel).
__global__ void cvt_weights(const float* __restrict__ Win, const float* __restrict__ Wp,
                            const float* __restrict__ Wout,
                            unsigned short* __restrict__ Wcat,
                            unsigned short* __restrict__ Woutb,
                            unsigned short* __restrict__ hi,
                            unsigned short* __restrict__ lo)
{
    int i = blockIdx.x * 256 + threadIdx.x;        // 0 .. 5M-1
    if (i < 1048576)       Wcat[i] = f2bf(Win[i]);
    else if (i < 4194304)  Wcat[i] = f2bf(Wp[i - 1048576]);
    else if (i < 5242880)  Woutb[i - 4194304] = f2bf(Wout[i - 4194304]);
    if (i < 2097152) {
        float wv = (i < MEG_) ? Win[i] : Wout[i - MEG_];
        unsigned short h = f2bf(wv);
        hi[i] = h;
        lo[i] = f2bf(wv - bf2f(h));                // w - hi exact in fp32
    }
}

// ---------------- per-stripe u conversion ----------------
__global__ void cvt_u(const float* __restrict__ src, unsigned short* __restrict__ dst)
{
    int i = blockIdx.x * 256 + threadIdx.x;        // 0 .. 2M-1
    dst[i] = f2bf(src[i]);
}

// =====================================================================
// Split-bf16 MFMA gram: C[z] = W[z] W[z]^T computed as
//   hi.hi^T + hi.lo^T + lo.hi^T  (lo.lo dropped, ~2^-36 of diag).
// 64x64 tile (512 blocks -> occupancy), BK=32, 4 waves 2x2 x (2x2
// mfma_16x16x32). Writes fp32 C (Rayleigh quotient) AND bf16 Cb (chain seed).
// =====================================================================
__global__ __launch_bounds__(256, 4) void gram_bf16x2(
    const unsigned short* __restrict__ hi, const unsigned short* __restrict__ lo,
    float* __restrict__ C, unsigned short* __restrict__ Cb)
{
    __shared__ __align__(16) unsigned short Ah[64 * 32];
    __shared__ __align__(16) unsigned short Al[64 * 32];
    __shared__ __align__(16) unsigned short Bh[64 * 32];
    __shared__ __align__(16) unsigned short Bl[64 * 32];
    const int tid = threadIdx.x;
    const int z   = blockIdx.z;
    const int m0  = blockIdx.y * 64;
    const int n0  = blockIdx.x * 64;

    const unsigned short* hz = hi + (size_t)z * MEG_;
    const unsigned short* lz = lo + (size_t)z * MEG_;

    const int lane = tid & 63;
    const int w    = tid >> 6;
    const int wm   = (w >> 1) * 32;
    const int wn   = (w & 1) * 32;
    const int lrow = lane & 15;
    const int quad = lane >> 4;
    const int srow = lane >> 2;          // 16 rows per wave-load
    const int scol = (lane & 3) * 8;     // 4 x 16B granules per row

    const size_t arow = (size_t)(m0 + w*16 + srow) * 1024 + scol;
    const size_t brow = (size_t)(n0 + w*16 + srow) * 1024 + scol;
    unsigned short* dA = &Ah[(w*16) * 32];
    unsigned short* eA = &Al[(w*16) * 32];
    unsigned short* dB = &Bh[(w*16) * 32];
    unsigned short* eB = &Bl[(w*16) * 32];

    f4v acc[2][2];
    #pragma unroll
    for (int i = 0; i < 2; ++i)
      #pragma unroll
      for (int j = 0; j < 2; ++j) acc[i][j] = (f4v){0.f, 0.f, 0.f, 0.f};

    for (int kt = 0; kt < 1024; kt += 32) {
        __syncthreads();
        gload_lds16(hz + arow + kt, dA);
        gload_lds16(lz + arow + kt, eA);
        gload_lds16(hz + brow + kt, dB);
        gload_lds16(lz + brow + kt, eB);
        __syncthreads();

        s8v ah[2], al[2], bh[2], bl[2];
        #pragma unroll
        for (int i = 0; i < 2; ++i) {
            ah[i] = *(const s8v*)&Ah[(wm + i*16 + lrow) * 32 + quad * 8];
            al[i] = *(const s8v*)&Al[(wm + i*16 + lrow) * 32 + quad * 8];
        }
        #pragma unroll
        for (int j = 0; j < 2; ++j) {
            bh[j] = *(const s8v*)&Bh[(wn + j*16 + lrow) * 32 + quad * 8];
            bl[j] = *(const s8v*)&Bl[(wn + j*16 + lrow) * 32 + quad * 8];
        }
        #pragma unroll
        for (int i = 0; i < 2; ++i)
          #pragma unroll
          for (int j = 0; j < 2; ++j) {
              acc[i][j] = __builtin_amdgcn_mfma_f32_16x16x32_bf16(ah[i], bh[j], acc[i][j], 0, 0, 0);
              acc[i][j] = __builtin_amdgcn_mfma_f32_16x16x32_bf16(ah[i], bl[j], acc[i][j], 0, 0, 0);
              acc[i][j] = __builtin_amdgcn_mfma_f32_16x16x32_bf16(al[i], bh[j], acc[i][j], 0, 0, 0);
          }
    }

    float*          Cz  = C  + (size_t)z * MEG_;
    unsigned short* Cbz = Cb + (size_t)z * MEG_;
    #pragma unroll
    for (int i = 0; i < 2; ++i)
      #pragma unroll
      for (int j = 0; j < 2; ++j) {
        const int col = n0 + wn + j * 16 + lrow;
        #pragma unroll
        for (int r = 0; r < 4; ++r) {
            const int row = m0 + wm + i * 16 + quad * 4 + r;
            float v = acc[i][j][r];
            Cz [(size_t)row * 1024 + col] = v;
            Cbz[(size_t)row * 1024 + col] = f2bf(v);
        }
    }
}

// =====================================================================
// bf16 MFMA NT GEMM, 64x64 tile (high grid count for 1024-class shapes),
// BK=32, 4 waves 2x2, each 32x32 via 2x2 mfma_16x16x32. z-batched.
// OBF: bf16 output (zsC still in floats of the underlying buffer).
// mode: 0 plain, 1 scale by sptr[0].
// =====================================================================
template<bool OBF>
__global__ __launch_bounds__(256, 4) void gemm64_t(
    const unsigned short* __restrict__ A, const unsigned short* __restrict__ B,
    float* __restrict__ C, int K, int ldc,
    long zsA, long zsB, long zsC,
    const float* __restrict__ sptr, int mode)
{
    __shared__ __align__(16) unsigned short As[64 * 32];
    __shared__ __align__(16) unsigned short Bs[64 * 32];
    const int tid = threadIdx.x;
    const int z   = blockIdx.z;
    const int m0  = blockIdx.y * 64;
    const int n0  = blockIdx.x * 64;

    const unsigned short* Az = A + (size_t)z * zsA;
    const unsigned short* Bz = B + (size_t)z * zsB;

    const int lane = tid & 63;
    const int w    = tid >> 6;
    const int wm   = (w >> 1) * 32;
    const int wn   = (w & 1) * 32;
    const int lrow = lane & 15;
    const int quad = lane >> 4;
    const int srow = lane >> 2;
    const int scol = (lane & 3) * 8;

    const unsigned short* Agl = Az + (size_t)(m0 + w*16 + srow) * K + scol;
    const unsigned short* Bgl = Bz + (size_t)(n0 + w*16 + srow) * K + scol;
    unsigned short* lA = &As[(w*16) * 32];
    unsigned short* lB = &Bs[(w*16) * 32];

    f4v acc[2][2];
    #pragma unroll
    for (int i = 0; i < 2; ++i)
      #pragma unroll
      for (int j = 0; j < 2; ++j) acc[i][j] = (f4v){0.f, 0.f, 0.f, 0.f};

    for (int kt = 0; kt < K; kt += 32) {
        __syncthreads();
        gload_lds16(Agl + kt, lA);
        gload_lds16(Bgl + kt, lB);
        __syncthreads();

        s8v af[2], bf[2];
        #pragma unroll
        for (int i = 0; i < 2; ++i)
            af[i] = *(const s8v*)&As[(wm + i*16 + lrow) * 32 + quad * 8];
        #pragma unroll
        for (int j = 0; j < 2; ++j)
            bf[j] = *(const s8v*)&Bs[(wn + j*16 + lrow) * 32 + quad * 8];
        #pragma unroll
        for (int i = 0; i < 2; ++i)
          #pragma unroll
          for (int j = 0; j < 2; ++j)
              acc[i][j] = __builtin_amdgcn_mfma_f32_16x16x32_bf16(af[i], bf[j], acc[i][j], 0, 0, 0);
    }

    float sc = (mode == 1) ? sptr[0] : 1.0f;
    float* Cp = C + (size_t)z * zsC;

    // C/D layout: col = lane&15, row = quad*4 + reg  [m89-verified]
    #pragma unroll
    for (int i = 0; i < 2; ++i)
      #pragma unroll
      for (int j = 0; j < 2; ++j) {
        const int col = n0 + wn + j * 16 + lrow;
        #pragma unroll
        for (int r = 0; r < 4; ++r) {
            const int row = m0 + wm + i * 16 + quad * 4 + r;
            if (OBF)
                ((unsigned short*)Cp)[(size_t)row * ldc + col] = f2bf(acc[i][j][r] * sc);
            else
                Cp[(size_t)row * ldc + col] = acc[i][j][r] * sc;
        }
    }
}

// =====================================================================
// Pure-bf16 MFMA NT GEMM, 128x128 tile, BK=32, 256 thr (4 waves 2x2,
// each 64x64 via 4x4 mfma_16x16x32). Dual-output column split at nsplit.
// Used for the big per-stripe u-projection (grid 512 blocks).
// =====================================================================
__global__ __launch_bounds__(256, 2) void gemm_bf16(
    const unsigned short* __restrict__ A,
    const unsigned short* __restrict__ B0, const unsigned short* __restrict__ B1,
    float* __restrict__ C0, float* __restrict__ C1,
    int K, int ldc0, int ldc1, int nsplit)
{
    __shared__ __align__(16) unsigned short As[128 * 32];
    __shared__ __align__(16) unsigned short Bs[128 * 32];
    const int tid = threadIdx.x;
    const int m0  = blockIdx.y * 128;
    const int n0g = blockIdx.x * 128;

    const unsigned short* Bsrc; float* Cp; int ldc; int c0;
    if (n0g < nsplit) {
        Bsrc = B0 + (size_t)n0g * K;
        Cp = C0; ldc = ldc0; c0 = n0g;
    } else {
        Bsrc = B1 + (size_t)(n0g - nsplit) * K;
        Cp = C1; ldc = ldc1; c0 = n0g - nsplit;
    }

    const int lane = tid & 63;
    const int w    = tid >> 6;          // wave 0..3
    const int wm   = (w >> 1) * 64;
    const int wn   = (w & 1) * 64;
    const int lrow = lane & 15;
    const int quad = lane >> 4;

    const int srow = (lane >> 2);
    const int scol = (lane & 3) * 8;
    const unsigned short* Agl0 = A    + (size_t)(m0 + w*32 + srow) * K + scol;
    const unsigned short* Agl1 = Agl0 + (size_t)16 * K;
    const unsigned short* Bgl0 = Bsrc + (size_t)(w*32 + srow) * K + scol;
    const unsigned short* Bgl1 = Bgl0 + (size_t)16 * K;
    unsigned short* lA0 = &As[(w*32     ) * 32];
    unsigned short* lA1 = &As[(w*32 + 16) * 32];
    unsigned short* lB0 = &Bs[(w*32     ) * 32];
    unsigned short* lB1 = &Bs[(w*32 + 16) * 32];

    f4v acc[4][4];
    #pragma unroll
    for (int i = 0; i < 4; ++i)
      #pragma unroll
      for (int j = 0; j < 4; ++j) acc[i][j] = (f4v){0.f, 0.f, 0.f, 0.f};

    for (int kt = 0; kt < K; kt += 32) {
        __syncthreads();                       // prev iter's LDS reads done
        gload_lds16(Agl0 + kt, lA0);
        gload_lds16(Agl1 + kt, lA1);
        gload_lds16(Bgl0 + kt, lB0);
        gload_lds16(Bgl1 + kt, lB1);
        __syncthreads();                       // drains vmcnt before barrier

        s8v af[4], bf[4];
        #pragma unroll
        for (int i = 0; i < 4; ++i)
            af[i] = *(const s8v*)&As[(wm + i*16 + lrow) * 32 + quad * 8];
        #pragma unroll
        for (int j = 0; j < 4; ++j)
            bf[j] = *(const s8v*)&Bs[(wn + j*16 + lrow) * 32 + quad * 8];
        #pragma unroll
        for (int i = 0; i < 4; ++i)
          #pragma unroll
          for (int j = 0; j < 4; ++j)
              acc[i][j] = __builtin_amdgcn_mfma_f32_16x16x32_bf16(af[i], bf[j], acc[i][j], 0, 0, 0);
    }

    // C/D layout: col = lane&15, row = quad*4 + reg  [m89-verified]
    #pragma unroll
    for (int i = 0; i < 4; ++i)
      #pragma unroll
      for (int j = 0; j < 4; ++j) {
        const int col = c0 + wn + j * 16 + lrow;
        #pragma unroll
        for (int r = 0; r < 4; ++r) {
            const int row = m0 + wm + i * 16 + quad * 4 + r;
            Cp[(size_t)row * ldc + col] = acc[i][j][r];
        }
    }
}

// ---- pick column with max diagonal (dominant-eigvec seed), z=blockIdx.x ----
// Input is the bf16 S^64 from the squaring chain.
__global__ void pick_col(const unsigned short* __restrict__ Pall, float* __restrict__ vall)
{
    const unsigned short* P = Pall + (size_t)blockIdx.x * MEG_;
    float* v = vall + blockIdx.x * N_;
    __shared__ float sval[256];
    __shared__ int   sidx[256];
    __shared__ int   jstar;
    const int tid = threadIdx.x;
    float best = -1.f; int bidx = 0;
    for (int i = tid; i < N_; i += 256) {
        float d = bf2f(P[(size_t)i * (N_ + 1)]);
        if (d > best) { best = d; bidx = i; }
    }
    sval[tid] = best; sidx[tid] = bidx; __syncthreads();
    for (int off = 128; off > 0; off >>= 1) {
        if (tid < off && sval[tid + off] > sval[tid]) {
            sval[tid] = sval[tid + off]; sidx[tid] = sidx[tid + off];
        }
        __syncthreads();
    }
    if (tid == 0) jstar = sidx[0];
    __syncthreads();
    const int j = jstar;   // symmetric: row j == column j
    for (int i = tid; i < N_; i += 256) v[i] = bf2f(P[(size_t)j * N_ + i]);
}

// ---------------- w = G[z] * v[z] (one wave per row), z=blockIdx.y ----------
__global__ __launch_bounds__(256) void matvec_z(
    const float* __restrict__ Gall, const float* __restrict__ vall,
    float* __restrict__ wall)
{
    const int z = blockIdx.y;
    const float* G = Gall + (size_t)z * MEG_;
    const float* v = vall + z * N_;
    const int row  = blockIdx.x * 4 + (threadIdx.x >> 6);
    const int lane = threadIdx.x & 63;
    const float* g = G + (size_t)row * N_;
    float s = 0.f;
    for (int j = lane; j < N_; j += 64) s += g[j] * v[j];
    #pragma unroll
    for (int off = 32; off > 0; off >>= 1) s += __shfl_down(s, off, 64);
    if (lane == 0) wall[z * N_ + row] = s;
}

// ------- Rayleigh quotient -> inv_scale[z] = 1/max(sigma,1), z=blockIdx.x ----
__global__ void rq_scale(const float* __restrict__ w1a, const float* __restrict__ w2a,
                         float* __restrict__ slot)
{
    const int z = blockIdx.x;
    const float* w1 = w1a + z * N_;
    const float* w2 = w2a + z * N_;
    __shared__ float r11[256];
    __shared__ float r12[256];
    const int tid = threadIdx.x;
    float d11 = 0.f, d12 = 0.f;
    for (int i = tid; i < N_; i += 256) {
        float a = w1[i], b = w2[i];
        d11 = fmaf(a, a, d11);
        d12 = fmaf(a, b, d12);
    }
    r11[tid] = d11; r12[tid] = d12; __syncthreads();
    for (int off = 128; off > 0; off >>= 1) {
        if (tid < off) { r11[tid] += r11[tid + off]; r12[tid] += r12[tid + off]; }
        __syncthreads();
    }
    if (tid == 0) {
        float lam = r12[0] / fmaxf(r11[0], 1e-30f);
        float sig = sqrtf(fmaxf(lam, 0.f));
        slot[z] = 1.0f / fmaxf(sig, 1.0f);
    }
}

// ---------------- fast elementwise math (hw v_exp/v_log) ----------------
__device__ __forceinline__ float fast_sp(float x)   // softplus
{
    return fmaxf(x, 0.f) + __logf(1.0f + __expf(-fabsf(x)));
}
__device__ __forceinline__ float fast_tanh(float x)
{
    float e = __expf(2.0f * fabsf(x));
    float t = 1.0f - 2.0f / (e + 1.0f);
    return copysignf(t, x);
}

__device__ __forceinline__ void abc_math(
    float dr, float br, float cr, float uval,
    float alpha, float db, float sgain,
    float* pa, float* pbu, float* pc)
{
    float delta = fast_sp(dr + db);
    float a = fminf(__expf(-delta * alpha), 1.0f - 1e-4f);
    float b = fast_tanh(br);
    float c = fast_tanh(cr);
    float p = fmaf(a, a, c * c);
    float r = b * b;
    float q = a * b;
    float pr = p - r;
    float disc = fmaf(pr, pr, 4.0f * q * q);
    float lam = 0.5f * (p + r + sqrtf(disc + 1e-12f));
    float sig = sqrtf(lam + 1e-12f);
    float inv = 1.0f / fmaxf(sig, 1.0f);
    a *= inv; b *= inv; c *= inv;
    *pa = a; *pc = c; *pbu = b * (sgain * uval);
}

// --------- scan phase 1 (per stripe): per-chunk composite (CL=16) ---------
// Stores the computed (a, bu, cv) IN-PLACE over rawS (each thread owns its
// (t,n) slots exclusively; fp32 round-trip is exact) so phase 3 replays
// with no transcendentals and no usS read.
__global__ __launch_bounds__(256) void scan_phase1(
    float* __restrict__ rawS, const float* __restrict__ usS,
    const float* __restrict__ bp, const float* __restrict__ dbias,
    const float* __restrict__ alog, const float* __restrict__ lgam,
    const float* __restrict__ inv_sin,
    float* __restrict__ agg_a, float* __restrict__ agg_b)
{
    const int gid = blockIdx.x * 256 + threadIdx.x;   // [0, CPS_*N_)
    const int n   = gid & (N_ - 1);
    const int cl  = gid >> 10;                        // local chunk 0..127

    const float alpha = fast_sp(alog[n]);
    const float db    = dbias[n];
    const float bpd   = bp[n];
    const float bpb   = bp[N_ + n];
    const float bpc   = bp[2*N_ + n];
    const float sgain = __expf(lgam[0]) * inv_sin[0];

    float Ap = 1.f, Bc = 0.f;
    size_t base  = (size_t)(cl * CL_) * K3_ + n;      // stripe-local
    size_t ubase = (size_t)(cl * CL_) * N_  + n;
    #pragma unroll 4
    for (int j = 0; j < CL_; ++j) {
        float dr = rawS[base]        + bpd;
        float br = rawS[base + N_]   + bpb;
        float cr = rawS[base + 2*N_] + bpc;
        float uv = usS[ubase];
        float a, bu, cv;
        abc_math(dr, br, cr, uv, alpha, db, sgain, &a, &bu, &cv);
        rawS[base]        = a;                         // in-place for phase 3
        rawS[base + N_]   = bu;
        rawS[base + 2*N_] = cv;
        Bc = fmaf(a, Bc, bu);
        Ap *= a;
        base += K3_; ubase += N_;
    }
    agg_a[(size_t)cl * N_ + n] = Ap;
    agg_b[(size_t)cl * N_ + n] = Bc;
}

// --------- scan phase 3 (per stripe): self-fold prefix + replay ---------
// Folds predecessor chunk aggregates (identical fmaf order to the old
// phase2, bit-identical z0), then replays from the stored (a, bu, cv) —
// no transcendentals. Carry written only on even stripes (use_carry=0);
// odd stripes end their batch, their carry is dead — also avoids any
// same-dispatch read/write race on carry.
__global__ __launch_bounds__(256) void scan_phase3f(
    const float* __restrict__ rawS,
    const float* __restrict__ agg_a, const float* __restrict__ agg_b,
    float* __restrict__ carry, unsigned short* __restrict__ yh,
    int bidx, int use_carry)
{
    const int gid = blockIdx.x * 256 + threadIdx.x;
    const int n   = gid & (N_ - 1);
    const int cl  = gid >> 10;

    // fold predecessor chunks (coalesced, L2-resident aggregates)
    float z = use_carry ? carry[bidx * N_ + n] : 0.f;
    for (int c = 0; c < cl; ++c)
        z = fmaf(agg_a[(size_t)c * N_ + n], z, agg_b[(size_t)c * N_ + n]);

    size_t base  = (size_t)(cl * CL_) * K3_ + n;
    size_t ubase = (size_t)(cl * CL_) * N_  + n;
    #pragma unroll 4
    for (int j = 0; j < CL_; ++j) {
        float a  = rawS[base];
        float bu = rawS[base + N_];
        float cv = rawS[base + 2*N_];
        yh[ubase] = f2bf(cv * z);          // y_hat[t] uses pre-update state
        z = fmaf(a, z, bu);
        base += K3_; ubase += N_;
    }
    if (!use_carry && cl == CPS_ - 1) carry[bidx * N_ + n] = z;
}

// =====================================================================
extern "C" void kernel_launch(void* const* d_in, const int* in_sizes, int n_in,
                              void* d_out, int out_size, void* d_ws, size_t ws_size,
                              hipStream_t stream)
{
    (void)in_sizes; (void)n_in;
    const float* u     = (const float*)d_in[0];
    const float* W_in  = (const float*)d_in[1];
    const float* W_out = (const float*)d_in[2];
    const float* Wp    = (const float*)d_in[3];
    const float* bp    = (const float*)d_in[4];
    const float* alog  = (const float*)d_in[5];
    const float* dbias = (const float*)d_in[6];
    const float* lgam  = (const float*)d_in[7];
    float* y = (float*)d_out;

    if (ws_size < (size_t)REQ_FLOATS * sizeof(float)) {
        zero_out<<<(out_size + 255) / 256, dim3(256), 0, stream>>>(y, out_size);
        return;
    }

    float* ws = (float*)d_ws;
    float*          rawS  = ws + OFF_RAWS;
    float*          usS   = ws + OFF_USS;
    unsigned short* ubf   = (unsigned short*)(ws + OFF_UBF);
    unsigned short* Wcat  = (unsigned short*)(ws + OFF_WCAT);
    unsigned short* Woutb = (unsigned short*)(ws + OFF_WOUTB);
    float* agg_a = ws + OFF_AGA;
    float* agg_b = ws + OFF_AGB;
    float* carry = ws + OFF_CARRY;
    float* v0    = ws + OFF_V0;
    float* w1    = ws + OFF_W1;
    float* w2    = ws + OFF_W2;
    float* scal  = ws + OFF_SCAL;
    // sigma-phase aliases (live only before stripe processing)
    float*          G0   = rawS;                               // 2 x 1M f
    unsigned short* hiW  = (unsigned short*)(rawS + 2*MEG_);   // 2 x 1M shorts
    unsigned short* loW  = (unsigned short*)(rawS + 3*MEG_);   // 2 x 1M shorts
    unsigned short* SbfA = (unsigned short*)usS;               // 2 x 1M shorts
    unsigned short* SbfB = SbfA + 2*MEG_;                      // 2 x 1M shorts

    const dim3 blk(256);

    cvt_weights<<<20480, blk, 0, stream>>>(W_in, Wp, W_out, Wcat, Woutb, hiW, loW);

    // ---- spectral norms: split-bf16 MFMA gram (z=2), 6 bf16 squarings
    //      (unnormalized: bf16 exponent range covers lambda^64 ~ 4e13),
    //      then fp32 Rayleigh quotient on the MFMA-accurate G0. ----
    gram_bf16x2<<<dim3(16, 16, 2), blk, 0, stream>>>(hiW, loW, G0, SbfA);
    unsigned short* Sc = SbfA;
    unsigned short* Sn = SbfB;
    for (int r = 0; r < 6; ++r) {
        gemm64_t<true><<<dim3(16, 16, 2), blk, 0, stream>>>(
            Sc, Sc, (float*)Sn, 1024, 1024, MEG_, MEG_, MEG_ / 2, nullptr, 0);
        unsigned short* t = Sc; Sc = Sn; Sn = t;
    }
    pick_col<<<2, blk, 0, stream>>>(Sc, v0);     // Sc == SbfA after 6 swaps
    matvec_z<<<dim3(256, 2), blk, 0, stream>>>(G0, v0, w1);
    matvec_z<<<dim3(256, 2), blk, 0, stream>>>(G0, w1, w2);
    rq_scale<<<2, blk, 0, stream>>>(w1, w2, scal);   // scal[0]=inv_in, scal[1]=inv_out

    // ---- single pass over stripes (sequential carry) ----
    for (int s = 0; s < NSTRIPE_; ++s) {
        const int r0 = s * SROWS_;
        cvt_u<<<8192, blk, 0, stream>>>(u + (size_t)r0 * DD_, ubf);
        // fused (W_in | Wp) gemm: cols < 1024 -> usS, cols >= 1024 -> rawS
        gemm_bf16<<<dim3(32, 16), blk, 0, stream>>>(
            ubf, Wcat, Wcat + (size_t)1024 * 1024, usS, rawS,
            1024, N_, K3_, 1024);
        scan_phase1<<<512, blk, 0, stream>>>(rawS, usS, bp, dbias, alog, lgam,
                                             scal, agg_a, agg_b);
        scan_phase3f<<<512, blk, 0, stream>>>(rawS, agg_a, agg_b, carry, ubf,
                                              s >> 1, s & 1);
        gemm64_t<false><<<dim3(16, 32, 1), blk, 0, stream>>>(
            ubf, Woutb, y + (size_t)r0 * N_, 1024, 1024,
            0, 0, 0, scal + 1, 1);
    }
}

// Round 6
// 812.485 us; speedup vs baseline: 1.4128x; 1.3172x over previous
//
#include <hip/hip_runtime.h>

// ---------------- problem dims (fixed by setup_inputs) ----------------
#define B_    4
#define T_    4096
#define DD_   1024
#define N_    1024
#define K3_   3072
#define M_    16384      // B_*T_
#define CL_   16         // scan chunk length (time steps)
#define MEG_  1048576

// ---------------- small-path ws layout (floats, ~48 MiB) ----------------
#define SROWS_ 2048
#define NSTRIPE_ (M_/SROWS_)     // 8
#define CPS_  (SROWS_/CL_)       // 128 chunks per stripe
#define OFF_RAWS  ((size_t)0)                        // 6M f
#define OFF_USS   ((size_t)6*MEG_)                   // 2M f
#define OFF_UBF   ((size_t)8*MEG_)                   // 1M f (2M shorts)
#define OFF_WCAT  ((size_t)9*MEG_)                   // 2M f (4M shorts)
#define OFF_WOUTB ((size_t)11*MEG_)                  // 512K f
#define OFF_AGA   (OFF_WOUTB + 524288)               // 128K f
#define OFF_AGB   (OFF_AGA + 131072)
#define OFF_PRE   (OFF_AGB + 131072)
#define OFF_CARRY (OFF_PRE + 131072)                 // 4096 f
#define OFF_V0    (OFF_CARRY + 4096)
#define OFF_W1    (OFF_V0 + 2048)
#define OFF_W2    (OFF_W1 + 2048)
#define OFF_SCAL  (OFF_W2 + 2048)
#define REQ_FLOATS (OFF_SCAL + 16)

// ---------------- big-path ws layout (floats, ~160 MiB) ----------------
// Stripe = 8192 rows = 2 whole batches -> no inter-stripe carry.
#define BSROWS_  8192
#define BNSTRIPE_ 2
#define BCPS_    (BSROWS_/CL_)     // 512 chunks per stripe
#define BCPB_    (T_/CL_)          // 256 chunks per batch chain
#define BOFF_RAWS  ((size_t)0)                       // 24M f (96 MiB)
#define BOFF_USS   ((size_t)24*MEG_)                 // 8M f  (32 MiB)
#define BOFF_UBF   ((size_t)32*MEG_)                 // 4M f  (8M shorts)
#define BOFF_WCAT  ((size_t)36*MEG_)                 // 2M f  (4M shorts)
#define BOFF_WOUTB ((size_t)38*MEG_)                 // 512K f
#define BOFF_AGA   (BOFF_WOUTB + 524288)             // 512K f
#define BOFF_AGB   (BOFF_AGA + 524288)
#define BOFF_PRE   (BOFF_AGB + 524288)               // 512K f
#define BOFF_V0    (BOFF_PRE + 524288)
#define BOFF_W1    (BOFF_V0 + 2048)
#define BOFF_W2    (BOFF_W1 + 2048)
#define BOFF_SCAL  (BOFF_W2 + 2048)
#define BREQ_FLOATS (BOFF_SCAL + 16)

typedef short s8v __attribute__((ext_vector_type(8)));   // 8 bf16 (4 VGPRs)
typedef float f4v __attribute__((ext_vector_type(4)));   // MFMA acc

typedef __attribute__((address_space(3))) unsigned int       lds_u32;
typedef const __attribute__((address_space(1))) unsigned int glb_u32;

__device__ __forceinline__ void gload_lds16(const void* g, void* l)
{
    __builtin_amdgcn_global_load_lds((glb_u32*)g, (lds_u32*)l, 16, 0, 0);
}

// fp32 -> bf16 round-to-nearest-even
__device__ __forceinline__ unsigned short f2bf(float f)
{
    unsigned u = __float_as_uint(f);
    u += 0x7FFFu + ((u >> 16) & 1u);
    return (unsigned short)(u >> 16);
}
__device__ __forceinline__ float bf2f(unsigned short h)
{
    return __uint_as_float((unsigned)h << 16);
}

// ---------------- fallback: zero a float buffer ----------------
__global__ void zero_out(float* __restrict__ y, int n)
{
    int i = blockIdx.x * 256 + threadIdx.x;
    if (i < n) y[i] = 0.f;
}

// ------- one-time weight conversion to bf16 + split-bf16 hi/lo planes -------
__global__ void cvt_weights(const float* __restrict__ Win, const float* __restrict__ Wp,
                            const float* __restrict__ Wout,
                            unsigned short* __restrict__ Wcat,
                            unsigned short* __restrict__ Woutb,
                            unsigned short* __restrict__ hi,
                            unsigned short* __restrict__ lo)
{
    int i = blockIdx.x * 256 + threadIdx.x;        // 0 .. 5M-1
    if (i < 1048576)       Wcat[i] = f2bf(Win[i]);
    else if (i < 4194304)  Wcat[i] = f2bf(Wp[i - 1048576]);
    else if (i < 5242880)  Woutb[i - 4194304] = f2bf(Wout[i - 4194304]);
    if (i < 2097152) {
        float wv = (i < MEG_) ? Win[i] : Wout[i - MEG_];
        unsigned short h = f2bf(wv);
        hi[i] = h;
        lo[i] = f2bf(wv - bf2f(h));                // w - hi exact in fp32
    }
}

// ---------------- per-stripe u conversion ----------------
__global__ void cvt_u(const float* __restrict__ src, unsigned short* __restrict__ dst)
{
    int i = blockIdx.x * 256 + threadIdx.x;
    dst[i] = f2bf(src[i]);
}

// =====================================================================
// Split-bf16 MFMA gram: C[z] = W[z] W[z]^T  (hi.hi + hi.lo + lo.hi).
// 64x64 tile, BK=32, 4 waves 2x2 x (2x2 mfma_16x16x32).
// =====================================================================
__global__ __launch_bounds__(256, 4) void gram_bf16x2(
    const unsigned short* __restrict__ hi, const unsigned short* __restrict__ lo,
    float* __restrict__ C, unsigned short* __restrict__ Cb)
{
    __shared__ __align__(16) unsigned short Ah[64 * 32];
    __shared__ __align__(16) unsigned short Al[64 * 32];
    __shared__ __align__(16) unsigned short Bh[64 * 32];
    __shared__ __align__(16) unsigned short Bl[64 * 32];
    const int tid = threadIdx.x;
    const int z   = blockIdx.z;
    const int m0  = blockIdx.y * 64;
    const int n0  = blockIdx.x * 64;

    const unsigned short* hz = hi + (size_t)z * MEG_;
    const unsigned short* lz = lo + (size_t)z * MEG_;

    const int lane = tid & 63;
    const int w    = tid >> 6;
    const int wm   = (w >> 1) * 32;
    const int wn   = (w & 1) * 32;
    const int lrow = lane & 15;
    const int quad = lane >> 4;
    const int srow = lane >> 2;
    const int scol = (lane & 3) * 8;

    const size_t arow = (size_t)(m0 + w*16 + srow) * 1024 + scol;
    const size_t brow = (size_t)(n0 + w*16 + srow) * 1024 + scol;
    unsigned short* dA = &Ah[(w*16) * 32];
    unsigned short* eA = &Al[(w*16) * 32];
    unsigned short* dB = &Bh[(w*16) * 32];
    unsigned short* eB = &Bl[(w*16) * 32];

    f4v acc[2][2];
    #pragma unroll
    for (int i = 0; i < 2; ++i)
      #pragma unroll
      for (int j = 0; j < 2; ++j) acc[i][j] = (f4v){0.f, 0.f, 0.f, 0.f};

    for (int kt = 0; kt < 1024; kt += 32) {
        __syncthreads();
        gload_lds16(hz + arow + kt, dA);
        gload_lds16(lz + arow + kt, eA);
        gload_lds16(hz + brow + kt, dB);
        gload_lds16(lz + brow + kt, eB);
        __syncthreads();

        s8v ah[2], al[2], bh[2], bl[2];
        #pragma unroll
        for (int i = 0; i < 2; ++i) {
            ah[i] = *(const s8v*)&Ah[(wm + i*16 + lrow) * 32 + quad * 8];
            al[i] = *(const s8v*)&Al[(wm + i*16 + lrow) * 32 + quad * 8];
        }
        #pragma unroll
        for (int j = 0; j < 2; ++j) {
            bh[j] = *(const s8v*)&Bh[(wn + j*16 + lrow) * 32 + quad * 8];
            bl[j] = *(const s8v*)&Bl[(wn + j*16 + lrow) * 32 + quad * 8];
        }
        #pragma unroll
        for (int i = 0; i < 2; ++i)
          #pragma unroll
          for (int j = 0; j < 2; ++j) {
              acc[i][j] = __builtin_amdgcn_mfma_f32_16x16x32_bf16(ah[i], bh[j], acc[i][j], 0, 0, 0);
              acc[i][j] = __builtin_amdgcn_mfma_f32_16x16x32_bf16(ah[i], bl[j], acc[i][j], 0, 0, 0);
              acc[i][j] = __builtin_amdgcn_mfma_f32_16x16x32_bf16(al[i], bh[j], acc[i][j], 0, 0, 0);
          }
    }

    float*          Cz  = C  + (size_t)z * MEG_;
    unsigned short* Cbz = Cb + (size_t)z * MEG_;
    #pragma unroll
    for (int i = 0; i < 2; ++i)
      #pragma unroll
      for (int j = 0; j < 2; ++j) {
        const int col = n0 + wn + j * 16 + lrow;
        #pragma unroll
        for (int r = 0; r < 4; ++r) {
            const int row = m0 + wm + i * 16 + quad * 4 + r;
            float v = acc[i][j][r];
            Cz [(size_t)row * 1024 + col] = v;
            Cbz[(size_t)row * 1024 + col] = f2bf(v);
        }
    }
}

// =====================================================================
// bf16 MFMA NT GEMM, 64x64 tile, BK=32, z-batched. OBF: bf16 output.
// mode: 0 plain, 1 scale by sptr[0].
// =====================================================================
template<bool OBF>
__global__ __launch_bounds__(256, 4) void gemm64_t(
    const unsigned short* __restrict__ A, const unsigned short* __restrict__ B,
    float* __restrict__ C, int K, int ldc,
    long zsA, long zsB, long zsC,
    const float* __restrict__ sptr, int mode)
{
    __shared__ __align__(16) unsigned short As[64 * 32];
    __shared__ __align__(16) unsigned short Bs[64 * 32];
    const int tid = threadIdx.x;
    const int z   = blockIdx.z;
    const int m0  = blockIdx.y * 64;
    const int n0  = blockIdx.x * 64;

    const unsigned short* Az = A + (size_t)z * zsA;
    const unsigned short* Bz = B + (size_t)z * zsB;

    const int lane = tid & 63;
    const int w    = tid >> 6;
    const int wm   = (w >> 1) * 32;
    const int wn   = (w & 1) * 32;
    const int lrow = lane & 15;
    const int quad = lane >> 4;
    const int srow = lane >> 2;
    const int scol = (lane & 3) * 8;

    const unsigned short* Agl = Az + (size_t)(m0 + w*16 + srow) * K + scol;
    const unsigned short* Bgl = Bz + (size_t)(n0 + w*16 + srow) * K + scol;
    unsigned short* lA = &As[(w*16) * 32];
    unsigned short* lB = &Bs[(w*16) * 32];

    f4v acc[2][2];
    #pragma unroll
    for (int i = 0; i < 2; ++i)
      #pragma unroll
      for (int j = 0; j < 2; ++j) acc[i][j] = (f4v){0.f, 0.f, 0.f, 0.f};

    for (int kt = 0; kt < K; kt += 32) {
        __syncthreads();
        gload_lds16(Agl + kt, lA);
        gload_lds16(Bgl + kt, lB);
        __syncthreads();

        s8v af[2], bf[2];
        #pragma unroll
        for (int i = 0; i < 2; ++i)
            af[i] = *(const s8v*)&As[(wm + i*16 + lrow) * 32 + quad * 8];
        #pragma unroll
        for (int j = 0; j < 2; ++j)
            bf[j] = *(const s8v*)&Bs[(wn + j*16 + lrow) * 32 + quad * 8];
        #pragma unroll
        for (int i = 0; i < 2; ++i)
          #pragma unroll
          for (int j = 0; j < 2; ++j)
              acc[i][j] = __builtin_amdgcn_mfma_f32_16x16x32_bf16(af[i], bf[j], acc[i][j], 0, 0, 0);
    }

    float sc = (mode == 1) ? sptr[0] : 1.0f;
    float* Cp = C + (size_t)z * zsC;

    #pragma unroll
    for (int i = 0; i < 2; ++i)
      #pragma unroll
      for (int j = 0; j < 2; ++j) {
        const int col = n0 + wn + j * 16 + lrow;
        #pragma unroll
        for (int r = 0; r < 4; ++r) {
            const int row = m0 + wm + i * 16 + quad * 4 + r;
            if (OBF)
                ((unsigned short*)Cp)[(size_t)row * ldc + col] = f2bf(acc[i][j][r] * sc);
            else
                Cp[(size_t)row * ldc + col] = acc[i][j][r] * sc;
        }
    }
}

// =====================================================================
// Pure-bf16 MFMA NT GEMM, 128x128 tile, BK=32. Dual-output split at nsplit.
// =====================================================================
__global__ __launch_bounds__(256, 2) void gemm_bf16(
    const unsigned short* __restrict__ A,
    const unsigned short* __restrict__ B0, const unsigned short* __restrict__ B1,
    float* __restrict__ C0, float* __restrict__ C1,
    int K, int ldc0, int ldc1, int nsplit)
{
    __shared__ __align__(16) unsigned short As[128 * 32];
    __shared__ __align__(16) unsigned short Bs[128 * 32];
    const int tid = threadIdx.x;
    const int m0  = blockIdx.y * 128;
    const int n0g = blockIdx.x * 128;

    const unsigned short* Bsrc; float* Cp; int ldc; int c0;
    if (n0g < nsplit) {
        Bsrc = B0 + (size_t)n0g * K;
        Cp = C0; ldc = ldc0; c0 = n0g;
    } else {
        Bsrc = B1 + (size_t)(n0g - nsplit) * K;
        Cp = C1; ldc = ldc1; c0 = n0g - nsplit;
    }

    const int lane = tid & 63;
    const int w    = tid >> 6;
    const int wm   = (w >> 1) * 64;
    const int wn   = (w & 1) * 64;
    const int lrow = lane & 15;
    const int quad = lane >> 4;

    const int srow = (lane >> 2);
    const int scol = (lane & 3) * 8;
    const unsigned short* Agl0 = A    + (size_t)(m0 + w*32 + srow) * K + scol;
    const unsigned short* Agl1 = Agl0 + (size_t)16 * K;
    const unsigned short* Bgl0 = Bsrc + (size_t)(w*32 + srow) * K + scol;
    const unsigned short* Bgl1 = Bgl0 + (size_t)16 * K;
    unsigned short* lA0 = &As[(w*32     ) * 32];
    unsigned short* lA1 = &As[(w*32 + 16) * 32];
    unsigned short* lB0 = &Bs[(w*32     ) * 32];
    unsigned short* lB1 = &Bs[(w*32 + 16) * 32];

    f4v acc[4][4];
    #pragma unroll
    for (int i = 0; i < 4; ++i)
      #pragma unroll
      for (int j = 0; j < 4; ++j) acc[i][j] = (f4v){0.f, 0.f, 0.f, 0.f};

    for (int kt = 0; kt < K; kt += 32) {
        __syncthreads();
        gload_lds16(Agl0 + kt, lA0);
        gload_lds16(Agl1 + kt, lA1);
        gload_lds16(Bgl0 + kt, lB0);
        gload_lds16(Bgl1 + kt, lB1);
        __syncthreads();

        s8v af[4], bf[4];
        #pragma unroll
        for (int i = 0; i < 4; ++i)
            af[i] = *(const s8v*)&As[(wm + i*16 + lrow) * 32 + quad * 8];
        #pragma unroll
        for (int j = 0; j < 4; ++j)
            bf[j] = *(const s8v*)&Bs[(wn + j*16 + lrow) * 32 + quad * 8];
        #pragma unroll
        for (int i = 0; i < 4; ++i)
          #pragma unroll
          for (int j = 0; j < 4; ++j)
              acc[i][j] = __builtin_amdgcn_mfma_f32_16x16x32_bf16(af[i], bf[j], acc[i][j], 0, 0, 0);
    }

    #pragma unroll
    for (int i = 0; i < 4; ++i)
      #pragma unroll
      for (int j = 0; j < 4; ++j) {
        const int col = c0 + wn + j * 16 + lrow;
        #pragma unroll
        for (int r = 0; r < 4; ++r) {
            const int row = m0 + wm + i * 16 + quad * 4 + r;
            Cp[(size_t)row * ldc + col] = acc[i][j][r];
        }
    }
}

// ---- pick column with max diagonal (dominant-eigvec seed), z=blockIdx.x ----
__global__ void pick_col(const unsigned short* __restrict__ Pall, float* __restrict__ vall)
{
    const unsigned short* P = Pall + (size_t)blockIdx.x * MEG_;
    float* v = vall + blockIdx.x * N_;
    __shared__ float sval[256];
    __shared__ int   sidx[256];
    __shared__ int   jstar;
    const int tid = threadIdx.x;
    float best = -1.f; int bidx = 0;
    for (int i = tid; i < N_; i += 256) {
        float d = bf2f(P[(size_t)i * (N_ + 1)]);
        if (d > best) { best = d; bidx = i; }
    }
    sval[tid] = best; sidx[tid] = bidx; __syncthreads();
    for (int off = 128; off > 0; off >>= 1) {
        if (tid < off && sval[tid + off] > sval[tid]) {
            sval[tid] = sval[tid + off]; sidx[tid] = sidx[tid + off];
        }
        __syncthreads();
    }
    if (tid == 0) jstar = sidx[0];
    __syncthreads();
    const int j = jstar;
    for (int i = tid; i < N_; i += 256) v[i] = bf2f(P[(size_t)j * N_ + i]);
}

// ---------------- w = G[z] * v[z] (one wave per row), z=blockIdx.y ----------
__global__ __launch_bounds__(256) void matvec_z(
    const float* __restrict__ Gall, const float* __restrict__ vall,
    float* __restrict__ wall)
{
    const int z = blockIdx.y;
    const float* G = Gall + (size_t)z * MEG_;
    const float* v = vall + z * N_;
    const int row  = blockIdx.x * 4 + (threadIdx.x >> 6);
    const int lane = threadIdx.x & 63;
    const float* g = G + (size_t)row * N_;
    float s = 0.f;
    for (int j = lane; j < N_; j += 64) s += g[j] * v[j];
    #pragma unroll
    for (int off = 32; off > 0; off >>= 1) s += __shfl_down(s, off, 64);
    if (lane == 0) wall[z * N_ + row] = s;
}

// ------- Rayleigh quotient -> inv_scale[z] = 1/max(sigma,1), z=blockIdx.x ----
__global__ void rq_scale(const float* __restrict__ w1a, const float* __restrict__ w2a,
                         float* __restrict__ slot)
{
    const int z = blockIdx.x;
    const float* w1 = w1a + z * N_;
    const float* w2 = w2a + z * N_;
    __shared__ float r11[256];
    __shared__ float r12[256];
    const int tid = threadIdx.x;
    float d11 = 0.f, d12 = 0.f;
    for (int i = tid; i < N_; i += 256) {
        float a = w1[i], b = w2[i];
        d11 = fmaf(a, a, d11);
        d12 = fmaf(a, b, d12);
    }
    r11[tid] = d11; r12[tid] = d12; __syncthreads();
    for (int off = 128; off > 0; off >>= 1) {
        if (tid < off) { r11[tid] += r11[tid + off]; r12[tid] += r12[tid + off]; }
        __syncthreads();
    }
    if (tid == 0) {
        float lam = r12[0] / fmaxf(r11[0], 1e-30f);
        float sig = sqrtf(fmaxf(lam, 0.f));
        slot[z] = 1.0f / fmaxf(sig, 1.0f);
    }
}

// ---------------- fast elementwise math (hw v_exp/v_log) ----------------
__device__ __forceinline__ float fast_sp(float x)
{
    return fmaxf(x, 0.f) + __logf(1.0f + __expf(-fabsf(x)));
}
__device__ __forceinline__ float fast_tanh(float x)
{
    float e = __expf(2.0f * fabsf(x));
    float t = 1.0f - 2.0f / (e + 1.0f);
    return copysignf(t, x);
}

__device__ __forceinline__ void abc_math(
    float dr, float br, float cr, float uval,
    float alpha, float db, float sgain,
    float* pa, float* pbu, float* pc)
{
    float delta = fast_sp(dr + db);
    float a = fminf(__expf(-delta * alpha), 1.0f - 1e-4f);
    float b = fast_tanh(br);
    float c = fast_tanh(cr);
    float p = fmaf(a, a, c * c);
    float r = b * b;
    float q = a * b;
    float pr = p - r;
    float disc = fmaf(pr, pr, 4.0f * q * q);
    float lam = 0.5f * (p + r + sqrtf(disc + 1e-12f));
    float sig = sqrtf(lam + 1e-12f);
    float inv = 1.0f / fmaxf(sig, 1.0f);
    a *= inv; b *= inv; c *= inv;
    *pa = a; *pc = c; *pbu = b * (sgain * uval);
}

// --------- scan phase 1: per-chunk composite (CL=16), grid covers stripe ---
__global__ __launch_bounds__(256) void scan_phase1(
    const float* __restrict__ rawS, const float* __restrict__ usS,
    const float* __restrict__ bp, const float* __restrict__ dbias,
    const float* __restrict__ alog, const float* __restrict__ lgam,
    const float* __restrict__ inv_sin,
    float* __restrict__ agg_a, float* __restrict__ agg_b)
{
    const int gid = blockIdx.x * 256 + threadIdx.x;
    const int n   = gid & (N_ - 1);
    const int cl  = gid >> 10;

    const float alpha = fast_sp(alog[n]);
    const float db    = dbias[n];
    const float bpd   = bp[n];
    const float bpb   = bp[N_ + n];
    const float bpc   = bp[2*N_ + n];
    const float sgain = __expf(lgam[0]) * inv_sin[0];

    float Ap = 1.f, Bc = 0.f;
    size_t base  = (size_t)(cl * CL_) * K3_ + n;
    size_t ubase = (size_t)(cl * CL_) * N_  + n;
    #pragma unroll 4
    for (int j = 0; j < CL_; ++j) {
        float dr = rawS[base]        + bpd;
        float br = rawS[base + N_]   + bpb;
        float cr = rawS[base + 2*N_] + bpc;
        float uv = usS[ubase];
        float a, bu, cv;
        abc_math(dr, br, cr, uv, alpha, db, sgain, &a, &bu, &cv);
        Bc = fmaf(a, Bc, bu);
        Ap *= a;
        base += K3_; ubase += N_;
    }
    agg_a[(size_t)cl * N_ + n] = Ap;
    agg_b[(size_t)cl * N_ + n] = Bc;
}

// --------- scan phase 2 (small path): chunk-prefix with inter-stripe carry --
__global__ void scan_phase2s(const float* __restrict__ agg_a,
                             const float* __restrict__ agg_b,
                             float* __restrict__ pref, float* __restrict__ carry,
                             int bidx, int use_carry)
{
    const int n = blockIdx.x * 256 + threadIdx.x;
    float z = use_carry ? carry[bidx * N_ + n] : 0.f;
    size_t idx = n;
    for (int c = 0; c < CPS_; ++c) {
        pref[idx] = z;
        z = fmaf(agg_a[idx], z, agg_b[idx]);
        idx += N_;
    }
    carry[bidx * N_ + n] = z;
}

// --------- scan phase 2 (big path): independent per-batch chains, z0 = 0 ---
// blockIdx.y = chain (batch within stripe); cpb chunks per chain.
__global__ void scan_phase2b(const float* __restrict__ agg_a,
                             const float* __restrict__ agg_b,
                             float* __restrict__ pref, int cpb)
{
    const int n = blockIdx.x * 256 + threadIdx.x;
    const int chain = blockIdx.y;
    size_t idx = (size_t)chain * cpb * N_ + n;
    float z = 0.f;
    for (int c = 0; c < cpb; ++c) {
        pref[idx] = z;
        z = fmaf(agg_a[idx], z, agg_b[idx]);
        idx += N_;
    }
}

// --------- scan phase 3: replay with chunk prefix, write y_hat bf16 ---------
__global__ __launch_bounds__(256) void scan_phase3(
    const float* __restrict__ rawS, const float* __restrict__ usS,
    const float* __restrict__ bp, const float* __restrict__ dbias,
    const float* __restrict__ alog, const float* __restrict__ lgam,
    const float* __restrict__ inv_sin, const float* __restrict__ pref,
    unsigned short* __restrict__ yh)
{
    const int gid = blockIdx.x * 256 + threadIdx.x;
    const int n   = gid & (N_ - 1);
    const int cl  = gid >> 10;

    const float alpha = fast_sp(alog[n]);
    const float db    = dbias[n];
    const float bpd   = bp[n];
    const float bpb   = bp[N_ + n];
    const float bpc   = bp[2*N_ + n];
    const float sgain = __expf(lgam[0]) * inv_sin[0];

    float z = pref[(size_t)cl * N_ + n];
    size_t base  = (size_t)(cl * CL_) * K3_ + n;
    size_t ubase = (size_t)(cl * CL_) * N_  + n;
    #pragma unroll 4
    for (int j = 0; j < CL_; ++j) {
        float dr = rawS[base]        + bpd;
        float br = rawS[base + N_]   + bpb;
        float cr = rawS[base + 2*N_] + bpc;
        float uv = usS[ubase];
        float a, bu, cv;
        abc_math(dr, br, cr, uv, alpha, db, sgain, &a, &bu, &cv);
        yh[ubase] = f2bf(cv * z);
        z = fmaf(a, z, bu);
        base += K3_; ubase += N_;
    }
}

// =====================================================================
extern "C" void kernel_launch(void* const* d_in, const int* in_sizes, int n_in,
                              void* d_out, int out_size, void* d_ws, size_t ws_size,
                              hipStream_t stream)
{
    (void)in_sizes; (void)n_in;
    const float* u     = (const float*)d_in[0];
    const float* W_in  = (const float*)d_in[1];
    const float* W_out = (const float*)d_in[2];
    const float* Wp    = (const float*)d_in[3];
    const float* bp    = (const float*)d_in[4];
    const float* alog  = (const float*)d_in[5];
    const float* dbias = (const float*)d_in[6];
    const float* lgam  = (const float*)d_in[7];
    float* y = (float*)d_out;

    if (ws_size < (size_t)REQ_FLOATS * sizeof(float)) {
        zero_out<<<(out_size + 255) / 256, dim3(256), 0, stream>>>(y, out_size);
        return;
    }
    const bool big = ws_size >= (size_t)BREQ_FLOATS * sizeof(float);

    float* ws = (float*)d_ws;
    float*          rawS  = ws + (big ? BOFF_RAWS  : OFF_RAWS);
    float*          usS   = ws + (big ? BOFF_USS   : OFF_USS);
    unsigned short* ubf   = (unsigned short*)(ws + (big ? BOFF_UBF   : OFF_UBF));
    unsigned short* Wcat  = (unsigned short*)(ws + (big ? BOFF_WCAT  : OFF_WCAT));
    unsigned short* Woutb = (unsigned short*)(ws + (big ? BOFF_WOUTB : OFF_WOUTB));
    float* agg_a = ws + (big ? BOFF_AGA  : OFF_AGA);
    float* agg_b = ws + (big ? BOFF_AGB  : OFF_AGB);
    float* pref  = ws + (big ? BOFF_PRE  : OFF_PRE);
    float* carry = ws + OFF_CARRY;                       // small path only
    float* v0    = ws + (big ? BOFF_V0   : OFF_V0);
    float* w1    = ws + (big ? BOFF_W1   : OFF_W1);
    float* w2    = ws + (big ? BOFF_W2   : OFF_W2);
    float* scal  = ws + (big ? BOFF_SCAL : OFF_SCAL);
    // sigma-phase aliases (live only before stripe processing)
    float*          G0   = rawS;                               // 2 x 1M f
    unsigned short* hiW  = (unsigned short*)(rawS + 2*MEG_);   // 2 x 1M shorts
    unsigned short* loW  = (unsigned short*)(rawS + 3*MEG_);   // 2 x 1M shorts
    unsigned short* SbfA = (unsigned short*)usS;               // 2 x 1M shorts
    unsigned short* SbfB = SbfA + 2*MEG_;                      // 2 x 1M shorts

    const dim3 blk(256);

    cvt_weights<<<20480, blk, 0, stream>>>(W_in, Wp, W_out, Wcat, Woutb, hiW, loW);

    // ---- spectral norms: split-bf16 MFMA gram (z=2), 6 bf16 squarings,
    //      fp32 Rayleigh quotient on the MFMA-accurate G0. ----
    gram_bf16x2<<<dim3(16, 16, 2), blk, 0, stream>>>(hiW, loW, G0, SbfA);
    unsigned short* Sc = SbfA;
    unsigned short* Sn = SbfB;
    for (int r = 0; r < 6; ++r) {
        gemm64_t<true><<<dim3(16, 16, 2), blk, 0, stream>>>(
            Sc, Sc, (float*)Sn, 1024, 1024, MEG_, MEG_, MEG_ / 2, nullptr, 0);
        unsigned short* t = Sc; Sc = Sn; Sn = t;
    }
    pick_col<<<2, blk, 0, stream>>>(Sc, v0);
    matvec_z<<<dim3(256, 2), blk, 0, stream>>>(G0, v0, w1);
    matvec_z<<<dim3(256, 2), blk, 0, stream>>>(G0, w1, w2);
    rq_scale<<<2, blk, 0, stream>>>(w1, w2, scal);   // scal[0]=inv_in, scal[1]=inv_out

    if (big) {
        // ---- 2 stripes of 8192 rows (2 whole batches each, no carry) ----
        for (int s = 0; s < BNSTRIPE_; ++s) {
            const int r0 = s * BSROWS_;
            cvt_u<<<32768, blk, 0, stream>>>(u + (size_t)r0 * DD_, ubf);
            gemm_bf16<<<dim3(32, 64), blk, 0, stream>>>(
                ubf, Wcat, Wcat + (size_t)1024 * 1024, usS, rawS,
                1024, N_, K3_, 1024);
            scan_phase1<<<2048, blk, 0, stream>>>(rawS, usS, bp, dbias, alog,
                                                  lgam, scal, agg_a, agg_b);
            scan_phase2b<<<dim3(4, 2), blk, 0, stream>>>(agg_a, agg_b, pref, BCPB_);
            scan_phase3<<<2048, blk, 0, stream>>>(rawS, usS, bp, dbias, alog,
                                                  lgam, scal, pref, ubf);
            gemm64_t<false><<<dim3(16, 128, 1), blk, 0, stream>>>(
                ubf, Woutb, y + (size_t)r0 * N_, 1024, 1024,
                0, 0, 0, scal + 1, 1);
        }
    } else {
        // ---- 8 stripes of 2048 rows with sequential carry (round-2 path) ----
        for (int s = 0; s < NSTRIPE_; ++s) {
            const int r0 = s * SROWS_;
            cvt_u<<<8192, blk, 0, stream>>>(u + (size_t)r0 * DD_, ubf);
            gemm_bf16<<<dim3(32, 16), blk, 0, stream>>>(
                ubf, Wcat, Wcat + (size_t)1024 * 1024, usS, rawS,
                1024, N_, K3_, 1024);
            scan_phase1<<<512, blk, 0, stream>>>(rawS, usS, bp, dbias, alog,
                                                 lgam, scal, agg_a, agg_b);
            scan_phase2s<<<4, blk, 0, stream>>>(agg_a, agg_b, pref, carry,
                                                s >> 1, s & 1);
            scan_phase3<<<512, blk, 0, stream>>>(rawS, usS, bp, dbias, alog,
                                                 lgam, scal, pref, ubf);
            gemm64_t<false><<<dim3(16, 32, 1), blk, 0, stream>>>(
                ubf, Woutb, y + (size_t)r0 * N_, 1024, 1024,
                0, 0, 0, scal + 1, 1);
        }
    }
}

// Round 7
// 800.031 us; speedup vs baseline: 1.4348x; 1.0156x over previous
//
#include <hip/hip_runtime.h>

// ---------------- problem dims (fixed by setup_inputs) ----------------
#define B_    4
#define T_    4096
#define DD_   1024
#define N_    1024
#define K3_   3072
#define M_    16384      // B_*T_
#define CL_   16         // scan chunk length (time steps)
#define MEG_  1048576

// ---------------- small-path ws layout (floats, ~48 MiB) ----------------
#define SROWS_ 2048
#define NSTRIPE_ (M_/SROWS_)     // 8
#define CPS_  (SROWS_/CL_)       // 128 chunks per stripe
#define OFF_RAWS  ((size_t)0)                        // 6M f
#define OFF_USS   ((size_t)6*MEG_)                   // 2M f
#define OFF_UBF   ((size_t)8*MEG_)                   // 1M f (2M shorts)
#define OFF_WCAT  ((size_t)9*MEG_)                   // 2M f (4M shorts)
#define OFF_WOUTB ((size_t)11*MEG_)                  // 512K f
#define OFF_AGA   (OFF_WOUTB + 524288)               // 128K f
#define OFF_AGB   (OFF_AGA + 131072)
#define OFF_PRE   (OFF_AGB + 131072)
#define OFF_CARRY (OFF_PRE + 131072)                 // 4096 f
#define OFF_V0    (OFF_CARRY + 4096)
#define OFF_W1    (OFF_V0 + 2048)
#define OFF_W2    (OFF_W1 + 2048)
#define OFF_SCAL  (OFF_W2 + 2048)
#define REQ_FLOATS (OFF_SCAL + 16)

// ---------------- big-path ws layout (floats, ~160 MiB) ----------------
// Stripe = 8192 rows = 2 whole batches -> no inter-stripe carry.
#define BSROWS_  8192
#define BNSTRIPE_ 2
#define BCPS_    (BSROWS_/CL_)     // 512 chunks per stripe
#define BCPB_    (T_/CL_)          // 256 chunks per batch chain
#define BOFF_RAWS  ((size_t)0)                       // 24M f (96 MiB)
#define BOFF_USS   ((size_t)24*MEG_)                 // 8M f  (32 MiB)
#define BOFF_UBF   ((size_t)32*MEG_)                 // 4M f  (8M shorts)
#define BOFF_WCAT  ((size_t)36*MEG_)                 // 2M f  (4M shorts)
#define BOFF_WOUTB ((size_t)38*MEG_)                 // 512K f
#define BOFF_AGA   (BOFF_WOUTB + 524288)             // 512K f
#define BOFF_AGB   (BOFF_AGA + 524288)
#define BOFF_PRE   (BOFF_AGB + 524288)               // 512K f
#define BOFF_V0    (BOFF_PRE + 524288)
#define BOFF_W1    (BOFF_V0 + 2048)
#define BOFF_W2    (BOFF_W1 + 2048)
#define BOFF_SCAL  (BOFF_W2 + 2048)
#define BREQ_FLOATS (BOFF_SCAL + 16)

typedef short s8v __attribute__((ext_vector_type(8)));   // 8 bf16 (4 VGPRs)
typedef float f4v __attribute__((ext_vector_type(4)));   // MFMA acc

typedef __attribute__((address_space(3))) unsigned int       lds_u32;
typedef const __attribute__((address_space(1))) unsigned int glb_u32;

__device__ __forceinline__ void gload_lds16(const void* g, void* l)
{
    __builtin_amdgcn_global_load_lds((glb_u32*)g, (lds_u32*)l, 16, 0, 0);
}

// fp32 -> bf16 round-to-nearest-even
__device__ __forceinline__ unsigned short f2bf(float f)
{
    unsigned u = __float_as_uint(f);
    u += 0x7FFFu + ((u >> 16) & 1u);
    return (unsigned short)(u >> 16);
}
__device__ __forceinline__ float bf2f(unsigned short h)
{
    return __uint_as_float((unsigned)h << 16);
}

// ---- LDS bank-conflict XOR swizzle (rule #21: linear dest, permuted
// source granule on stage + matching slot on read; bit-identical data).
// Stage: lane sources granule (lane&3)^((lane>>3)&3) of its row.
// Read: granule q of row r lives at slot q ^ ((r>>1)&3); all row bases
// are multiples of 16, so (r>>1)&3 == (lrow>>1)&3.
#define SWZ_SRC_GRAN(lane)  (((lane) & 3) ^ (((lane) >> 3) & 3))
#define SWZ_SLOT(quad,lrow) ((quad) ^ (((lrow) >> 1) & 3))

// ---------------- fallback: zero a float buffer ----------------
__global__ void zero_out(float* __restrict__ y, int n)
{
    int i = blockIdx.x * 256 + threadIdx.x;
    if (i < n) y[i] = 0.f;
}

// ------- one-time weight conversion to bf16 + split-bf16 hi/lo planes -------
__global__ void cvt_weights(const float* __restrict__ Win, const float* __restrict__ Wp,
                            const float* __restrict__ Wout,
                            unsigned short* __restrict__ Wcat,
                            unsigned short* __restrict__ Woutb,
                            unsigned short* __restrict__ hi,
                            unsigned short* __restrict__ lo)
{
    int i = blockIdx.x * 256 + threadIdx.x;        // 0 .. 5M-1
    if (i < 1048576)       Wcat[i] = f2bf(Win[i]);
    else if (i < 4194304)  Wcat[i] = f2bf(Wp[i - 1048576]);
    else if (i < 5242880)  Woutb[i - 4194304] = f2bf(Wout[i - 4194304]);
    if (i < 2097152) {
        float wv = (i < MEG_) ? Win[i] : Wout[i - MEG_];
        unsigned short h = f2bf(wv);
        hi[i] = h;
        lo[i] = f2bf(wv - bf2f(h));                // w - hi exact in fp32
    }
}

// ---------------- per-stripe u conversion ----------------
__global__ void cvt_u(const float* __restrict__ src, unsigned short* __restrict__ dst)
{
    int i = blockIdx.x * 256 + threadIdx.x;
    dst[i] = f2bf(src[i]);
}

// =====================================================================
// Split-bf16 MFMA gram: C[z] = W[z] W[z]^T  (hi.hi + hi.lo + lo.hi).
// 64x64 tile, BK=32, 4 waves 2x2 x (2x2 mfma_16x16x32). Swizzled LDS.
// =====================================================================
__global__ __launch_bounds__(256, 4) void gram_bf16x2(
    const unsigned short* __restrict__ hi, const unsigned short* __restrict__ lo,
    float* __restrict__ C, unsigned short* __restrict__ Cb)
{
    __shared__ __align__(16) unsigned short Ah[64 * 32];
    __shared__ __align__(16) unsigned short Al[64 * 32];
    __shared__ __align__(16) unsigned short Bh[64 * 32];
    __shared__ __align__(16) unsigned short Bl[64 * 32];
    const int tid = threadIdx.x;
    const int z   = blockIdx.z;
    const int m0  = blockIdx.y * 64;
    const int n0  = blockIdx.x * 64;

    const unsigned short* hz = hi + (size_t)z * MEG_;
    const unsigned short* lz = lo + (size_t)z * MEG_;

    const int lane = tid & 63;
    const int w    = tid >> 6;
    const int wm   = (w >> 1) * 32;
    const int wn   = (w & 1) * 32;
    const int lrow = lane & 15;
    const int quad = lane >> 4;
    const int srow = lane >> 2;
    const int scol = SWZ_SRC_GRAN(lane) * 8;
    const int slot = SWZ_SLOT(quad, lrow) * 8;

    const size_t arow = (size_t)(m0 + w*16 + srow) * 1024 + scol;
    const size_t brow = (size_t)(n0 + w*16 + srow) * 1024 + scol;
    unsigned short* dA = &Ah[(w*16) * 32];
    unsigned short* eA = &Al[(w*16) * 32];
    unsigned short* dB = &Bh[(w*16) * 32];
    unsigned short* eB = &Bl[(w*16) * 32];

    f4v acc[2][2];
    #pragma unroll
    for (int i = 0; i < 2; ++i)
      #pragma unroll
      for (int j = 0; j < 2; ++j) acc[i][j] = (f4v){0.f, 0.f, 0.f, 0.f};

    for (int kt = 0; kt < 1024; kt += 32) {
        __syncthreads();
        gload_lds16(hz + arow + kt, dA);
        gload_lds16(lz + arow + kt, eA);
        gload_lds16(hz + brow + kt, dB);
        gload_lds16(lz + brow + kt, eB);
        __syncthreads();

        s8v ah[2], al[2], bh[2], bl[2];
        #pragma unroll
        for (int i = 0; i < 2; ++i) {
            ah[i] = *(const s8v*)&Ah[(wm + i*16 + lrow) * 32 + slot];
            al[i] = *(const s8v*)&Al[(wm + i*16 + lrow) * 32 + slot];
        }
        #pragma unroll
        for (int j = 0; j < 2; ++j) {
            bh[j] = *(const s8v*)&Bh[(wn + j*16 + lrow) * 32 + slot];
            bl[j] = *(const s8v*)&Bl[(wn + j*16 + lrow) * 32 + slot];
        }
        #pragma unroll
        for (int i = 0; i < 2; ++i)
          #pragma unroll
          for (int j = 0; j < 2; ++j) {
              acc[i][j] = __builtin_amdgcn_mfma_f32_16x16x32_bf16(ah[i], bh[j], acc[i][j], 0, 0, 0);
              acc[i][j] = __builtin_amdgcn_mfma_f32_16x16x32_bf16(ah[i], bl[j], acc[i][j], 0, 0, 0);
              acc[i][j] = __builtin_amdgcn_mfma_f32_16x16x32_bf16(al[i], bh[j], acc[i][j], 0, 0, 0);
          }
    }

    float*          Cz  = C  + (size_t)z * MEG_;
    unsigned short* Cbz = Cb + (size_t)z * MEG_;
    #pragma unroll
    for (int i = 0; i < 2; ++i)
      #pragma unroll
      for (int j = 0; j < 2; ++j) {
        const int col = n0 + wn + j * 16 + lrow;
        #pragma unroll
        for (int r = 0; r < 4; ++r) {
            const int row = m0 + wm + i * 16 + quad * 4 + r;
            float v = acc[i][j][r];
            Cz [(size_t)row * 1024 + col] = v;
            Cbz[(size_t)row * 1024 + col] = f2bf(v);
        }
    }
}

// =====================================================================
// bf16 MFMA NT GEMM, 64x64 tile, BK=32, z-batched. OBF: bf16 output.
// mode: 0 plain, 1 scale by sptr[0]. Swizzled LDS.
// =====================================================================
template<bool OBF>
__global__ __launch_bounds__(256, 4) void gemm64_t(
    const unsigned short* __restrict__ A, const unsigned short* __restrict__ B,
    float* __restrict__ C, int K, int ldc,
    long zsA, long zsB, long zsC,
    const float* __restrict__ sptr, int mode)
{
    __shared__ __align__(16) unsigned short As[64 * 32];
    __shared__ __align__(16) unsigned short Bs[64 * 32];
    const int tid = threadIdx.x;
    const int z   = blockIdx.z;
    const int m0  = blockIdx.y * 64;
    const int n0  = blockIdx.x * 64;

    const unsigned short* Az = A + (size_t)z * zsA;
    const unsigned short* Bz = B + (size_t)z * zsB;

    const int lane = tid & 63;
    const int w    = tid >> 6;
    const int wm   = (w >> 1) * 32;
    const int wn   = (w & 1) * 32;
    const int lrow = lane & 15;
    const int quad = lane >> 4;
    const int srow = lane >> 2;
    const int scol = SWZ_SRC_GRAN(lane) * 8;
    const int slot = SWZ_SLOT(quad, lrow) * 8;

    const unsigned short* Agl = Az + (size_t)(m0 + w*16 + srow) * K + scol;
    const unsigned short* Bgl = Bz + (size_t)(n0 + w*16 + srow) * K + scol;
    unsigned short* lA = &As[(w*16) * 32];
    unsigned short* lB = &Bs[(w*16) * 32];

    f4v acc[2][2];
    #pragma unroll
    for (int i = 0; i < 2; ++i)
      #pragma unroll
      for (int j = 0; j < 2; ++j) acc[i][j] = (f4v){0.f, 0.f, 0.f, 0.f};

    for (int kt = 0; kt < K; kt += 32) {
        __syncthreads();
        gload_lds16(Agl + kt, lA);
        gload_lds16(Bgl + kt, lB);
        __syncthreads();

        s8v af[2], bf[2];
        #pragma unroll
        for (int i = 0; i < 2; ++i)
            af[i] = *(const s8v*)&As[(wm + i*16 + lrow) * 32 + slot];
        #pragma unroll
        for (int j = 0; j < 2; ++j)
            bf[j] = *(const s8v*)&Bs[(wn + j*16 + lrow) * 32 + slot];
        #pragma unroll
        for (int i = 0; i < 2; ++i)
          #pragma unroll
          for (int j = 0; j < 2; ++j)
              acc[i][j] = __builtin_amdgcn_mfma_f32_16x16x32_bf16(af[i], bf[j], acc[i][j], 0, 0, 0);
    }

    float sc = (mode == 1) ? sptr[0] : 1.0f;
    float* Cp = C + (size_t)z * zsC;

    #pragma unroll
    for (int i = 0; i < 2; ++i)
      #pragma unroll
      for (int j = 0; j < 2; ++j) {
        const int col = n0 + wn + j * 16 + lrow;
        #pragma unroll
        for (int r = 0; r < 4; ++r) {
            const int row = m0 + wm + i * 16 + quad * 4 + r;
            if (OBF)
                ((unsigned short*)Cp)[(size_t)row * ldc + col] = f2bf(acc[i][j][r] * sc);
            else
                Cp[(size_t)row * ldc + col] = acc[i][j][r] * sc;
        }
    }
}

// =====================================================================
// Pure-bf16 MFMA NT GEMM, 128x128 tile, BK=32. Dual-output split at nsplit.
// Swizzled LDS.
// =====================================================================
__global__ __launch_bounds__(256, 2) void gemm_bf16(
    const unsigned short* __restrict__ A,
    const unsigned short* __restrict__ B0, const unsigned short* __restrict__ B1,
    float* __restrict__ C0, float* __restrict__ C1,
    int K, int ldc0, int ldc1, int nsplit)
{
    __shared__ __align__(16) unsigned short As[128 * 32];
    __shared__ __align__(16) unsigned short Bs[128 * 32];
    const int tid = threadIdx.x;
    const int m0  = blockIdx.y * 128;
    const int n0g = blockIdx.x * 128;

    const unsigned short* Bsrc; float* Cp; int ldc; int c0;
    if (n0g < nsplit) {
        Bsrc = B0 + (size_t)n0g * K;
        Cp = C0; ldc = ldc0; c0 = n0g;
    } else {
        Bsrc = B1 + (size_t)(n0g - nsplit) * K;
        Cp = C1; ldc = ldc1; c0 = n0g - nsplit;
    }

    const int lane = tid & 63;
    const int w    = tid >> 6;
    const int wm   = (w >> 1) * 64;
    const int wn   = (w & 1) * 64;
    const int lrow = lane & 15;
    const int quad = lane >> 4;

    const int srow = (lane >> 2);
    const int scol = SWZ_SRC_GRAN(lane) * 8;
    const int slot = SWZ_SLOT(quad, lrow) * 8;
    const unsigned short* Agl0 = A    + (size_t)(m0 + w*32 + srow) * K + scol;
    const unsigned short* Agl1 = Agl0 + (size_t)16 * K;
    const unsigned short* Bgl0 = Bsrc + (size_t)(w*32 + srow) * K + scol;
    const unsigned short* Bgl1 = Bgl0 + (size_t)16 * K;
    unsigned short* lA0 = &As[(w*32     ) * 32];
    unsigned short* lA1 = &As[(w*32 + 16) * 32];
    unsigned short* lB0 = &Bs[(w*32     ) * 32];
    unsigned short* lB1 = &Bs[(w*32 + 16) * 32];

    f4v acc[4][4];
    #pragma unroll
    for (int i = 0; i < 4; ++i)
      #pragma unroll
      for (int j = 0; j < 4; ++j) acc[i][j] = (f4v){0.f, 0.f, 0.f, 0.f};

    for (int kt = 0; kt < K; kt += 32) {
        __syncthreads();
        gload_lds16(Agl0 + kt, lA0);
        gload_lds16(Agl1 + kt, lA1);
        gload_lds16(Bgl0 + kt, lB0);
        gload_lds16(Bgl1 + kt, lB1);
        __syncthreads();

        s8v af[4], bf[4];
        #pragma unroll
        for (int i = 0; i < 4; ++i)
            af[i] = *(const s8v*)&As[(wm + i*16 + lrow) * 32 + slot];
        #pragma unroll
        for (int j = 0; j < 4; ++j)
            bf[j] = *(const s8v*)&Bs[(wn + j*16 + lrow) * 32 + slot];
        #pragma unroll
        for (int i = 0; i < 4; ++i)
          #pragma unroll
          for (int j = 0; j < 4; ++j)
              acc[i][j] = __builtin_amdgcn_mfma_f32_16x16x32_bf16(af[i], bf[j], acc[i][j], 0, 0, 0);
    }

    #pragma unroll
    for (int i = 0; i < 4; ++i)
      #pragma unroll
      for (int j = 0; j < 4; ++j) {
        const int col = c0 + wn + j * 16 + lrow;
        #pragma unroll
        for (int r = 0; r < 4; ++r) {
            const int row = m0 + wm + i * 16 + quad * 4 + r;
            Cp[(size_t)row * ldc + col] = acc[i][j][r];
        }
    }
}

// ---- pick column with max diagonal (dominant-eigvec seed), z=blockIdx.x ----
__global__ void pick_col(const unsigned short* __restrict__ Pall, float* __restrict__ vall)
{
    const unsigned short* P = Pall + (size_t)blockIdx.x * MEG_;
    float* v = vall + blockIdx.x * N_;
    __shared__ float sval[256];
    __shared__ int   sidx[256];
    __shared__ int   jstar;
    const int tid = threadIdx.x;
    float best = -1.f; int bidx = 0;
    for (int i = tid; i < N_; i += 256) {
        float d = bf2f(P[(size_t)i * (N_ + 1)]);
        if (d > best) { best = d; bidx = i; }
    }
    sval[tid] = best; sidx[tid] = bidx; __syncthreads();
    for (int off = 128; off > 0; off >>= 1) {
        if (tid < off && sval[tid + off] > sval[tid]) {
            sval[tid] = sval[tid + off]; sidx[tid] = sidx[tid + off];
        }
        __syncthreads();
    }
    if (tid == 0) jstar = sidx[0];
    __syncthreads();
    const int j = jstar;
    for (int i = tid; i < N_; i += 256) v[i] = bf2f(P[(size_t)j * N_ + i]);
}

// ---------------- w = G[z] * v[z] (one wave per row), z=blockIdx.y ----------
__global__ __launch_bounds__(256) void matvec_z(
    const float* __restrict__ Gall, const float* __restrict__ vall,
    float* __restrict__ wall)
{
    const int z = blockIdx.y;
    const float* G = Gall + (size_t)z * MEG_;
    const float* v = vall + z * N_;
    const int row  = blockIdx.x * 4 + (threadIdx.x >> 6);
    const int lane = threadIdx.x & 63;
    const float* g = G + (size_t)row * N_;
    float s = 0.f;
    for (int j = lane; j < N_; j += 64) s += g[j] * v[j];
    #pragma unroll
    for (int off = 32; off > 0; off >>= 1) s += __shfl_down(s, off, 64);
    if (lane == 0) wall[z * N_ + row] = s;
}

// ------- Rayleigh quotient -> inv_scale[z] = 1/max(sigma,1), z=blockIdx.x ----
__global__ void rq_scale(const float* __restrict__ w1a, const float* __restrict__ w2a,
                         float* __restrict__ slot)
{
    const int z = blockIdx.x;
    const float* w1 = w1a + z * N_;
    const float* w2 = w2a + z * N_;
    __shared__ float r11[256];
    __shared__ float r12[256];
    const int tid = threadIdx.x;
    float d11 = 0.f, d12 = 0.f;
    for (int i = tid; i < N_; i += 256) {
        float a = w1[i], b = w2[i];
        d11 = fmaf(a, a, d11);
        d12 = fmaf(a, b, d12);
    }
    r11[tid] = d11; r12[tid] = d12; __syncthreads();
    for (int off = 128; off > 0; off >>= 1) {
        if (tid < off) { r11[tid] += r11[tid + off]; r12[tid] += r12[tid + off]; }
        __syncthreads();
    }
    if (tid == 0) {
        float lam = r12[0] / fmaxf(r11[0], 1e-30f);
        float sig = sqrtf(fmaxf(lam, 0.f));
        slot[z] = 1.0f / fmaxf(sig, 1.0f);
    }
}

// ---------------- fast elementwise math (hw v_exp/v_log) ----------------
__device__ __forceinline__ float fast_sp(float x)
{
    return fmaxf(x, 0.f) + __logf(1.0f + __expf(-fabsf(x)));
}
__device__ __forceinline__ float fast_tanh(float x)
{
    float e = __expf(2.0f * fabsf(x));
    float t = 1.0f - 2.0f / (e + 1.0f);
    return copysignf(t, x);
}

__device__ __forceinline__ void abc_math(
    float dr, float br, float cr, float uval,
    float alpha, float db, float sgain,
    float* pa, float* pbu, float* pc)
{
    float delta = fast_sp(dr + db);
    float a = fminf(__expf(-delta * alpha), 1.0f - 1e-4f);
    float b = fast_tanh(br);
    float c = fast_tanh(cr);
    float p = fmaf(a, a, c * c);
    float r = b * b;
    float q = a * b;
    float pr = p - r;
    float disc = fmaf(pr, pr, 4.0f * q * q);
    float lam = 0.5f * (p + r + sqrtf(disc + 1e-12f));
    float sig = sqrtf(lam + 1e-12f);
    float inv = 1.0f / fmaxf(sig, 1.0f);
    a *= inv; b *= inv; c *= inv;
    *pa = a; *pc = c; *pbu = b * (sgain * uval);
}

// --------- scan phase 1: per-chunk composite (CL=16), grid covers stripe ---
__global__ __launch_bounds__(256) void scan_phase1(
    const float* __restrict__ rawS, const float* __restrict__ usS,
    const float* __restrict__ bp, const float* __restrict__ dbias,
    const float* __restrict__ alog, const float* __restrict__ lgam,
    const float* __restrict__ inv_sin,
    float* __restrict__ agg_a, float* __restrict__ agg_b)
{
    const int gid = blockIdx.x * 256 + threadIdx.x;
    const int n   = gid & (N_ - 1);
    const int cl  = gid >> 10;

    const float alpha = fast_sp(alog[n]);
    const float db    = dbias[n];
    const float bpd   = bp[n];
    const float bpb   = bp[N_ + n];
    const float bpc   = bp[2*N_ + n];
    const float sgain = __expf(lgam[0]) * inv_sin[0];

    float Ap = 1.f, Bc = 0.f;
    size_t base  = (size_t)(cl * CL_) * K3_ + n;
    size_t ubase = (size_t)(cl * CL_) * N_  + n;
    #pragma unroll 4
    for (int j = 0; j < CL_; ++j) {
        float dr = rawS[base]        + bpd;
        float br = rawS[base + N_]   + bpb;
        float cr = rawS[base + 2*N_] + bpc;
        float uv = usS[ubase];
        float a, bu, cv;
        abc_math(dr, br, cr, uv, alpha, db, sgain, &a, &bu, &cv);
        Bc = fmaf(a, Bc, bu);
        Ap *= a;
        base += K3_; ubase += N_;
    }
    agg_a[(size_t)cl * N_ + n] = Ap;
    agg_b[(size_t)cl * N_ + n] = Bc;
}

// --------- scan phase 2 (small path): chunk-prefix with inter-stripe carry --
__global__ void scan_phase2s(const float* __restrict__ agg_a,
                             const float* __restrict__ agg_b,
                             float* __restrict__ pref, float* __restrict__ carry,
                             int bidx, int use_carry)
{
    const int n = blockIdx.x * 256 + threadIdx.x;
    float z = use_carry ? carry[bidx * N_ + n] : 0.f;
    size_t idx = n;
    for (int c = 0; c < CPS_; ++c) {
        pref[idx] = z;
        z = fmaf(agg_a[idx], z, agg_b[idx]);
        idx += N_;
    }
    carry[bidx * N_ + n] = z;
}

// --------- scan phase 2 (big path): independent per-batch chains, z0 = 0 ---
__global__ void scan_phase2b(const float* __restrict__ agg_a,
                             const float* __restrict__ agg_b,
                             float* __restrict__ pref, int cpb)
{
    const int n = blockIdx.x * 256 + threadIdx.x;
    const int chain = blockIdx.y;
    size_t idx = (size_t)chain * cpb * N_ + n;
    float z = 0.f;
    for (int c = 0; c < cpb; ++c) {
        pref[idx] = z;
        z = fmaf(agg_a[idx], z, agg_b[idx]);
        idx += N_;
    }
}

// --------- scan phase 3: replay with chunk prefix, write y_hat bf16 ---------
__global__ __launch_bounds__(256) void scan_phase3(
    const float* __restrict__ rawS, const float* __restrict__ usS,
    const float* __restrict__ bp, const float* __restrict__ dbias,
    const float* __restrict__ alog, const float* __restrict__ lgam,
    const float* __restrict__ inv_sin, const float* __restrict__ pref,
    unsigned short* __restrict__ yh)
{
    const int gid = blockIdx.x * 256 + threadIdx.x;
    const int n   = gid & (N_ - 1);
    const int cl  = gid >> 10;

    const float alpha = fast_sp(alog[n]);
    const float db    = dbias[n];
    const float bpd   = bp[n];
    const float bpb   = bp[N_ + n];
    const float bpc   = bp[2*N_ + n];
    const float sgain = __expf(lgam[0]) * inv_sin[0];

    float z = pref[(size_t)cl * N_ + n];
    size_t base  = (size_t)(cl * CL_) * K3_ + n;
    size_t ubase = (size_t)(cl * CL_) * N_  + n;
    #pragma unroll 4
    for (int j = 0; j < CL_; ++j) {
        float dr = rawS[base]        + bpd;
        float br = rawS[base + N_]   + bpb;
        float cr = rawS[base + 2*N_] + bpc;
        float uv = usS[ubase];
        float a, bu, cv;
        abc_math(dr, br, cr, uv, alpha, db, sgain, &a, &bu, &cv);
        yh[ubase] = f2bf(cv * z);
        z = fmaf(a, z, bu);
        base += K3_; ubase += N_;
    }
}

// =====================================================================
extern "C" void kernel_launch(void* const* d_in, const int* in_sizes, int n_in,
                              void* d_out, int out_size, void* d_ws, size_t ws_size,
                              hipStream_t stream)
{
    (void)in_sizes; (void)n_in;
    const float* u     = (const float*)d_in[0];
    const float* W_in  = (const float*)d_in[1];
    const float* W_out = (const float*)d_in[2];
    const float* Wp    = (const float*)d_in[3];
    const float* bp    = (const float*)d_in[4];
    const float* alog  = (const float*)d_in[5];
    const float* dbias = (const float*)d_in[6];
    const float* lgam  = (const float*)d_in[7];
    float* y = (float*)d_out;

    if (ws_size < (size_t)REQ_FLOATS * sizeof(float)) {
        zero_out<<<(out_size + 255) / 256, dim3(256), 0, stream>>>(y, out_size);
        return;
    }
    const bool big = ws_size >= (size_t)BREQ_FLOATS * sizeof(float);

    float* ws = (float*)d_ws;
    float*          rawS  = ws + (big ? BOFF_RAWS  : OFF_RAWS);
    float*          usS   = ws + (big ? BOFF_USS   : OFF_USS);
    unsigned short* ubf   = (unsigned short*)(ws + (big ? BOFF_UBF   : OFF_UBF));
    unsigned short* Wcat  = (unsigned short*)(ws + (big ? BOFF_WCAT  : OFF_WCAT));
    unsigned short* Woutb = (unsigned short*)(ws + (big ? BOFF_WOUTB : OFF_WOUTB));
    float* agg_a = ws + (big ? BOFF_AGA  : OFF_AGA);
    float* agg_b = ws + (big ? BOFF_AGB  : OFF_AGB);
    float* pref  = ws + (big ? BOFF_PRE  : OFF_PRE);
    float* carry = ws + OFF_CARRY;                       // small path only
    float* v0    = ws + (big ? BOFF_V0   : OFF_V0);
    float* w1    = ws + (big ? BOFF_W1   : OFF_W1);
    float* w2    = ws + (big ? BOFF_W2   : OFF_W2);
    float* scal  = ws + (big ? BOFF_SCAL : OFF_SCAL);
    // sigma-phase aliases (live only before stripe processing)
    float*          G0   = rawS;                               // 2 x 1M f
    unsigned short* hiW  = (unsigned short*)(rawS + 2*MEG_);   // 2 x 1M shorts
    unsigned short* loW  = (unsigned short*)(rawS + 3*MEG_);   // 2 x 1M shorts
    unsigned short* SbfA = (unsigned short*)usS;               // 2 x 1M shorts
    unsigned short* SbfB = SbfA + 2*MEG_;                      // 2 x 1M shorts

    const dim3 blk(256);

    cvt_weights<<<20480, blk, 0, stream>>>(W_in, Wp, W_out, Wcat, Woutb, hiW, loW);

    // ---- spectral norms: split-bf16 MFMA gram (z=2), 6 bf16 squarings,
    //      fp32 Rayleigh quotient on the MFMA-accurate G0. ----
    gram_bf16x2<<<dim3(16, 16, 2), blk, 0, stream>>>(hiW, loW, G0, SbfA);
    unsigned short* Sc = SbfA;
    unsigned short* Sn = SbfB;
    for (int r = 0; r < 6; ++r) {
        gemm64_t<true><<<dim3(16, 16, 2), blk, 0, stream>>>(
            Sc, Sc, (float*)Sn, 1024, 1024, MEG_, MEG_, MEG_ / 2, nullptr, 0);
        unsigned short* t = Sc; Sc = Sn; Sn = t;
    }
    pick_col<<<2, blk, 0, stream>>>(Sc, v0);
    matvec_z<<<dim3(256, 2), blk, 0, stream>>>(G0, v0, w1);
    matvec_z<<<dim3(256, 2), blk, 0, stream>>>(G0, w1, w2);
    rq_scale<<<2, blk, 0, stream>>>(w1, w2, scal);   // scal[0]=inv_in, scal[1]=inv_out

    if (big) {
        // ---- 2 stripes of 8192 rows (2 whole batches each, no carry) ----
        for (int s = 0; s < BNSTRIPE_; ++s) {
            const int r0 = s * BSROWS_;
            cvt_u<<<32768, blk, 0, stream>>>(u + (size_t)r0 * DD_, ubf);
            gemm_bf16<<<dim3(32, 64), blk, 0, stream>>>(
                ubf, Wcat, Wcat + (size_t)1024 * 1024, usS, rawS,
                1024, N_, K3_, 1024);
            scan_phase1<<<2048, blk, 0, stream>>>(rawS, usS, bp, dbias, alog,
                                                  lgam, scal, agg_a, agg_b);
            scan_phase2b<<<dim3(4, 2), blk, 0, stream>>>(agg_a, agg_b, pref, BCPB_);
            scan_phase3<<<2048, blk, 0, stream>>>(rawS, usS, bp, dbias, alog,
                                                  lgam, scal, pref, ubf);
            gemm64_t<false><<<dim3(16, 128, 1), blk, 0, stream>>>(
                ubf, Woutb, y + (size_t)r0 * N_, 1024, 1024,
                0, 0, 0, scal + 1, 1);
        }
    } else {
        // ---- 8 stripes of 2048 rows with sequential carry (round-2 path) ----
        for (int s = 0; s < NSTRIPE_; ++s) {
            const int r0 = s * SROWS_;
            cvt_u<<<8192, blk, 0, stream>>>(u + (size_t)r0 * DD_, ubf);
            gemm_bf16<<<dim3(32, 16), blk, 0, stream>>>(
                ubf, Wcat, Wcat + (size_t)1024 * 1024, usS, rawS,
                1024, N_, K3_, 1024);
            scan_phase1<<<512, blk, 0, stream>>>(rawS, usS, bp, dbias, alog,
                                                 lgam, scal, agg_a, agg_b);
            scan_phase2s<<<4, blk, 0, stream>>>(agg_a, agg_b, pref, carry,
                                                s >> 1, s & 1);
            scan_phase3<<<512, blk, 0, stream>>>(rawS, usS, bp, dbias, alog,
                                                 lgam, scal, pref, ubf);
            gemm64_t<false><<<dim3(16, 32, 1), blk, 0, stream>>>(
                ubf, Woutb, y + (size_t)r0 * N_, 1024, 1024,
                0, 0, 0, scal + 1, 1);
        }
    }
}

// Round 8
// 784.519 us; speedup vs baseline: 1.4631x; 1.0198x over previous
//
#include <hip/hip_runtime.h>

// ---------------- problem dims (fixed by setup_inputs) ----------------
#define B_    4
#define T_    4096
#define DD_   1024
#define N_    1024
#define K3_   3072
#define M_    16384      // B_*T_
#define CL_   16         // scan chunk length (time steps)
#define MEG_  1048576

// ---------------- small-path ws layout (floats, ~48 MiB) ----------------
#define SROWS_ 2048
#define NSTRIPE_ (M_/SROWS_)     // 8
#define CPS_  (SROWS_/CL_)       // 128 chunks per stripe
#define OFF_RAWS  ((size_t)0)                        // 6M f
#define OFF_USS   ((size_t)6*MEG_)                   // 2M f
#define OFF_UBF   ((size_t)8*MEG_)                   // 1M f (2M shorts)
#define OFF_WCAT  ((size_t)9*MEG_)                   // 2M f (4M shorts)
#define OFF_WOUTB ((size_t)11*MEG_)                  // 512K f
#define OFF_AGA   (OFF_WOUTB + 524288)               // 128K f
#define OFF_AGB   (OFF_AGA + 131072)
#define OFF_PRE   (OFF_AGB + 131072)
#define OFF_CARRY (OFF_PRE + 131072)                 // 4096 f
#define OFF_V0    (OFF_CARRY + 4096)
#define OFF_W1    (OFF_V0 + 2048)
#define OFF_W2    (OFF_W1 + 2048)
#define OFF_SCAL  (OFF_W2 + 2048)
#define REQ_FLOATS (OFF_SCAL + 16)

// ---------------- big-path ws layout (floats, ~160 MiB) ----------------
// Stripe = 8192 rows = 2 whole batches -> no inter-stripe carry.
#define BSROWS_  8192
#define BNSTRIPE_ 2
#define BCPS_    (BSROWS_/CL_)     // 512 chunks per stripe
#define BCPB_    (T_/CL_)          // 256 chunks per batch chain
#define BOFF_RAWS  ((size_t)0)                       // 24M f (96 MiB)
#define BOFF_USS   ((size_t)24*MEG_)                 // 8M f  (32 MiB)
#define BOFF_UBF   ((size_t)32*MEG_)                 // 4M f  (8M shorts)
#define BOFF_WCAT  ((size_t)36*MEG_)                 // 2M f  (4M shorts)
#define BOFF_WOUTB ((size_t)38*MEG_)                 // 512K f
#define BOFF_AGA   (BOFF_WOUTB + 524288)             // 512K f
#define BOFF_AGB   (BOFF_AGA + 524288)
#define BOFF_PRE   (BOFF_AGB + 524288)               // 512K f
#define BOFF_V0    (BOFF_PRE + 524288)
#define BOFF_W1    (BOFF_V0 + 2048)
#define BOFF_W2    (BOFF_W1 + 2048)
#define BOFF_SCAL  (BOFF_W2 + 2048)
#define BREQ_FLOATS (BOFF_SCAL + 16)

typedef short s8v __attribute__((ext_vector_type(8)));   // 8 bf16 (4 VGPRs)
typedef float f4v __attribute__((ext_vector_type(4)));   // MFMA acc

typedef __attribute__((address_space(3))) unsigned int       lds_u32;
typedef const __attribute__((address_space(1))) unsigned int glb_u32;

__device__ __forceinline__ void gload_lds16(const void* g, void* l)
{
    __builtin_amdgcn_global_load_lds((glb_u32*)g, (lds_u32*)l, 16, 0, 0);
}

// fp32 -> bf16 round-to-nearest-even
__device__ __forceinline__ unsigned short f2bf(float f)
{
    unsigned u = __float_as_uint(f);
    u += 0x7FFFu + ((u >> 16) & 1u);
    return (unsigned short)(u >> 16);
}
__device__ __forceinline__ float bf2f(unsigned short h)
{
    return __uint_as_float((unsigned)h << 16);
}

// ---- BK=64 LDS swizzle (rows = 64 bf16 = 128 B = 8 granules of 16 B).
// bank = (slot*16)/4 % 32 depends ONLY on slot, so each 8-lane group needs
// 8 distinct slots: physical slot of logical granule g in row r = g ^ (r&7).
// Stage (rule #21): gload dest is lane-linear (slot = lane&7, row += lane>>3),
// so lane sources logical granule (lane&7) ^ (lane>>3). Bit-identical data.
#define SWZ64_SRC_GRAN(lane)  (((lane) & 7) ^ ((lane) >> 3))
#define SWZ64_SLOT(kk,quad,lrow) ((((kk)*4 + (quad)) ^ ((lrow) & 7)) * 8)

// ---- BK=32 swizzle (64 B rows, 4 granules) — used by gram only.
#define SWZ_SRC_GRAN(lane)  (((lane) & 3) ^ (((lane) >> 3) & 3))
#define SWZ_SLOT(quad,lrow) ((quad) ^ (((lrow) >> 1) & 3))

// ---------------- fallback: zero a float buffer ----------------
__global__ void zero_out(float* __restrict__ y, int n)
{
    int i = blockIdx.x * 256 + threadIdx.x;
    if (i < n) y[i] = 0.f;
}

// ------- one-time weight conversion to bf16 + split-bf16 hi/lo planes -------
__global__ void cvt_weights(const float* __restrict__ Win, const float* __restrict__ Wp,
                            const float* __restrict__ Wout,
                            unsigned short* __restrict__ Wcat,
                            unsigned short* __restrict__ Woutb,
                            unsigned short* __restrict__ hi,
                            unsigned short* __restrict__ lo)
{
    int i = blockIdx.x * 256 + threadIdx.x;        // 0 .. 5M-1
    if (i < 1048576)       Wcat[i] = f2bf(Win[i]);
    else if (i < 4194304)  Wcat[i] = f2bf(Wp[i - 1048576]);
    else if (i < 5242880)  Woutb[i - 4194304] = f2bf(Wout[i - 4194304]);
    if (i < 2097152) {
        float wv = (i < MEG_) ? Win[i] : Wout[i - MEG_];
        unsigned short h = f2bf(wv);
        hi[i] = h;
        lo[i] = f2bf(wv - bf2f(h));                // w - hi exact in fp32
    }
}

// ---------------- per-stripe u conversion ----------------
__global__ void cvt_u(const float* __restrict__ src, unsigned short* __restrict__ dst)
{
    int i = blockIdx.x * 256 + threadIdx.x;
    dst[i] = f2bf(src[i]);
}

// =====================================================================
// Split-bf16 MFMA gram: C[z] = W[z] W[z]^T  (hi.hi + hi.lo + lo.hi).
// 64x64 tile, BK=32, 4 waves 2x2 x (2x2 mfma_16x16x32). Swizzled LDS.
// =====================================================================
__global__ __launch_bounds__(256, 4) void gram_bf16x2(
    const unsigned short* __restrict__ hi, const unsigned short* __restrict__ lo,
    float* __restrict__ C, unsigned short* __restrict__ Cb)
{
    __shared__ __align__(16) unsigned short Ah[64 * 32];
    __shared__ __align__(16) unsigned short Al[64 * 32];
    __shared__ __align__(16) unsigned short Bh[64 * 32];
    __shared__ __align__(16) unsigned short Bl[64 * 32];
    const int tid = threadIdx.x;
    const int z   = blockIdx.z;
    const int m0  = blockIdx.y * 64;
    const int n0  = blockIdx.x * 64;

    const unsigned short* hz = hi + (size_t)z * MEG_;
    const unsigned short* lz = lo + (size_t)z * MEG_;

    const int lane = tid & 63;
    const int w    = tid >> 6;
    const int wm   = (w >> 1) * 32;
    const int wn   = (w & 1) * 32;
    const int lrow = lane & 15;
    const int quad = lane >> 4;
    const int srow = lane >> 2;
    const int scol = SWZ_SRC_GRAN(lane) * 8;
    const int slot = SWZ_SLOT(quad, lrow) * 8;

    const size_t arow = (size_t)(m0 + w*16 + srow) * 1024 + scol;
    const size_t brow = (size_t)(n0 + w*16 + srow) * 1024 + scol;
    unsigned short* dA = &Ah[(w*16) * 32];
    unsigned short* eA = &Al[(w*16) * 32];
    unsigned short* dB = &Bh[(w*16) * 32];
    unsigned short* eB = &Bl[(w*16) * 32];

    f4v acc[2][2];
    #pragma unroll
    for (int i = 0; i < 2; ++i)
      #pragma unroll
      for (int j = 0; j < 2; ++j) acc[i][j] = (f4v){0.f, 0.f, 0.f, 0.f};

    for (int kt = 0; kt < 1024; kt += 32) {
        __syncthreads();
        gload_lds16(hz + arow + kt, dA);
        gload_lds16(lz + arow + kt, eA);
        gload_lds16(hz + brow + kt, dB);
        gload_lds16(lz + brow + kt, eB);
        __syncthreads();

        s8v ah[2], al[2], bh[2], bl[2];
        #pragma unroll
        for (int i = 0; i < 2; ++i) {
            ah[i] = *(const s8v*)&Ah[(wm + i*16 + lrow) * 32 + slot];
            al[i] = *(const s8v*)&Al[(wm + i*16 + lrow) * 32 + slot];
        }
        #pragma unroll
        for (int j = 0; j < 2; ++j) {
            bh[j] = *(const s8v*)&Bh[(wn + j*16 + lrow) * 32 + slot];
            bl[j] = *(const s8v*)&Bl[(wn + j*16 + lrow) * 32 + slot];
        }
        #pragma unroll
        for (int i = 0; i < 2; ++i)
          #pragma unroll
          for (int j = 0; j < 2; ++j) {
              acc[i][j] = __builtin_amdgcn_mfma_f32_16x16x32_bf16(ah[i], bh[j], acc[i][j], 0, 0, 0);
              acc[i][j] = __builtin_amdgcn_mfma_f32_16x16x32_bf16(ah[i], bl[j], acc[i][j], 0, 0, 0);
              acc[i][j] = __builtin_amdgcn_mfma_f32_16x16x32_bf16(al[i], bh[j], acc[i][j], 0, 0, 0);
          }
    }

    float*          Cz  = C  + (size_t)z * MEG_;
    unsigned short* Cbz = Cb + (size_t)z * MEG_;
    #pragma unroll
    for (int i = 0; i < 2; ++i)
      #pragma unroll
      for (int j = 0; j < 2; ++j) {
        const int col = n0 + wn + j * 16 + lrow;
        #pragma unroll
        for (int r = 0; r < 4; ++r) {
            const int row = m0 + wm + i * 16 + quad * 4 + r;
            float v = acc[i][j][r];
            Cz [(size_t)row * 1024 + col] = v;
            Cbz[(size_t)row * 1024 + col] = f2bf(v);
        }
    }
}

// =====================================================================
// bf16 MFMA NT GEMM, 64x64 tile, BK=64 (half the barrier drains, 8 MFMA
// per wave per K-step), z-batched. OBF: bf16 output. Swizzled LDS (BK64).
// mode: 0 plain, 1 scale by sptr[0]. K must be a multiple of 64.
// =====================================================================
template<bool OBF>
__global__ __launch_bounds__(256, 4) void gemm64_t(
    const unsigned short* __restrict__ A, const unsigned short* __restrict__ B,
    float* __restrict__ C, int K, int ldc,
    long zsA, long zsB, long zsC,
    const float* __restrict__ sptr, int mode)
{
    __shared__ __align__(16) unsigned short As[64 * 64];   // 8 KiB
    __shared__ __align__(16) unsigned short Bs[64 * 64];   // 8 KiB
    const int tid = threadIdx.x;
    const int z   = blockIdx.z;
    const int m0  = blockIdx.y * 64;
    const int n0  = blockIdx.x * 64;

    const unsigned short* Az = A + (size_t)z * zsA;
    const unsigned short* Bz = B + (size_t)z * zsB;

    const int lane = tid & 63;
    const int w    = tid >> 6;
    const int wm   = (w >> 1) * 32;
    const int wn   = (w & 1) * 32;
    const int lrow = lane & 15;
    const int quad = lane >> 4;
    const int srow8 = lane >> 3;                 // 0..7 (8 rows per gload)
    const int scol  = SWZ64_SRC_GRAN(lane) * 8;  // source granule column

    // wave w stages tile rows [w*16, w*16+16): 2 gloads of 8 rows each
    const unsigned short* Agl = Az + (size_t)(m0 + w*16 + srow8) * K + scol;
    const unsigned short* Bgl = Bz + (size_t)(n0 + w*16 + srow8) * K + scol;
    unsigned short* lA = &As[(w*16) * 64];
    unsigned short* lB = &Bs[(w*16) * 64];

    f4v acc[2][2];
    #pragma unroll
    for (int i = 0; i < 2; ++i)
      #pragma unroll
      for (int j = 0; j < 2; ++j) acc[i][j] = (f4v){0.f, 0.f, 0.f, 0.f};

    for (int kt = 0; kt < K; kt += 64) {
        __syncthreads();
        gload_lds16(Agl + kt,                lA);
        gload_lds16(Agl + (size_t)8*K + kt,  lA + 8*64);
        gload_lds16(Bgl + kt,                lB);
        gload_lds16(Bgl + (size_t)8*K + kt,  lB + 8*64);
        __syncthreads();

        #pragma unroll
        for (int kk = 0; kk < 2; ++kk) {
            const int slot = SWZ64_SLOT(kk, quad, lrow);
            s8v af[2], bf[2];
            #pragma unroll
            for (int i = 0; i < 2; ++i)
                af[i] = *(const s8v*)&As[(wm + i*16 + lrow) * 64 + slot];
            #pragma unroll
            for (int j = 0; j < 2; ++j)
                bf[j] = *(const s8v*)&Bs[(wn + j*16 + lrow) * 64 + slot];
            #pragma unroll
            for (int i = 0; i < 2; ++i)
              #pragma unroll
              for (int j = 0; j < 2; ++j)
                  acc[i][j] = __builtin_amdgcn_mfma_f32_16x16x32_bf16(af[i], bf[j], acc[i][j], 0, 0, 0);
        }
    }

    float sc = (mode == 1) ? sptr[0] : 1.0f;
    float* Cp = C + (size_t)z * zsC;

    #pragma unroll
    for (int i = 0; i < 2; ++i)
      #pragma unroll
      for (int j = 0; j < 2; ++j) {
        const int col = n0 + wn + j * 16 + lrow;
        #pragma unroll
        for (int r = 0; r < 4; ++r) {
            const int row = m0 + wm + i * 16 + quad * 4 + r;
            if (OBF)
                ((unsigned short*)Cp)[(size_t)row * ldc + col] = f2bf(acc[i][j][r] * sc);
            else
                Cp[(size_t)row * ldc + col] = acc[i][j][r] * sc;
        }
    }
}

// =====================================================================
// Pure-bf16 MFMA NT GEMM, 128x128 tile, BK=64 (32 MFMA per wave per
// K-step). Dual-output split at nsplit. Swizzled LDS (BK64).
// K must be a multiple of 64.
// =====================================================================
__global__ __launch_bounds__(256, 2) void gemm_bf16(
    const unsigned short* __restrict__ A,
    const unsigned short* __restrict__ B0, const unsigned short* __restrict__ B1,
    float* __restrict__ C0, float* __restrict__ C1,
    int K, int ldc0, int ldc1, int nsplit)
{
    __shared__ __align__(16) unsigned short As[128 * 64];  // 16 KiB
    __shared__ __align__(16) unsigned short Bs[128 * 64];  // 16 KiB
    const int tid = threadIdx.x;
    const int m0  = blockIdx.y * 128;
    const int n0g = blockIdx.x * 128;

    const unsigned short* Bsrc; float* Cp; int ldc; int c0;
    if (n0g < nsplit) {
        Bsrc = B0 + (size_t)n0g * K;
        Cp = C0; ldc = ldc0; c0 = n0g;
    } else {
        Bsrc = B1 + (size_t)(n0g - nsplit) * K;
        Cp = C1; ldc = ldc1; c0 = n0g - nsplit;
    }

    const int lane = tid & 63;
    const int w    = tid >> 6;
    const int wm   = (w >> 1) * 64;
    const int wn   = (w & 1) * 64;
    const int lrow = lane & 15;
    const int quad = lane >> 4;
    const int srow8 = lane >> 3;
    const int scol  = SWZ64_SRC_GRAN(lane) * 8;

    // wave w stages tile rows [w*32, w*32+32): 4 gloads of 8 rows each
    const unsigned short* Agl = A    + (size_t)(m0 + w*32 + srow8) * K + scol;
    const unsigned short* Bgl = Bsrc + (size_t)(w*32 + srow8) * K + scol;
    unsigned short* lA = &As[(w*32) * 64];
    unsigned short* lB = &Bs[(w*32) * 64];

    f4v acc[4][4];
    #pragma unroll
    for (int i = 0; i < 4; ++i)
      #pragma unroll
      for (int j = 0; j < 4; ++j) acc[i][j] = (f4v){0.f, 0.f, 0.f, 0.f};

    for (int kt = 0; kt < K; kt += 64) {
        __syncthreads();
        #pragma unroll
        for (int q8 = 0; q8 < 4; ++q8) {
            gload_lds16(Agl + (size_t)(q8*8)*K + kt, lA + (q8*8)*64);
            gload_lds16(Bgl + (size_t)(q8*8)*K + kt, lB + (q8*8)*64);
        }
        __syncthreads();

        #pragma unroll
        for (int kk = 0; kk < 2; ++kk) {
            const int slot = SWZ64_SLOT(kk, quad, lrow);
            s8v af[4], bf[4];
            #pragma unroll
            for (int i = 0; i < 4; ++i)
                af[i] = *(const s8v*)&As[(wm + i*16 + lrow) * 64 + slot];
            #pragma unroll
            for (int j = 0; j < 4; ++j)
                bf[j] = *(const s8v*)&Bs[(wn + j*16 + lrow) * 64 + slot];
            #pragma unroll
            for (int i = 0; i < 4; ++i)
              #pragma unroll
              for (int j = 0; j < 4; ++j)
                  acc[i][j] = __builtin_amdgcn_mfma_f32_16x16x32_bf16(af[i], bf[j], acc[i][j], 0, 0, 0);
        }
    }

    #pragma unroll
    for (int i = 0; i < 4; ++i)
      #pragma unroll
      for (int j = 0; j < 4; ++j) {
        const int col = c0 + wn + j * 16 + lrow;
        #pragma unroll
        for (int r = 0; r < 4; ++r) {
            const int row = m0 + wm + i * 16 + quad * 4 + r;
            Cp[(size_t)row * ldc + col] = acc[i][j][r];
        }
    }
}

// ---- pick column with max diagonal (dominant-eigvec seed), z=blockIdx.x ----
__global__ void pick_col(const unsigned short* __restrict__ Pall, float* __restrict__ vall)
{
    const unsigned short* P = Pall + (size_t)blockIdx.x * MEG_;
    float* v = vall + blockIdx.x * N_;
    __shared__ float sval[256];
    __shared__ int   sidx[256];
    __shared__ int   jstar;
    const int tid = threadIdx.x;
    float best = -1.f; int bidx = 0;
    for (int i = tid; i < N_; i += 256) {
        float d = bf2f(P[(size_t)i * (N_ + 1)]);
        if (d > best) { best = d; bidx = i; }
    }
    sval[tid] = best; sidx[tid] = bidx; __syncthreads();
    for (int off = 128; off > 0; off >>= 1) {
        if (tid < off && sval[tid + off] > sval[tid]) {
            sval[tid] = sval[tid + off]; sidx[tid] = sidx[tid + off];
        }
        __syncthreads();
    }
    if (tid == 0) jstar = sidx[0];
    __syncthreads();
    const int j = jstar;
    for (int i = tid; i < N_; i += 256) v[i] = bf2f(P[(size_t)j * N_ + i]);
}

// ---------------- w = G[z] * v[z] (one wave per row), z=blockIdx.y ----------
__global__ __launch_bounds__(256) void matvec_z(
    const float* __restrict__ Gall, const float* __restrict__ vall,
    float* __restrict__ wall)
{
    const int z = blockIdx.y;
    const float* G = Gall + (size_t)z * MEG_;
    const float* v = vall + z * N_;
    const int row  = blockIdx.x * 4 + (threadIdx.x >> 6);
    const int lane = threadIdx.x & 63;
    const float* g = G + (size_t)row * N_;
    float s = 0.f;
    for (int j = lane; j < N_; j += 64) s += g[j] * v[j];
    #pragma unroll
    for (int off = 32; off > 0; off >>= 1) s += __shfl_down(s, off, 64);
    if (lane == 0) wall[z * N_ + row] = s;
}

// ------- Rayleigh quotient -> inv_scale[z] = 1/max(sigma,1), z=blockIdx.x ----
__global__ void rq_scale(const float* __restrict__ w1a, const float* __restrict__ w2a,
                         float* __restrict__ slot)
{
    const int z = blockIdx.x;
    const float* w1 = w1a + z * N_;
    const float* w2 = w2a + z * N_;
    __shared__ float r11[256];
    __shared__ float r12[256];
    const int tid = threadIdx.x;
    float d11 = 0.f, d12 = 0.f;
    for (int i = tid; i < N_; i += 256) {
        float a = w1[i], b = w2[i];
        d11 = fmaf(a, a, d11);
        d12 = fmaf(a, b, d12);
    }
    r11[tid] = d11; r12[tid] = d12; __syncthreads();
    for (int off = 128; off > 0; off >>= 1) {
        if (tid < off) { r11[tid] += r11[tid + off]; r12[tid] += r12[tid + off]; }
        __syncthreads();
    }
    if (tid == 0) {
        float lam = r12[0] / fmaxf(r11[0], 1e-30f);
        float sig = sqrtf(fmaxf(lam, 0.f));
        slot[z] = 1.0f / fmaxf(sig, 1.0f);
    }
}

// ---------------- fast elementwise math (hw v_exp/v_log) ----------------
__device__ __forceinline__ float fast_sp(float x)
{
    return fmaxf(x, 0.f) + __logf(1.0f + __expf(-fabsf(x)));
}
__device__ __forceinline__ float fast_tanh(float x)
{
    float e = __expf(2.0f * fabsf(x));
    float t = 1.0f - 2.0f / (e + 1.0f);
    return copysignf(t, x);
}

__device__ __forceinline__ void abc_math(
    float dr, float br, float cr, float uval,
    float alpha, float db, float sgain,
    float* pa, float* pbu, float* pc)
{
    float delta = fast_sp(dr + db);
    float a = fminf(__expf(-delta * alpha), 1.0f - 1e-4f);
    float b = fast_tanh(br);
    float c = fast_tanh(cr);
    float p = fmaf(a, a, c * c);
    float r = b * b;
    float q = a * b;
    float pr = p - r;
    float disc = fmaf(pr, pr, 4.0f * q * q);
    float lam = 0.5f * (p + r + sqrtf(disc + 1e-12f));
    float sig = sqrtf(lam + 1e-12f);
    float inv = 1.0f / fmaxf(sig, 1.0f);
    a *= inv; b *= inv; c *= inv;
    *pa = a; *pc = c; *pbu = b * (sgain * uval);
}

// --------- scan phase 1: per-chunk composite (CL=16), grid covers stripe ---
__global__ __launch_bounds__(256) void scan_phase1(
    const float* __restrict__ rawS, const float* __restrict__ usS,
    const float* __restrict__ bp, const float* __restrict__ dbias,
    const float* __restrict__ alog, const float* __restrict__ lgam,
    const float* __restrict__ inv_sin,
    float* __restrict__ agg_a, float* __restrict__ agg_b)
{
    const int gid = blockIdx.x * 256 + threadIdx.x;
    const int n   = gid & (N_ - 1);
    const int cl  = gid >> 10;

    const float alpha = fast_sp(alog[n]);
    const float db    = dbias[n];
    const float bpd   = bp[n];
    const float bpb   = bp[N_ + n];
    const float bpc   = bp[2*N_ + n];
    const float sgain = __expf(lgam[0]) * inv_sin[0];

    float Ap = 1.f, Bc = 0.f;
    size_t base  = (size_t)(cl * CL_) * K3_ + n;
    size_t ubase = (size_t)(cl * CL_) * N_  + n;
    #pragma unroll 4
    for (int j = 0; j < CL_; ++j) {
        float dr = rawS[base]        + bpd;
        float br = rawS[base + N_]   + bpb;
        float cr = rawS[base + 2*N_] + bpc;
        float uv = usS[ubase];
        float a, bu, cv;
        abc_math(dr, br, cr, uv, alpha, db, sgain, &a, &bu, &cv);
        Bc = fmaf(a, Bc, bu);
        Ap *= a;
        base += K3_; ubase += N_;
    }
    agg_a[(size_t)cl * N_ + n] = Ap;
    agg_b[(size_t)cl * N_ + n] = Bc;
}

// --------- scan phase 2 (small path): chunk-prefix with inter-stripe carry --
__global__ void scan_phase2s(const float* __restrict__ agg_a,
                             const float* __restrict__ agg_b,
                             float* __restrict__ pref, float* __restrict__ carry,
                             int bidx, int use_carry)
{
    const int n = blockIdx.x * 256 + threadIdx.x;
    float z = use_carry ? carry[bidx * N_ + n] : 0.f;
    size_t idx = n;
    for (int c = 0; c < CPS_; ++c) {
        pref[idx] = z;
        z = fmaf(agg_a[idx], z, agg_b[idx]);
        idx += N_;
    }
    carry[bidx * N_ + n] = z;
}

// --------- scan phase 2 (big path): independent per-batch chains, z0 = 0 ---
__global__ void scan_phase2b(const float* __restrict__ agg_a,
                             const float* __restrict__ agg_b,
                             float* __restrict__ pref, int cpb)
{
    const int n = blockIdx.x * 256 + threadIdx.x;
    const int chain = blockIdx.y;
    size_t idx = (size_t)chain * cpb * N_ + n;
    float z = 0.f;
    for (int c = 0; c < cpb; ++c) {
        pref[idx] = z;
        z = fmaf(agg_a[idx], z, agg_b[idx]);
        idx += N_;
    }
}

// --------- scan phase 3: replay with chunk prefix, write y_hat bf16 ---------
__global__ __launch_bounds__(256) void scan_phase3(
    const float* __restrict__ rawS, const float* __restrict__ usS,
    const float* __restrict__ bp, const float* __restrict__ dbias,
    const float* __restrict__ alog, const float* __restrict__ lgam,
    const float* __restrict__ inv_sin, const float* __restrict__ pref,
    unsigned short* __restrict__ yh)
{
    const int gid = blockIdx.x * 256 + threadIdx.x;
    const int n   = gid & (N_ - 1);
    const int cl  = gid >> 10;

    const float alpha = fast_sp(alog[n]);
    const float db    = dbias[n];
    const float bpd   = bp[n];
    const float bpb   = bp[N_ + n];
    const float bpc   = bp[2*N_ + n];
    const float sgain = __expf(lgam[0]) * inv_sin[0];

    float z = pref[(size_t)cl * N_ + n];
    size_t base  = (size_t)(cl * CL_) * K3_ + n;
    size_t ubase = (size_t)(cl * CL_) * N_  + n;
    #pragma unroll 4
    for (int j = 0; j < CL_; ++j) {
        float dr = rawS[base]        + bpd;
        float br = rawS[base + N_]   + bpb;
        float cr = rawS[base + 2*N_] + bpc;
        float uv = usS[ubase];
        float a, bu, cv;
        abc_math(dr, br, cr, uv, alpha, db, sgain, &a, &bu, &cv);
        yh[ubase] = f2bf(cv * z);
        z = fmaf(a, z, bu);
        base += K3_; ubase += N_;
    }
}

// =====================================================================
extern "C" void kernel_launch(void* const* d_in, const int* in_sizes, int n_in,
                              void* d_out, int out_size, void* d_ws, size_t ws_size,
                              hipStream_t stream)
{
    (void)in_sizes; (void)n_in;
    const float* u     = (const float*)d_in[0];
    const float* W_in  = (const float*)d_in[1];
    const float* W_out = (const float*)d_in[2];
    const float* Wp    = (const float*)d_in[3];
    const float* bp    = (const float*)d_in[4];
    const float* alog  = (const float*)d_in[5];
    const float* dbias = (const float*)d_in[6];
    const float* lgam  = (const float*)d_in[7];
    float* y = (float*)d_out;

    if (ws_size < (size_t)REQ_FLOATS * sizeof(float)) {
        zero_out<<<(out_size + 255) / 256, dim3(256), 0, stream>>>(y, out_size);
        return;
    }
    const bool big = ws_size >= (size_t)BREQ_FLOATS * sizeof(float);

    float* ws = (float*)d_ws;
    float*          rawS  = ws + (big ? BOFF_RAWS  : OFF_RAWS);
    float*          usS   = ws + (big ? BOFF_USS   : OFF_USS);
    unsigned short* ubf   = (unsigned short*)(ws + (big ? BOFF_UBF   : OFF_UBF));
    unsigned short* Wcat  = (unsigned short*)(ws + (big ? BOFF_WCAT  : OFF_WCAT));
    unsigned short* Woutb = (unsigned short*)(ws + (big ? BOFF_WOUTB : OFF_WOUTB));
    float* agg_a = ws + (big ? BOFF_AGA  : OFF_AGA);
    float* agg_b = ws + (big ? BOFF_AGB  : OFF_AGB);
    float* pref  = ws + (big ? BOFF_PRE  : OFF_PRE);
    float* carry = ws + OFF_CARRY;                       // small path only
    float* v0    = ws + (big ? BOFF_V0   : OFF_V0);
    float* w1    = ws + (big ? BOFF_W1   : OFF_W1);
    float* w2    = ws + (big ? BOFF_W2   : OFF_W2);
    float* scal  = ws + (big ? BOFF_SCAL : OFF_SCAL);
    // sigma-phase aliases (live only before stripe processing)
    float*          G0   = rawS;                               // 2 x 1M f
    unsigned short* hiW  = (unsigned short*)(rawS + 2*MEG_);   // 2 x 1M shorts
    unsigned short* loW  = (unsigned short*)(rawS + 3*MEG_);   // 2 x 1M shorts
    unsigned short* SbfA = (unsigned short*)usS;               // 2 x 1M shorts
    unsigned short* SbfB = SbfA + 2*MEG_;                      // 2 x 1M shorts

    const dim3 blk(256);

    cvt_weights<<<20480, blk, 0, stream>>>(W_in, Wp, W_out, Wcat, Woutb, hiW, loW);

    // ---- spectral norms: split-bf16 MFMA gram (z=2), 6 bf16 squarings,
    //      fp32 Rayleigh quotient on the MFMA-accurate G0. ----
    gram_bf16x2<<<dim3(16, 16, 2), blk, 0, stream>>>(hiW, loW, G0, SbfA);
    unsigned short* Sc = SbfA;
    unsigned short* Sn = SbfB;
    for (int r = 0; r < 6; ++r) {
        gemm64_t<true><<<dim3(16, 16, 2), blk, 0, stream>>>(
            Sc, Sc, (float*)Sn, 1024, 1024, MEG_, MEG_, MEG_ / 2, nullptr, 0);
        unsigned short* t = Sc; Sc = Sn; Sn = t;
    }
    pick_col<<<2, blk, 0, stream>>>(Sc, v0);
    matvec_z<<<dim3(256, 2), blk, 0, stream>>>(G0, v0, w1);
    matvec_z<<<dim3(256, 2), blk, 0, stream>>>(G0, w1, w2);
    rq_scale<<<2, blk, 0, stream>>>(w1, w2, scal);   // scal[0]=inv_in, scal[1]=inv_out

    if (big) {
        // ---- 2 stripes of 8192 rows (2 whole batches each, no carry) ----
        for (int s = 0; s < BNSTRIPE_; ++s) {
            const int r0 = s * BSROWS_;
            cvt_u<<<32768, blk, 0, stream>>>(u + (size_t)r0 * DD_, ubf);
            gemm_bf16<<<dim3(32, 64), blk, 0, stream>>>(
                ubf, Wcat, Wcat + (size_t)1024 * 1024, usS, rawS,
                1024, N_, K3_, 1024);
            scan_phase1<<<2048, blk, 0, stream>>>(rawS, usS, bp, dbias, alog,
                                                  lgam, scal, agg_a, agg_b);
            scan_phase2b<<<dim3(4, 2), blk, 0, stream>>>(agg_a, agg_b, pref, BCPB_);
            scan_phase3<<<2048, blk, 0, stream>>>(rawS, usS, bp, dbias, alog,
                                                  lgam, scal, pref, ubf);
            gemm64_t<false><<<dim3(16, 128, 1), blk, 0, stream>>>(
                ubf, Woutb, y + (size_t)r0 * N_, 1024, 1024,
                0, 0, 0, scal + 1, 1);
        }
    } else {
        // ---- 8 stripes of 2048 rows with sequential carry (round-2 path) ----
        for (int s = 0; s < NSTRIPE_; ++s) {
            const int r0 = s * SROWS_;
            cvt_u<<<8192, blk, 0, stream>>>(u + (size_t)r0 * DD_, ubf);
            gemm_bf16<<<dim3(32, 16), blk, 0, stream>>>(
                ubf, Wcat, Wcat + (size_t)1024 * 1024, usS, rawS,
                1024, N_, K3_, 1024);
            scan_phase1<<<512, blk, 0, stream>>>(rawS, usS, bp, dbias, alog,
                                                 lgam, scal, agg_a, agg_b);
            scan_phase2s<<<4, blk, 0, stream>>>(agg_a, agg_b, pref, carry,
                                                s >> 1, s & 1);
            scan_phase3<<<512, blk, 0, stream>>>(rawS, usS, bp, dbias, alog,
                                                 lgam, scal, pref, ubf);
            gemm64_t<false><<<dim3(16, 32, 1), blk, 0, stream>>>(
                ubf, Woutb, y + (size_t)r0 * N_, 1024, 1024,
                0, 0, 0, scal + 1, 1);
        }
    }
}

// Round 9
// 659.382 us; speedup vs baseline: 1.7408x; 1.1898x over previous
//
#include <hip/hip_runtime.h>

// ---------------- problem dims (fixed by setup_inputs) ----------------
#define B_    4
#define T_    4096
#define DD_   1024
#define N_    1024
#define K3_   3072
#define M_    16384      // B_*T_
#define CL_   16         // scan chunk length (time steps)
#define MEG_  1048576

// ---------------- small-path ws layout (floats, ~48 MiB) ----------------
#define SROWS_ 2048
#define NSTRIPE_ (M_/SROWS_)     // 8
#define CPS_  (SROWS_/CL_)       // 128 chunks per stripe
#define OFF_RAWS  ((size_t)0)
#define OFF_USS   ((size_t)6*MEG_)
#define OFF_UBF   ((size_t)8*MEG_)
#define OFF_WCAT  ((size_t)9*MEG_)
#define OFF_WOUTB ((size_t)11*MEG_)
#define OFF_AGA   (OFF_WOUTB + 524288)
#define OFF_AGB   (OFF_AGA + 131072)
#define OFF_PRE   (OFF_AGB + 131072)
#define OFF_CARRY (OFF_PRE + 131072)
#define OFF_V0    (OFF_CARRY + 4096)
#define OFF_W1    (OFF_V0 + 2048)
#define OFF_W2    (OFF_W1 + 2048)
#define OFF_SCAL  (OFF_W2 + 2048)
#define REQ_FLOATS (OFF_SCAL + 16)

// ---------------- big-path ws layout (floats, ~160 MiB) ----------------
#define BSROWS_  8192
#define BNSTRIPE_ 2
#define BCPB_    (T_/CL_)          // 256 chunks per batch chain
#define BOFF_RAWS  ((size_t)0)
#define BOFF_USS   ((size_t)24*MEG_)
#define BOFF_UBF   ((size_t)32*MEG_)
#define BOFF_WCAT  ((size_t)36*MEG_)
#define BOFF_WOUTB ((size_t)38*MEG_)
#define BOFF_AGA   (BOFF_WOUTB + 524288)
#define BOFF_AGB   (BOFF_AGA + 524288)
#define BOFF_PRE   (BOFF_AGB + 524288)
#define BOFF_V0    (BOFF_PRE + 524288)
#define BOFF_W1    (BOFF_V0 + 2048)
#define BOFF_W2    (BOFF_W1 + 2048)
#define BOFF_SCAL  (BOFF_W2 + 2048)
#define BREQ_FLOATS (BOFF_SCAL + 16)

// ---------------- mega-path ws layout (floats, ~246 MiB) ----------------
// ONE stripe = whole problem (16384 rows, 4 batch chains). rawS stored
// bf16 (96 MiB) so everything fits; usS stays fp32.
#define MCHUNKS_ (M_/CL_)          // 1024 chunks total
#define MCPB_    (T_/CL_)          // 256 chunks per batch chain
#define MOFF_RAWB  ((size_t)0)                     // 24M f region: 48M shorts
#define MOFF_USS   ((size_t)24*MEG_)               // 16M f (64 MiB)
#define MOFF_UALL  ((size_t)40*MEG_)               // 8M f: 16M shorts (u bf16)
#define MOFF_YH    ((size_t)48*MEG_)               // 8M f: 16M shorts (y_hat)
#define MOFF_WCAT  ((size_t)56*MEG_)               // 2M f
#define MOFF_WOUTB ((size_t)58*MEG_)               // 512K f
#define MOFF_AGA   (MOFF_WOUTB + 524288)           // 1M f
#define MOFF_AGB   (MOFF_AGA + MEG_)
#define MOFF_PRE   (MOFF_AGB + MEG_)
#define MOFF_V0    (MOFF_PRE + MEG_)
#define MOFF_W1    (MOFF_V0 + 2048)
#define MOFF_W2    (MOFF_W1 + 2048)
#define MOFF_SCAL  (MOFF_W2 + 2048)
#define MREQ_FLOATS (MOFF_SCAL + 16)

typedef short s8v __attribute__((ext_vector_type(8)));   // 8 bf16 (4 VGPRs)
typedef float f4v __attribute__((ext_vector_type(4)));   // MFMA acc

typedef __attribute__((address_space(3))) unsigned int       lds_u32;
typedef const __attribute__((address_space(1))) unsigned int glb_u32;

__device__ __forceinline__ void gload_lds16(const void* g, void* l)
{
    __builtin_amdgcn_global_load_lds((glb_u32*)g, (lds_u32*)l, 16, 0, 0);
}

// fp32 -> bf16 round-to-nearest-even
__device__ __forceinline__ unsigned short f2bf(float f)
{
    unsigned u = __float_as_uint(f);
    u += 0x7FFFu + ((u >> 16) & 1u);
    return (unsigned short)(u >> 16);
}
__device__ __forceinline__ float bf2f(unsigned short h)
{
    return __uint_as_float((unsigned)h << 16);
}
// dtype-generic raw loads for scan kernels
__device__ __forceinline__ float ldr(const float* p, size_t i)          { return p[i]; }
__device__ __forceinline__ float ldr(const unsigned short* p, size_t i) { return bf2f(p[i]); }

// ---- BK=64 LDS swizzle (128 B rows, 8 granules of 16 B). Physical slot of
// logical granule g in row r = g ^ (r&7); gload dest is lane-linear so lane
// sources logical granule (lane&7)^(lane>>3). Bit-identical data (rule #21).
#define SWZ64_SRC_GRAN(lane)  (((lane) & 7) ^ ((lane) >> 3))
#define SWZ64_SLOT(kk,quad,lrow) ((((kk)*4 + (quad)) ^ ((lrow) & 7)) * 8)

// ---- BK=32 swizzle (64 B rows, 4 granules) — gram only.
#define SWZ_SRC_GRAN(lane)  (((lane) & 3) ^ (((lane) >> 3) & 3))
#define SWZ_SLOT(quad,lrow) ((quad) ^ (((lrow) >> 1) & 3))

// ---------------- fallback: zero a float buffer ----------------
__global__ void zero_out(float* __restrict__ y, int n)
{
    int i = blockIdx.x * 256 + threadIdx.x;
    if (i < n) y[i] = 0.f;
}

// ------- one-time weight conversion + split-bf16 planes + optional u ------
__global__ void cvt_weights(const float* __restrict__ Win, const float* __restrict__ Wp,
                            const float* __restrict__ Wout,
                            unsigned short* __restrict__ Wcat,
                            unsigned short* __restrict__ Woutb,
                            unsigned short* __restrict__ hi,
                            unsigned short* __restrict__ lo,
                            const float* __restrict__ u,
                            unsigned short* __restrict__ uall, int nU)
{
    int i = blockIdx.x * 256 + threadIdx.x;
    if (i < 1048576)       Wcat[i] = f2bf(Win[i]);
    else if (i < 4194304)  Wcat[i] = f2bf(Wp[i - 1048576]);
    else if (i < 5242880)  Woutb[i - 4194304] = f2bf(Wout[i - 4194304]);
    if (i < 2097152) {
        float wv = (i < MEG_) ? Win[i] : Wout[i - MEG_];
        unsigned short h = f2bf(wv);
        hi[i] = h;
        lo[i] = f2bf(wv - bf2f(h));                // w - hi exact in fp32
    }
    if (i < nU) uall[i] = f2bf(u[i]);
}

// ---------------- per-stripe u conversion (small/big paths) ----------------
__global__ void cvt_u(const float* __restrict__ src, unsigned short* __restrict__ dst)
{
    int i = blockIdx.x * 256 + threadIdx.x;
    dst[i] = f2bf(src[i]);
}

// =====================================================================
// Split-bf16 MFMA gram: C[z] = W[z] W[z]^T  (hi.hi + hi.lo + lo.hi).
// 64x64 tile, BK=32, swizzled LDS.
// =====================================================================
__global__ __launch_bounds__(256, 4) void gram_bf16x2(
    const unsigned short* __restrict__ hi, const unsigned short* __restrict__ lo,
    float* __restrict__ C, unsigned short* __restrict__ Cb)
{
    __shared__ __align__(16) unsigned short Ah[64 * 32];
    __shared__ __align__(16) unsigned short Al[64 * 32];
    __shared__ __align__(16) unsigned short Bh[64 * 32];
    __shared__ __align__(16) unsigned short Bl[64 * 32];
    const int tid = threadIdx.x;
    const int z   = blockIdx.z;
    const int m0  = blockIdx.y * 64;
    const int n0  = blockIdx.x * 64;

    const unsigned short* hz = hi + (size_t)z * MEG_;
    const unsigned short* lz = lo + (size_t)z * MEG_;

    const int lane = tid & 63;
    const int w    = tid >> 6;
    const int wm   = (w >> 1) * 32;
    const int wn   = (w & 1) * 32;
    const int lrow = lane & 15;
    const int quad = lane >> 4;
    const int srow = lane >> 2;
    const int scol = SWZ_SRC_GRAN(lane) * 8;
    const int slot = SWZ_SLOT(quad, lrow) * 8;

    const size_t arow = (size_t)(m0 + w*16 + srow) * 1024 + scol;
    const size_t brow = (size_t)(n0 + w*16 + srow) * 1024 + scol;
    unsigned short* dA = &Ah[(w*16) * 32];
    unsigned short* eA = &Al[(w*16) * 32];
    unsigned short* dB = &Bh[(w*16) * 32];
    unsigned short* eB = &Bl[(w*16) * 32];

    f4v acc[2][2];
    #pragma unroll
    for (int i = 0; i < 2; ++i)
      #pragma unroll
      for (int j = 0; j < 2; ++j) acc[i][j] = (f4v){0.f, 0.f, 0.f, 0.f};

    for (int kt = 0; kt < 1024; kt += 32) {
        __syncthreads();
        gload_lds16(hz + arow + kt, dA);
        gload_lds16(lz + arow + kt, eA);
        gload_lds16(hz + brow + kt, dB);
        gload_lds16(lz + brow + kt, eB);
        __syncthreads();

        s8v ah[2], al[2], bh[2], bl[2];
        #pragma unroll
        for (int i = 0; i < 2; ++i) {
            ah[i] = *(const s8v*)&Ah[(wm + i*16 + lrow) * 32 + slot];
            al[i] = *(const s8v*)&Al[(wm + i*16 + lrow) * 32 + slot];
        }
        #pragma unroll
        for (int j = 0; j < 2; ++j) {
            bh[j] = *(const s8v*)&Bh[(wn + j*16 + lrow) * 32 + slot];
            bl[j] = *(const s8v*)&Bl[(wn + j*16 + lrow) * 32 + slot];
        }
        #pragma unroll
        for (int i = 0; i < 2; ++i)
          #pragma unroll
          for (int j = 0; j < 2; ++j) {
              acc[i][j] = __builtin_amdgcn_mfma_f32_16x16x32_bf16(ah[i], bh[j], acc[i][j], 0, 0, 0);
              acc[i][j] = __builtin_amdgcn_mfma_f32_16x16x32_bf16(ah[i], bl[j], acc[i][j], 0, 0, 0);
              acc[i][j] = __builtin_amdgcn_mfma_f32_16x16x32_bf16(al[i], bh[j], acc[i][j], 0, 0, 0);
          }
    }

    float*          Cz  = C  + (size_t)z * MEG_;
    unsigned short* Cbz = Cb + (size_t)z * MEG_;
    #pragma unroll
    for (int i = 0; i < 2; ++i)
      #pragma unroll
      for (int j = 0; j < 2; ++j) {
        const int col = n0 + wn + j * 16 + lrow;
        #pragma unroll
        for (int r = 0; r < 4; ++r) {
            const int row = m0 + wm + i * 16 + quad * 4 + r;
            float v = acc[i][j][r];
            Cz [(size_t)row * 1024 + col] = v;
            Cbz[(size_t)row * 1024 + col] = f2bf(v);
        }
    }
}

// =====================================================================
// bf16 MFMA NT GEMM, 64x64 tile, BK=64, z-batched. OBF: bf16 output.
// mode: 0 plain, 1 scale by sptr[0]. Swizzled LDS (BK64). K % 64 == 0.
// =====================================================================
template<bool OBF>
__global__ __launch_bounds__(256, 4) void gemm64_t(
    const unsigned short* __restrict__ A, const unsigned short* __restrict__ B,
    float* __restrict__ C, int K, int ldc,
    long zsA, long zsB, long zsC,
    const float* __restrict__ sptr, int mode)
{
    __shared__ __align__(16) unsigned short As[64 * 64];   // 8 KiB
    __shared__ __align__(16) unsigned short Bs[64 * 64];   // 8 KiB
    const int tid = threadIdx.x;
    const int z   = blockIdx.z;
    const int m0  = blockIdx.y * 64;
    const int n0  = blockIdx.x * 64;

    const unsigned short* Az = A + (size_t)z * zsA;
    const unsigned short* Bz = B + (size_t)z * zsB;

    const int lane = tid & 63;
    const int w    = tid >> 6;
    const int wm   = (w >> 1) * 32;
    const int wn   = (w & 1) * 32;
    const int lrow = lane & 15;
    const int quad = lane >> 4;
    const int srow8 = lane >> 3;
    const int scol  = SWZ64_SRC_GRAN(lane) * 8;

    const unsigned short* Agl = Az + (size_t)(m0 + w*16 + srow8) * K + scol;
    const unsigned short* Bgl = Bz + (size_t)(n0 + w*16 + srow8) * K + scol;
    unsigned short* lA = &As[(w*16) * 64];
    unsigned short* lB = &Bs[(w*16) * 64];

    f4v acc[2][2];
    #pragma unroll
    for (int i = 0; i < 2; ++i)
      #pragma unroll
      for (int j = 0; j < 2; ++j) acc[i][j] = (f4v){0.f, 0.f, 0.f, 0.f};

    for (int kt = 0; kt < K; kt += 64) {
        __syncthreads();
        gload_lds16(Agl + kt,                lA);
        gload_lds16(Agl + (size_t)8*K + kt,  lA + 8*64);
        gload_lds16(Bgl + kt,                lB);
        gload_lds16(Bgl + (size_t)8*K + kt,  lB + 8*64);
        __syncthreads();

        #pragma unroll
        for (int kk = 0; kk < 2; ++kk) {
            const int slot = SWZ64_SLOT(kk, quad, lrow);
            s8v af[2], bf[2];
            #pragma unroll
            for (int i = 0; i < 2; ++i)
                af[i] = *(const s8v*)&As[(wm + i*16 + lrow) * 64 + slot];
            #pragma unroll
            for (int j = 0; j < 2; ++j)
                bf[j] = *(const s8v*)&Bs[(wn + j*16 + lrow) * 64 + slot];
            #pragma unroll
            for (int i = 0; i < 2; ++i)
              #pragma unroll
              for (int j = 0; j < 2; ++j)
                  acc[i][j] = __builtin_amdgcn_mfma_f32_16x16x32_bf16(af[i], bf[j], acc[i][j], 0, 0, 0);
        }
    }

    float sc = (mode == 1) ? sptr[0] : 1.0f;
    float* Cp = C + (size_t)z * zsC;

    #pragma unroll
    for (int i = 0; i < 2; ++i)
      #pragma unroll
      for (int j = 0; j < 2; ++j) {
        const int col = n0 + wn + j * 16 + lrow;
        #pragma unroll
        for (int r = 0; r < 4; ++r) {
            const int row = m0 + wm + i * 16 + quad * 4 + r;
            if (OBF)
                ((unsigned short*)Cp)[(size_t)row * ldc + col] = f2bf(acc[i][j][r] * sc);
            else
                Cp[(size_t)row * ldc + col] = acc[i][j][r] * sc;
        }
    }
}

// =====================================================================
// Pure-bf16 MFMA NT GEMM, 128x128 tile, BK=64. Dual-output split at
// nsplit; OBF1: write C1 as bf16 (ldc1 in shorts). Swizzled LDS (BK64).
// =====================================================================
template<bool OBF1>
__global__ __launch_bounds__(256, 2) void gemm_bf16(
    const unsigned short* __restrict__ A,
    const unsigned short* __restrict__ B0, const unsigned short* __restrict__ B1,
    float* __restrict__ C0, float* __restrict__ C1,
    int K, int ldc0, int ldc1, int nsplit)
{
    __shared__ __align__(16) unsigned short As[128 * 64];  // 16 KiB
    __shared__ __align__(16) unsigned short Bs[128 * 64];  // 16 KiB
    const int tid = threadIdx.x;
    const int m0  = blockIdx.y * 128;
    const int n0g = blockIdx.x * 128;

    const unsigned short* Bsrc; float* Cp; int ldc; int c0; bool obf;
    if (n0g < nsplit) {
        Bsrc = B0 + (size_t)n0g * K;
        Cp = C0; ldc = ldc0; c0 = n0g; obf = false;
    } else {
        Bsrc = B1 + (size_t)(n0g - nsplit) * K;
        Cp = C1; ldc = ldc1; c0 = n0g - nsplit; obf = OBF1;
    }

    const int lane = tid & 63;
    const int w    = tid >> 6;
    const int wm   = (w >> 1) * 64;
    const int wn   = (w & 1) * 64;
    const int lrow = lane & 15;
    const int quad = lane >> 4;
    const int srow8 = lane >> 3;
    const int scol  = SWZ64_SRC_GRAN(lane) * 8;

    const unsigned short* Agl = A    + (size_t)(m0 + w*32 + srow8) * K + scol;
    const unsigned short* Bgl = Bsrc + (size_t)(w*32 + srow8) * K + scol;
    unsigned short* lA = &As[(w*32) * 64];
    unsigned short* lB = &Bs[(w*32) * 64];

    f4v acc[4][4];
    #pragma unroll
    for (int i = 0; i < 4; ++i)
      #pragma unroll
      for (int j = 0; j < 4; ++j) acc[i][j] = (f4v){0.f, 0.f, 0.f, 0.f};

    for (int kt = 0; kt < K; kt += 64) {
        __syncthreads();
        #pragma unroll
        for (int q8 = 0; q8 < 4; ++q8) {
            gload_lds16(Agl + (size_t)(q8*8)*K + kt, lA + (q8*8)*64);
            gload_lds16(Bgl + (size_t)(q8*8)*K + kt, lB + (q8*8)*64);
        }
        __syncthreads();

        #pragma unroll
        for (int kk = 0; kk < 2; ++kk) {
            const int slot = SWZ64_SLOT(kk, quad, lrow);
            s8v af[4], bf[4];
            #pragma unroll
            for (int i = 0; i < 4; ++i)
                af[i] = *(const s8v*)&As[(wm + i*16 + lrow) * 64 + slot];
            #pragma unroll
            for (int j = 0; j < 4; ++j)
                bf[j] = *(const s8v*)&Bs[(wn + j*16 + lrow) * 64 + slot];
            #pragma unroll
            for (int i = 0; i < 4; ++i)
              #pragma unroll
              for (int j = 0; j < 4; ++j)
                  acc[i][j] = __builtin_amdgcn_mfma_f32_16x16x32_bf16(af[i], bf[j], acc[i][j], 0, 0, 0);
        }
    }

    #pragma unroll
    for (int i = 0; i < 4; ++i)
      #pragma unroll
      for (int j = 0; j < 4; ++j) {
        const int col = c0 + wn + j * 16 + lrow;
        #pragma unroll
        for (int r = 0; r < 4; ++r) {
            const int row = m0 + wm + i * 16 + quad * 4 + r;
            if (OBF1 && obf)
                ((unsigned short*)Cp)[(size_t)row * ldc + col] = f2bf(acc[i][j][r]);
            else
                Cp[(size_t)row * ldc + col] = acc[i][j][r];
        }
    }
}

// ---- pick column with max diagonal (dominant-eigvec seed), z=blockIdx.x ----
__global__ void pick_col(const unsigned short* __restrict__ Pall, float* __restrict__ vall)
{
    const unsigned short* P = Pall + (size_t)blockIdx.x * MEG_;
    float* v = vall + blockIdx.x * N_;
    __shared__ float sval[256];
    __shared__ int   sidx[256];
    __shared__ int   jstar;
    const int tid = threadIdx.x;
    float best = -1.f; int bidx = 0;
    for (int i = tid; i < N_; i += 256) {
        float d = bf2f(P[(size_t)i * (N_ + 1)]);
        if (d > best) { best = d; bidx = i; }
    }
    sval[tid] = best; sidx[tid] = bidx; __syncthreads();
    for (int off = 128; off > 0; off >>= 1) {
        if (tid < off && sval[tid + off] > sval[tid]) {
            sval[tid] = sval[tid + off]; sidx[tid] = sidx[tid + off];
        }
        __syncthreads();
    }
    if (tid == 0) jstar = sidx[0];
    __syncthreads();
    const int j = jstar;
    for (int i = tid; i < N_; i += 256) v[i] = bf2f(P[(size_t)j * N_ + i]);
}

// ---------------- w = G[z] * v[z] (one wave per row), z=blockIdx.y ----------
__global__ __launch_bounds__(256) void matvec_z(
    const float* __restrict__ Gall, const float* __restrict__ vall,
    float* __restrict__ wall)
{
    const int z = blockIdx.y;
    const float* G = Gall + (size_t)z * MEG_;
    const float* v = vall + z * N_;
    const int row  = blockIdx.x * 4 + (threadIdx.x >> 6);
    const int lane = threadIdx.x & 63;
    const float* g = G + (size_t)row * N_;
    float s = 0.f;
    for (int j = lane; j < N_; j += 64) s += g[j] * v[j];
    #pragma unroll
    for (int off = 32; off > 0; off >>= 1) s += __shfl_down(s, off, 64);
    if (lane == 0) wall[z * N_ + row] = s;
}

// ------- Rayleigh quotient -> inv_scale[z] = 1/max(sigma,1), z=blockIdx.x ----
__global__ void rq_scale(const float* __restrict__ w1a, const float* __restrict__ w2a,
                         float* __restrict__ slot)
{
    const int z = blockIdx.x;
    const float* w1 = w1a + z * N_;
    const float* w2 = w2a + z * N_;
    __shared__ float r11[256];
    __shared__ float r12[256];
    const int tid = threadIdx.x;
    float d11 = 0.f, d12 = 0.f;
    for (int i = tid; i < N_; i += 256) {
        float a = w1[i], b = w2[i];
        d11 = fmaf(a, a, d11);
        d12 = fmaf(a, b, d12);
    }
    r11[tid] = d11; r12[tid] = d12; __syncthreads();
    for (int off = 128; off > 0; off >>= 1) {
        if (tid < off) { r11[tid] += r11[tid + off]; r12[tid] += r12[tid + off]; }
        __syncthreads();
    }
    if (tid == 0) {
        float lam = r12[0] / fmaxf(r11[0], 1e-30f);
        float sig = sqrtf(fmaxf(lam, 0.f));
        slot[z] = 1.0f / fmaxf(sig, 1.0f);
    }
}

// ---------------- fast elementwise math (hw v_exp/v_log) ----------------
__device__ __forceinline__ float fast_sp(float x)
{
    return fmaxf(x, 0.f) + __logf(1.0f + __expf(-fabsf(x)));
}
__device__ __forceinline__ float fast_tanh(float x)
{
    float e = __expf(2.0f * fabsf(x));
    float t = 1.0f - 2.0f / (e + 1.0f);
    return copysignf(t, x);
}

__device__ __forceinline__ void abc_math(
    float dr, float br, float cr, float uval,
    float alpha, float db, float sgain,
    float* pa, float* pbu, float* pc)
{
    float delta = fast_sp(dr + db);
    float a = fminf(__expf(-delta * alpha), 1.0f - 1e-4f);
    float b = fast_tanh(br);
    float c = fast_tanh(cr);
    float p = fmaf(a, a, c * c);
    float r = b * b;
    float q = a * b;
    float pr = p - r;
    float disc = fmaf(pr, pr, 4.0f * q * q);
    float lam = 0.5f * (p + r + sqrtf(disc + 1e-12f));
    float sig = sqrtf(lam + 1e-12f);
    float inv = 1.0f / fmaxf(sig, 1.0f);
    a *= inv; b *= inv; c *= inv;
    *pa = a; *pc = c; *pbu = b * (sgain * uval);
}

// --------- scan phase 1: per-chunk composite (CL=16). TR = raw dtype. ---
template<class TR>
__global__ __launch_bounds__(256) void scan_phase1(
    const TR* __restrict__ rawS, const float* __restrict__ usS,
    const float* __restrict__ bp, const float* __restrict__ dbias,
    const float* __restrict__ alog, const float* __restrict__ lgam,
    const float* __restrict__ inv_sin,
    float* __restrict__ agg_a, float* __restrict__ agg_b)
{
    const int gid = blockIdx.x * 256 + threadIdx.x;
    const int n   = gid & (N_ - 1);
    const int cl  = gid >> 10;

    const float alpha = fast_sp(alog[n]);
    const float db    = dbias[n];
    const float bpd   = bp[n];
    const float bpb   = bp[N_ + n];
    const float bpc   = bp[2*N_ + n];
    const float sgain = __expf(lgam[0]) * inv_sin[0];

    float Ap = 1.f, Bc = 0.f;
    size_t base  = (size_t)(cl * CL_) * K3_ + n;
    size_t ubase = (size_t)(cl * CL_) * N_  + n;
    #pragma unroll 4
    for (int j = 0; j < CL_; ++j) {
        float dr = ldr(rawS, base)        + bpd;
        float br = ldr(rawS, base + N_)   + bpb;
        float cr = ldr(rawS, base + 2*N_) + bpc;
        float uv = usS[ubase];
        float a, bu, cv;
        abc_math(dr, br, cr, uv, alpha, db, sgain, &a, &bu, &cv);
        Bc = fmaf(a, Bc, bu);
        Ap *= a;
        base += K3_; ubase += N_;
    }
    agg_a[(size_t)cl * N_ + n] = Ap;
    agg_b[(size_t)cl * N_ + n] = Bc;
}

// --------- scan phase 2 (small path): chunk-prefix with inter-stripe carry --
__global__ void scan_phase2s(const float* __restrict__ agg_a,
                             const float* __restrict__ agg_b,
                             float* __restrict__ pref, float* __restrict__ carry,
                             int bidx, int use_carry)
{
    const int n = blockIdx.x * 256 + threadIdx.x;
    float z = use_carry ? carry[bidx * N_ + n] : 0.f;
    size_t idx = n;
    for (int c = 0; c < CPS_; ++c) {
        pref[idx] = z;
        z = fmaf(agg_a[idx], z, agg_b[idx]);
        idx += N_;
    }
    carry[bidx * N_ + n] = z;
}

// --------- scan phase 2 (chains): independent per-batch chains, z0 = 0 ---
__global__ void scan_phase2b(const float* __restrict__ agg_a,
                             const float* __restrict__ agg_b,
                             float* __restrict__ pref, int cpb)
{
    const int n = blockIdx.x * 256 + threadIdx.x;
    const int chain = blockIdx.y;
    size_t idx = (size_t)chain * cpb * N_ + n;
    float z = 0.f;
    for (int c = 0; c < cpb; ++c) {
        pref[idx] = z;
        z = fmaf(agg_a[idx], z, agg_b[idx]);
        idx += N_;
    }
}

// --------- scan phase 3: replay with chunk prefix, write y_hat bf16 ---------
template<class TR>
__global__ __launch_bounds__(256) void scan_phase3(
    const TR* __restrict__ rawS, const float* __restrict__ usS,
    const float* __restrict__ bp, const float* __restrict__ dbias,
    const float* __restrict__ alog, const float* __restrict__ lgam,
    const float* __restrict__ inv_sin, const float* __restrict__ pref,
    unsigned short* __restrict__ yh)
{
    const int gid = blockIdx.x * 256 + threadIdx.x;
    const int n   = gid & (N_ - 1);
    const int cl  = gid >> 10;

    const float alpha = fast_sp(alog[n]);
    const float db    = dbias[n];
    const float bpd   = bp[n];
    const float bpb   = bp[N_ + n];
    const float bpc   = bp[2*N_ + n];
    const float sgain = __expf(lgam[0]) * inv_sin[0];

    float z = pref[(size_t)cl * N_ + n];
    size_t base  = (size_t)(cl * CL_) * K3_ + n;
    size_t ubase = (size_t)(cl * CL_) * N_  + n;
    #pragma unroll 4
    for (int j = 0; j < CL_; ++j) {
        float dr = ldr(rawS, base)        + bpd;
        float br = ldr(rawS, base + N_)   + bpb;
        float cr = ldr(rawS, base + 2*N_) + bpc;
        float uv = usS[ubase];
        float a, bu, cv;
        abc_math(dr, br, cr, uv, alpha, db, sgain, &a, &bu, &cv);
        yh[ubase] = f2bf(cv * z);
        z = fmaf(a, z, bu);
        base += K3_; ubase += N_;
    }
}

// =====================================================================
extern "C" void kernel_launch(void* const* d_in, const int* in_sizes, int n_in,
                              void* d_out, int out_size, void* d_ws, size_t ws_size,
                              hipStream_t stream)
{
    (void)in_sizes; (void)n_in;
    const float* u     = (const float*)d_in[0];
    const float* W_in  = (const float*)d_in[1];
    const float* W_out = (const float*)d_in[2];
    const float* Wp    = (const float*)d_in[3];
    const float* bp    = (const float*)d_in[4];
    const float* alog  = (const float*)d_in[5];
    const float* dbias = (const float*)d_in[6];
    const float* lgam  = (const float*)d_in[7];
    float* y = (float*)d_out;

    if (ws_size < (size_t)REQ_FLOATS * sizeof(float)) {
        zero_out<<<(out_size + 255) / 256, dim3(256), 0, stream>>>(y, out_size);
        return;
    }
    const bool mega = ws_size >= (size_t)MREQ_FLOATS * sizeof(float);
    const bool big  = !mega && ws_size >= (size_t)BREQ_FLOATS * sizeof(float);

    float* ws = (float*)d_ws;
    const dim3 blk(256);

    // path-dependent layout
    size_t oRAW, oUSS, oWCAT, oWOUTB, oAGA, oAGB, oPRE, oV0, oW1, oW2, oSCAL;
    if (mega) {
        oRAW = MOFF_RAWB; oUSS = MOFF_USS; oWCAT = MOFF_WCAT; oWOUTB = MOFF_WOUTB;
        oAGA = MOFF_AGA; oAGB = MOFF_AGB; oPRE = MOFF_PRE;
        oV0 = MOFF_V0; oW1 = MOFF_W1; oW2 = MOFF_W2; oSCAL = MOFF_SCAL;
    } else if (big) {
        oRAW = BOFF_RAWS; oUSS = BOFF_USS; oWCAT = BOFF_WCAT; oWOUTB = BOFF_WOUTB;
        oAGA = BOFF_AGA; oAGB = BOFF_AGB; oPRE = BOFF_PRE;
        oV0 = BOFF_V0; oW1 = BOFF_W1; oW2 = BOFF_W2; oSCAL = BOFF_SCAL;
    } else {
        oRAW = OFF_RAWS; oUSS = OFF_USS; oWCAT = OFF_WCAT; oWOUTB = OFF_WOUTB;
        oAGA = OFF_AGA; oAGB = OFF_AGB; oPRE = OFF_PRE;
        oV0 = OFF_V0; oW1 = OFF_W1; oW2 = OFF_W2; oSCAL = OFF_SCAL;
    }

    float*          usS   = ws + oUSS;
    unsigned short* Wcat  = (unsigned short*)(ws + oWCAT);
    unsigned short* Woutb = (unsigned short*)(ws + oWOUTB);
    float* agg_a = ws + oAGA;
    float* agg_b = ws + oAGB;
    float* pref  = ws + oPRE;
    float* carry = ws + OFF_CARRY;                       // small path only
    float* v0    = ws + oV0;
    float* w1    = ws + oW1;
    float* w2    = ws + oW2;
    float* scal  = ws + oSCAL;
    // sigma-phase aliases over the raw region (live only before stripes)
    float*          G0   = ws + oRAW;
    unsigned short* hiW  = (unsigned short*)(ws + oRAW + 2*MEG_);
    unsigned short* loW  = (unsigned short*)(ws + oRAW + 3*MEG_);
    unsigned short* SbfA = (unsigned short*)usS;
    unsigned short* SbfB = SbfA + 2*MEG_;
    // mega-only buffers
    unsigned short* uall = (unsigned short*)(ws + MOFF_UALL);
    unsigned short* yhM  = (unsigned short*)(ws + MOFF_YH);
    unsigned short* rawB = (unsigned short*)(ws + MOFF_RAWB);

    if (mega)
        cvt_weights<<<65536, blk, 0, stream>>>(W_in, Wp, W_out, Wcat, Woutb,
                                               hiW, loW, u, uall, 16777216);
    else
        cvt_weights<<<20480, blk, 0, stream>>>(W_in, Wp, W_out, Wcat, Woutb,
                                               hiW, loW, nullptr, nullptr, 0);

    // ---- spectral norms: split-bf16 MFMA gram (z=2), 6 bf16 squarings,
    //      fp32 Rayleigh quotient on the MFMA-accurate G0. ----
    gram_bf16x2<<<dim3(16, 16, 2), blk, 0, stream>>>(hiW, loW, G0, SbfA);
    unsigned short* Sc = SbfA;
    unsigned short* Sn = SbfB;
    for (int r = 0; r < 6; ++r) {
        gemm64_t<true><<<dim3(16, 16, 2), blk, 0, stream>>>(
            Sc, Sc, (float*)Sn, 1024, 1024, MEG_, MEG_, MEG_ / 2, nullptr, 0);
        unsigned short* t = Sc; Sc = Sn; Sn = t;
    }
    pick_col<<<2, blk, 0, stream>>>(Sc, v0);
    matvec_z<<<dim3(256, 2), blk, 0, stream>>>(G0, v0, w1);
    matvec_z<<<dim3(256, 2), blk, 0, stream>>>(G0, w1, w2);
    rq_scale<<<2, blk, 0, stream>>>(w1, w2, scal);   // scal[0]=inv_in, scal[1]=inv_out

    if (mega) {
        // ---- whole problem at once: 4 independent batch chains, no carry.
        // rawS stored bf16 (96 MiB); usS fp32. ----
        gemm_bf16<true><<<dim3(32, 128), blk, 0, stream>>>(
            uall, Wcat, Wcat + (size_t)1024 * 1024, usS, (float*)rawB,
            1024, N_, K3_, 1024);
        scan_phase1<<<4096, blk, 0, stream>>>(rawB, usS, bp, dbias, alog,
                                              lgam, scal, agg_a, agg_b);
        scan_phase2b<<<dim3(4, B_), blk, 0, stream>>>(agg_a, agg_b, pref, MCPB_);
        scan_phase3<<<4096, blk, 0, stream>>>(rawB, usS, bp, dbias, alog,
                                              lgam, scal, pref, yhM);
        gemm64_t<false><<<dim3(16, 256, 1), blk, 0, stream>>>(
            yhM, Woutb, y, 1024, 1024, 0, 0, 0, scal + 1, 1);
    } else if (big) {
        float*          rawS = ws + oRAW;
        unsigned short* ubf  = (unsigned short*)(ws + BOFF_UBF);
        for (int s = 0; s < BNSTRIPE_; ++s) {
            const int r0 = s * BSROWS_;
            cvt_u<<<32768, blk, 0, stream>>>(u + (size_t)r0 * DD_, ubf);
            gemm_bf16<false><<<dim3(32, 64), blk, 0, stream>>>(
                ubf, Wcat, Wcat + (size_t)1024 * 1024, usS, rawS,
                1024, N_, K3_, 1024);
            scan_phase1<<<2048, blk, 0, stream>>>(rawS, usS, bp, dbias, alog,
                                                  lgam, scal, agg_a, agg_b);
            scan_phase2b<<<dim3(4, 2), blk, 0, stream>>>(agg_a, agg_b, pref, BCPB_);
            scan_phase3<<<2048, blk, 0, stream>>>(rawS, usS, bp, dbias, alog,
                                                  lgam, scal, pref, ubf);
            gemm64_t<false><<<dim3(16, 128, 1), blk, 0, stream>>>(
                ubf, Woutb, y + (size_t)r0 * N_, 1024, 1024,
                0, 0, 0, scal + 1, 1);
        }
    } else {
        float*          rawS = ws + oRAW;
        unsigned short* ubf  = (unsigned short*)(ws + OFF_UBF);
        for (int s = 0; s < NSTRIPE_; ++s) {
            const int r0 = s * SROWS_;
            cvt_u<<<8192, blk, 0, stream>>>(u + (size_t)r0 * DD_, ubf);
            gemm_bf16<false><<<dim3(32, 16), blk, 0, stream>>>(
                ubf, Wcat, Wcat + (size_t)1024 * 1024, usS, rawS,
                1024, N_, K3_, 1024);
            scan_phase1<<<512, blk, 0, stream>>>(rawS, usS, bp, dbias, alog,
                                                 lgam, scal, agg_a, agg_b);
            scan_phase2s<<<4, blk, 0, stream>>>(agg_a, agg_b, pref, carry,
                                                s >> 1, s & 1);
            scan_phase3<<<512, blk, 0, stream>>>(rawS, usS, bp, dbias, alog,
                                                 lgam, scal, pref, ubf);
            gemm64_t<false><<<dim3(16, 32, 1), blk, 0, stream>>>(
                ubf, Woutb, y + (size_t)r0 * N_, 1024, 1024,
                0, 0, 0, scal + 1, 1);
        }
    }
}

// Round 10
// 622.884 us; speedup vs baseline: 1.8428x; 1.0586x over previous
//
#include <hip/hip_runtime.h>

// ---------------- problem dims (fixed by setup_inputs) ----------------
#define B_    4
#define T_    4096
#define DD_   1024
#define N_    1024
#define K3_   3072
#define M_    16384      // B_*T_
#define CL_   16         // scan chunk length (time steps)
#define MEG_  1048576

// ---------------- small-path ws layout (floats, ~48 MiB) ----------------
#define SROWS_ 2048
#define NSTRIPE_ (M_/SROWS_)     // 8
#define CPS_  (SROWS_/CL_)       // 128 chunks per stripe
#define OFF_RAWS  ((size_t)0)
#define OFF_USS   ((size_t)6*MEG_)
#define OFF_UBF   ((size_t)8*MEG_)
#define OFF_WCAT  ((size_t)9*MEG_)
#define OFF_WOUTB ((size_t)11*MEG_)
#define OFF_AGA   (OFF_WOUTB + 524288)
#define OFF_AGB   (OFF_AGA + 131072)
#define OFF_PRE   (OFF_AGB + 131072)
#define OFF_CARRY (OFF_PRE + 131072)
#define OFF_V0    (OFF_CARRY + 4096)
#define OFF_W1    (OFF_V0 + 2048)
#define OFF_W2    (OFF_W1 + 2048)
#define OFF_SCAL  (OFF_W2 + 2048)
#define REQ_FLOATS (OFF_SCAL + 16)

// ---------------- big-path ws layout (floats, ~160 MiB) ----------------
#define BSROWS_  8192
#define BNSTRIPE_ 2
#define BCPB_    (T_/CL_)          // 256 chunks per batch chain
#define BOFF_RAWS  ((size_t)0)
#define BOFF_USS   ((size_t)24*MEG_)
#define BOFF_UBF   ((size_t)32*MEG_)
#define BOFF_WCAT  ((size_t)36*MEG_)
#define BOFF_WOUTB ((size_t)38*MEG_)
#define BOFF_AGA   (BOFF_WOUTB + 524288)
#define BOFF_AGB   (BOFF_AGA + 524288)
#define BOFF_PRE   (BOFF_AGB + 524288)
#define BOFF_V0    (BOFF_PRE + 524288)
#define BOFF_W1    (BOFF_V0 + 2048)
#define BOFF_W2    (BOFF_W1 + 2048)
#define BOFF_SCAL  (BOFF_W2 + 2048)
#define BREQ_FLOATS (BOFF_SCAL + 16)

// ---------------- mega-path ws layout (floats, ~246 MiB) ----------------
// ONE stripe = whole problem (16384 rows, 4 batch chains). rawS stored
// bf16 (96 MiB); usS fp32.
#define MCPB_    (T_/CL_)          // 256 chunks per batch chain
#define MOFF_RAWB  ((size_t)0)                     // 24M f region: 48M shorts
#define MOFF_USS   ((size_t)24*MEG_)               // 16M f (64 MiB)
#define MOFF_UALL  ((size_t)40*MEG_)               // 8M f: 16M shorts (u bf16)
#define MOFF_YH    ((size_t)48*MEG_)               // 8M f: 16M shorts (y_hat)
#define MOFF_WCAT  ((size_t)56*MEG_)               // 2M f
#define MOFF_WOUTB ((size_t)58*MEG_)               // 512K f
#define MOFF_AGA   (MOFF_WOUTB + 524288)           // 1M f
#define MOFF_AGB   (MOFF_AGA + MEG_)
#define MOFF_PRE   (MOFF_AGB + MEG_)
#define MOFF_V0    (MOFF_PRE + MEG_)
#define MOFF_W1    (MOFF_V0 + 2048)
#define MOFF_W2    (MOFF_W1 + 2048)
#define MOFF_SCAL  (MOFF_W2 + 2048)
#define MREQ_FLOATS (MOFF_SCAL + 16)

typedef short s8v __attribute__((ext_vector_type(8)));   // 8 bf16 (4 VGPRs)
typedef float f4v __attribute__((ext_vector_type(4)));   // MFMA acc

typedef __attribute__((address_space(3))) unsigned int       lds_u32;
typedef const __attribute__((address_space(1))) unsigned int glb_u32;

__device__ __forceinline__ void gload_lds16(const void* g, void* l)
{
    __builtin_amdgcn_global_load_lds((glb_u32*)g, (lds_u32*)l, 16, 0, 0);
}

// fp32 -> bf16 round-to-nearest-even
__device__ __forceinline__ unsigned short f2bf(float f)
{
    unsigned u = __float_as_uint(f);
    u += 0x7FFFu + ((u >> 16) & 1u);
    return (unsigned short)(u >> 16);
}
__device__ __forceinline__ float bf2f(unsigned short h)
{
    return __uint_as_float((unsigned)h << 16);
}
// dtype-generic raw loads for scan kernels
__device__ __forceinline__ float ldr(const float* p, size_t i)          { return p[i]; }
__device__ __forceinline__ float ldr(const unsigned short* p, size_t i) { return bf2f(p[i]); }

__device__ __forceinline__ ushort4 f2bf4(float4 v)
{
    ushort4 o;
    o.x = f2bf(v.x); o.y = f2bf(v.y); o.z = f2bf(v.z); o.w = f2bf(v.w);
    return o;
}

// ---- BK=64 LDS swizzle (128 B rows, 8 granules of 16 B). Physical slot of
// logical granule g in row r = g ^ (r&7); gload dest is lane-linear so lane
// sources logical granule (lane&7)^(lane>>3). Bit-identical data (rule #21).
#define SWZ64_SRC_GRAN(lane)  (((lane) & 7) ^ ((lane) >> 3))
#define SWZ64_SLOT(kk,quad,lrow) ((((kk)*4 + (quad)) ^ ((lrow) & 7)) * 8)

// ---- BK=32 swizzle (64 B rows, 4 granules) — gram only.
#define SWZ_SRC_GRAN(lane)  (((lane) & 3) ^ (((lane) >> 3) & 3))
#define SWZ_SLOT(quad,lrow) ((quad) ^ (((lrow) >> 1) & 3))

// ---------------- fallback: zero a float buffer ----------------
__global__ void zero_out(float* __restrict__ y, int n)
{
    int i = blockIdx.x * 256 + threadIdx.x;
    if (i < n) y[i] = 0.f;
}

// ------- one-time weight conversion + split-bf16 planes + optional u ------
// Vectorized x4 (all region boundaries divide by 4). nU4 = u elems / 4.
__global__ void cvt_weights(const float* __restrict__ Win, const float* __restrict__ Wp,
                            const float* __restrict__ Wout,
                            unsigned short* __restrict__ Wcat,
                            unsigned short* __restrict__ Woutb,
                            unsigned short* __restrict__ hi,
                            unsigned short* __restrict__ lo,
                            const float* __restrict__ u,
                            unsigned short* __restrict__ uall, int nU4)
{
    const int i  = blockIdx.x * 256 + threadIdx.x;
    const int i4 = i * 4;
    if (i4 < 1048576) {
        float4 v = *(const float4*)(Win + i4);
        *(ushort4*)(Wcat + i4) = f2bf4(v);
    } else if (i4 < 4194304) {
        float4 v = *(const float4*)(Wp + (i4 - 1048576));
        *(ushort4*)(Wcat + i4) = f2bf4(v);
    } else if (i4 < 5242880) {
        float4 v = *(const float4*)(Wout + (i4 - 4194304));
        *(ushort4*)(Woutb + (i4 - 4194304)) = f2bf4(v);
    }
    if (i4 < 2097152) {
        const float* src = (i4 < MEG_) ? (Win + i4) : (Wout + (i4 - MEG_));
        float4 v = *(const float4*)src;
        ushort4 h = f2bf4(v);
        float4 res;
        res.x = v.x - bf2f(h.x); res.y = v.y - bf2f(h.y);
        res.z = v.z - bf2f(h.z); res.w = v.w - bf2f(h.w);
        *(ushort4*)(hi + i4) = h;
        *(ushort4*)(lo + i4) = f2bf4(res);
    }
    if (i < nU4) {
        float4 v = *(const float4*)(u + i4);
        *(ushort4*)(uall + i4) = f2bf4(v);
    }
}

// ---------------- per-stripe u conversion (small/big paths) ----------------
__global__ void cvt_u(const float* __restrict__ src, unsigned short* __restrict__ dst)
{
    int i = blockIdx.x * 256 + threadIdx.x;
    dst[i] = f2bf(src[i]);
}

// =====================================================================
// Split-bf16 MFMA gram: C[z] = W[z] W[z]^T  (hi.hi + hi.lo + lo.hi).
// 64x64 tile, BK=32, swizzled LDS.
// =====================================================================
__global__ __launch_bounds__(256, 4) void gram_bf16x2(
    const unsigned short* __restrict__ hi, const unsigned short* __restrict__ lo,
    float* __restrict__ C, unsigned short* __restrict__ Cb)
{
    __shared__ __align__(16) unsigned short Ah[64 * 32];
    __shared__ __align__(16) unsigned short Al[64 * 32];
    __shared__ __align__(16) unsigned short Bh[64 * 32];
    __shared__ __align__(16) unsigned short Bl[64 * 32];
    const int tid = threadIdx.x;
    const int z   = blockIdx.z;
    const int m0  = blockIdx.y * 64;
    const int n0  = blockIdx.x * 64;

    const unsigned short* hz = hi + (size_t)z * MEG_;
    const unsigned short* lz = lo + (size_t)z * MEG_;

    const int lane = tid & 63;
    const int w    = tid >> 6;
    const int wm   = (w >> 1) * 32;
    const int wn   = (w & 1) * 32;
    const int lrow = lane & 15;
    const int quad = lane >> 4;
    const int srow = lane >> 2;
    const int scol = SWZ_SRC_GRAN(lane) * 8;
    const int slot = SWZ_SLOT(quad, lrow) * 8;

    const size_t arow = (size_t)(m0 + w*16 + srow) * 1024 + scol;
    const size_t brow = (size_t)(n0 + w*16 + srow) * 1024 + scol;
    unsigned short* dA = &Ah[(w*16) * 32];
    unsigned short* eA = &Al[(w*16) * 32];
    unsigned short* dB = &Bh[(w*16) * 32];
    unsigned short* eB = &Bl[(w*16) * 32];

    f4v acc[2][2];
    #pragma unroll
    for (int i = 0; i < 2; ++i)
      #pragma unroll
      for (int j = 0; j < 2; ++j) acc[i][j] = (f4v){0.f, 0.f, 0.f, 0.f};

    for (int kt = 0; kt < 1024; kt += 32) {
        __syncthreads();
        gload_lds16(hz + arow + kt, dA);
        gload_lds16(lz + arow + kt, eA);
        gload_lds16(hz + brow + kt, dB);
        gload_lds16(lz + brow + kt, eB);
        __syncthreads();

        s8v ah[2], al[2], bh[2], bl[2];
        #pragma unroll
        for (int i = 0; i < 2; ++i) {
            ah[i] = *(const s8v*)&Ah[(wm + i*16 + lrow) * 32 + slot];
            al[i] = *(const s8v*)&Al[(wm + i*16 + lrow) * 32 + slot];
        }
        #pragma unroll
        for (int j = 0; j < 2; ++j) {
            bh[j] = *(const s8v*)&Bh[(wn + j*16 + lrow) * 32 + slot];
            bl[j] = *(const s8v*)&Bl[(wn + j*16 + lrow) * 32 + slot];
        }
        #pragma unroll
        for (int i = 0; i < 2; ++i)
          #pragma unroll
          for (int j = 0; j < 2; ++j) {
              acc[i][j] = __builtin_amdgcn_mfma_f32_16x16x32_bf16(ah[i], bh[j], acc[i][j], 0, 0, 0);
              acc[i][j] = __builtin_amdgcn_mfma_f32_16x16x32_bf16(ah[i], bl[j], acc[i][j], 0, 0, 0);
              acc[i][j] = __builtin_amdgcn_mfma_f32_16x16x32_bf16(al[i], bh[j], acc[i][j], 0, 0, 0);
          }
    }

    float*          Cz  = C  + (size_t)z * MEG_;
    unsigned short* Cbz = Cb + (size_t)z * MEG_;
    #pragma unroll
    for (int i = 0; i < 2; ++i)
      #pragma unroll
      for (int j = 0; j < 2; ++j) {
        const int col = n0 + wn + j * 16 + lrow;
        #pragma unroll
        for (int r = 0; r < 4; ++r) {
            const int row = m0 + wm + i * 16 + quad * 4 + r;
            float v = acc[i][j][r];
            Cz [(size_t)row * 1024 + col] = v;
            Cbz[(size_t)row * 1024 + col] = f2bf(v);
        }
    }
}

// =====================================================================
// bf16 MFMA NT GEMM, 64x64 tile, BK=64, z-batched. OBF: bf16 output.
// mode: 0 plain, 1 scale by sptr[0]. Swizzled LDS (BK64). K % 64 == 0.
// =====================================================================
template<bool OBF>
__global__ __launch_bounds__(256, 4) void gemm64_t(
    const unsigned short* __restrict__ A, const unsigned short* __restrict__ B,
    float* __restrict__ C, int K, int ldc,
    long zsA, long zsB, long zsC,
    const float* __restrict__ sptr, int mode)
{
    __shared__ __align__(16) unsigned short As[64 * 64];   // 8 KiB
    __shared__ __align__(16) unsigned short Bs[64 * 64];   // 8 KiB
    const int tid = threadIdx.x;
    const int z   = blockIdx.z;
    const int m0  = blockIdx.y * 64;
    const int n0  = blockIdx.x * 64;

    const unsigned short* Az = A + (size_t)z * zsA;
    const unsigned short* Bz = B + (size_t)z * zsB;

    const int lane = tid & 63;
    const int w    = tid >> 6;
    const int wm   = (w >> 1) * 32;
    const int wn   = (w & 1) * 32;
    const int lrow = lane & 15;
    const int quad = lane >> 4;
    const int srow8 = lane >> 3;
    const int scol  = SWZ64_SRC_GRAN(lane) * 8;

    const unsigned short* Agl = Az + (size_t)(m0 + w*16 + srow8) * K + scol;
    const unsigned short* Bgl = Bz + (size_t)(n0 + w*16 + srow8) * K + scol;
    unsigned short* lA = &As[(w*16) * 64];
    unsigned short* lB = &Bs[(w*16) * 64];

    f4v acc[2][2];
    #pragma unroll
    for (int i = 0; i < 2; ++i)
      #pragma unroll
      for (int j = 0; j < 2; ++j) acc[i][j] = (f4v){0.f, 0.f, 0.f, 0.f};

    for (int kt = 0; kt < K; kt += 64) {
        __syncthreads();
        gload_lds16(Agl + kt,                lA);
        gload_lds16(Agl + (size_t)8*K + kt,  lA + 8*64);
        gload_lds16(Bgl + kt,                lB);
        gload_lds16(Bgl + (size_t)8*K + kt,  lB + 8*64);
        __syncthreads();

        #pragma unroll
        for (int kk = 0; kk < 2; ++kk) {
            const int slot = SWZ64_SLOT(kk, quad, lrow);
            s8v af[2], bf[2];
            #pragma unroll
            for (int i = 0; i < 2; ++i)
                af[i] = *(const s8v*)&As[(wm + i*16 + lrow) * 64 + slot];
            #pragma unroll
            for (int j = 0; j < 2; ++j)
                bf[j] = *(const s8v*)&Bs[(wn + j*16 + lrow) * 64 + slot];
            #pragma unroll
            for (int i = 0; i < 2; ++i)
              #pragma unroll
              for (int j = 0; j < 2; ++j)
                  acc[i][j] = __builtin_amdgcn_mfma_f32_16x16x32_bf16(af[i], bf[j], acc[i][j], 0, 0, 0);
        }
    }

    float sc = (mode == 1) ? sptr[0] : 1.0f;
    float* Cp = C + (size_t)z * zsC;

    #pragma unroll
    for (int i = 0; i < 2; ++i)
      #pragma unroll
      for (int j = 0; j < 2; ++j) {
        const int col = n0 + wn + j * 16 + lrow;
        #pragma unroll
        for (int r = 0; r < 4; ++r) {
            const int row = m0 + wm + i * 16 + quad * 4 + r;
            if (OBF)
                ((unsigned short*)Cp)[(size_t)row * ldc + col] = f2bf(acc[i][j][r] * sc);
            else
                Cp[(size_t)row * ldc + col] = acc[i][j][r] * sc;
        }
    }
}

// =====================================================================
// Pure-bf16 MFMA NT GEMM, 128x128 tile, BK=64. Dual-output split at
// nsplit; OBF0/OBF1: write C0/C1 as bf16 (ldc in shorts then).
// mode: 0 plain, 1 scale both outputs by sptr[0].
// XCD-aware bijective block swizzle (T1, m204 formula). Swizzled LDS.
// =====================================================================
template<bool OBF0, bool OBF1>
__global__ __launch_bounds__(256, 2) void gemm_bf16(
    const unsigned short* __restrict__ A,
    const unsigned short* __restrict__ B0, const unsigned short* __restrict__ B1,
    float* __restrict__ C0, float* __restrict__ C1,
    int K, int ldc0, int ldc1, int nsplit,
    const float* __restrict__ sptr, int mode)
{
    __shared__ __align__(16) unsigned short As[128 * 64];  // 16 KiB
    __shared__ __align__(16) unsigned short Bs[128 * 64];  // 16 KiB
    const int tid = threadIdx.x;

    // T1: bijective XCD chunking of the flattened block id
    const int nwg  = gridDim.x * gridDim.y;
    const int flat = blockIdx.y * gridDim.x + blockIdx.x;
    const int q = nwg >> 3, r = nwg & 7;
    const int xcd = flat & 7;
    const int lin = flat >> 3;
    const int wg  = (xcd < r ? xcd * (q + 1) : r * (q + 1) + (xcd - r) * q) + lin;
    const int m0  = (wg / gridDim.x) * 128;
    const int n0g = (wg % gridDim.x) * 128;

    const unsigned short* Bsrc; float* Cp; int ldc; int c0; bool obf;
    if (n0g < nsplit) {
        Bsrc = B0 + (size_t)n0g * K;
        Cp = C0; ldc = ldc0; c0 = n0g; obf = OBF0;
    } else {
        Bsrc = B1 + (size_t)(n0g - nsplit) * K;
        Cp = C1; ldc = ldc1; c0 = n0g - nsplit; obf = OBF1;
    }

    const int lane = tid & 63;
    const int w    = tid >> 6;
    const int wm   = (w >> 1) * 64;
    const int wn   = (w & 1) * 64;
    const int lrow = lane & 15;
    const int quad = lane >> 4;
    const int srow8 = lane >> 3;
    const int scol  = SWZ64_SRC_GRAN(lane) * 8;

    const unsigned short* Agl = A    + (size_t)(m0 + w*32 + srow8) * K + scol;
    const unsigned short* Bgl = Bsrc + (size_t)(w*32 + srow8) * K + scol;
    unsigned short* lA = &As[(w*32) * 64];
    unsigned short* lB = &Bs[(w*32) * 64];

    f4v acc[4][4];
    #pragma unroll
    for (int i = 0; i < 4; ++i)
      #pragma unroll
      for (int j = 0; j < 4; ++j) acc[i][j] = (f4v){0.f, 0.f, 0.f, 0.f};

    for (int kt = 0; kt < K; kt += 64) {
        __syncthreads();
        #pragma unroll
        for (int q8 = 0; q8 < 4; ++q8) {
            gload_lds16(Agl + (size_t)(q8*8)*K + kt, lA + (q8*8)*64);
            gload_lds16(Bgl + (size_t)(q8*8)*K + kt, lB + (q8*8)*64);
        }
        __syncthreads();

        #pragma unroll
        for (int kk = 0; kk < 2; ++kk) {
            const int slot = SWZ64_SLOT(kk, quad, lrow);
            s8v af[4], bf[4];
            #pragma unroll
            for (int i = 0; i < 4; ++i)
                af[i] = *(const s8v*)&As[(wm + i*16 + lrow) * 64 + slot];
            #pragma unroll
            for (int j = 0; j < 4; ++j)
                bf[j] = *(const s8v*)&Bs[(wn + j*16 + lrow) * 64 + slot];
            #pragma unroll
            for (int i = 0; i < 4; ++i)
              #pragma unroll
              for (int j = 0; j < 4; ++j)
                  acc[i][j] = __builtin_amdgcn_mfma_f32_16x16x32_bf16(af[i], bf[j], acc[i][j], 0, 0, 0);
        }
    }

    const float sc = (mode == 1) ? sptr[0] : 1.0f;

    #pragma unroll
    for (int i = 0; i < 4; ++i)
      #pragma unroll
      for (int j = 0; j < 4; ++j) {
        const int col = c0 + wn + j * 16 + lrow;
        #pragma unroll
        for (int r2 = 0; r2 < 4; ++r2) {
            const int row = m0 + wm + i * 16 + quad * 4 + r2;
            if ((OBF0 || OBF1) && obf)
                ((unsigned short*)Cp)[(size_t)row * ldc + col] = f2bf(acc[i][j][r2] * sc);
            else
                Cp[(size_t)row * ldc + col] = acc[i][j][r2] * sc;
        }
    }
}

// ---- pick column with max diagonal (dominant-eigvec seed), z=blockIdx.x ----
__global__ void pick_col(const unsigned short* __restrict__ Pall, float* __restrict__ vall)
{
    const unsigned short* P = Pall + (size_t)blockIdx.x * MEG_;
    float* v = vall + blockIdx.x * N_;
    __shared__ float sval[256];
    __shared__ int   sidx[256];
    __shared__ int   jstar;
    const int tid = threadIdx.x;
    float best = -1.f; int bidx = 0;
    for (int i = tid; i < N_; i += 256) {
        float d = bf2f(P[(size_t)i * (N_ + 1)]);
        if (d > best) { best = d; bidx = i; }
    }
    sval[tid] = best; sidx[tid] = bidx; __syncthreads();
    for (int off = 128; off > 0; off >>= 1) {
        if (tid < off && sval[tid + off] > sval[tid]) {
            sval[tid] = sval[tid + off]; sidx[tid] = sidx[tid + off];
        }
        __syncthreads();
    }
    if (tid == 0) jstar = sidx[0];
    __syncthreads();
    const int j = jstar;
    for (int i = tid; i < N_; i += 256) v[i] = bf2f(P[(size_t)j * N_ + i]);
}

// ---------------- w = G[z] * v[z] (one wave per row), z=blockIdx.y ----------
__global__ __launch_bounds__(256) void matvec_z(
    const float* __restrict__ Gall, const float* __restrict__ vall,
    float* __restrict__ wall)
{
    const int z = blockIdx.y;
    const float* G = Gall + (size_t)z * MEG_;
    const float* v = vall + z * N_;
    const int row  = blockIdx.x * 4 + (threadIdx.x >> 6);
    const int lane = threadIdx.x & 63;
    const float* g = G + (size_t)row * N_;
    float s = 0.f;
    for (int j = lane; j < N_; j += 64) s += g[j] * v[j];
    #pragma unroll
    for (int off = 32; off > 0; off >>= 1) s += __shfl_down(s, off, 64);
    if (lane == 0) wall[z * N_ + row] = s;
}

// ------- Rayleigh quotient -> inv_scale[z] = 1/max(sigma,1), z=blockIdx.x ----
__global__ void rq_scale(const float* __restrict__ w1a, const float* __restrict__ w2a,
                         float* __restrict__ slot)
{
    const int z = blockIdx.x;
    const float* w1 = w1a + z * N_;
    const float* w2 = w2a + z * N_;
    __shared__ float r11[256];
    __shared__ float r12[256];
    const int tid = threadIdx.x;
    float d11 = 0.f, d12 = 0.f;
    for (int i = tid; i < N_; i += 256) {
        float a = w1[i], b = w2[i];
        d11 = fmaf(a, a, d11);
        d12 = fmaf(a, b, d12);
    }
    r11[tid] = d11; r12[tid] = d12; __syncthreads();
    for (int off = 128; off > 0; off >>= 1) {
        if (tid < off) { r11[tid] += r11[tid + off]; r12[tid] += r12[tid + off]; }
        __syncthreads();
    }
    if (tid == 0) {
        float lam = r12[0] / fmaxf(r11[0], 1e-30f);
        float sig = sqrtf(fmaxf(lam, 0.f));
        slot[z] = 1.0f / fmaxf(sig, 1.0f);
    }
}

// ---------------- fast elementwise math (hw v_exp/v_log) ----------------
__device__ __forceinline__ float fast_sp(float x)
{
    return fmaxf(x, 0.f) + __logf(1.0f + __expf(-fabsf(x)));
}
__device__ __forceinline__ float fast_tanh(float x)
{
    float e = __expf(2.0f * fabsf(x));
    float t = 1.0f - 2.0f / (e + 1.0f);
    return copysignf(t, x);
}

__device__ __forceinline__ void abc_math(
    float dr, float br, float cr, float uval,
    float alpha, float db, float sgain,
    float* pa, float* pbu, float* pc)
{
    float delta = fast_sp(dr + db);
    float a = fminf(__expf(-delta * alpha), 1.0f - 1e-4f);
    float b = fast_tanh(br);
    float c = fast_tanh(cr);
    float p = fmaf(a, a, c * c);
    float r = b * b;
    float q = a * b;
    float pr = p - r;
    float disc = fmaf(pr, pr, 4.0f * q * q);
    float lam = 0.5f * (p + r + sqrtf(disc + 1e-12f));
    float sig = sqrtf(lam + 1e-12f);
    float inv = 1.0f / fmaxf(sig, 1.0f);
    a *= inv; b *= inv; c *= inv;
    *pa = a; *pc = c; *pbu = b * (sgain * uval);
}

// --------- scan phase 1: per-chunk composite (CL=16). TR = raw dtype. ---
template<class TR>
__global__ __launch_bounds__(256) void scan_phase1(
    const TR* __restrict__ rawS, const float* __restrict__ usS,
    const float* __restrict__ bp, const float* __restrict__ dbias,
    const float* __restrict__ alog, const float* __restrict__ lgam,
    const float* __restrict__ inv_sin,
    float* __restrict__ agg_a, float* __restrict__ agg_b)
{
    const int gid = blockIdx.x * 256 + threadIdx.x;
    const int n   = gid & (N_ - 1);
    const int cl  = gid >> 10;

    const float alpha = fast_sp(alog[n]);
    const float db    = dbias[n];
    const float bpd   = bp[n];
    const float bpb   = bp[N_ + n];
    const float bpc   = bp[2*N_ + n];
    const float sgain = __expf(lgam[0]) * inv_sin[0];

    float Ap = 1.f, Bc = 0.f;
    size_t base  = (size_t)(cl * CL_) * K3_ + n;
    size_t ubase = (size_t)(cl * CL_) * N_  + n;
    #pragma unroll 4
    for (int j = 0; j < CL_; ++j) {
        float dr = ldr(rawS, base)        + bpd;
        float br = ldr(rawS, base + N_)   + bpb;
        float cr = ldr(rawS, base + 2*N_) + bpc;
        float uv = usS[ubase];
        float a, bu, cv;
        abc_math(dr, br, cr, uv, alpha, db, sgain, &a, &bu, &cv);
        Bc = fmaf(a, Bc, bu);
        Ap *= a;
        base += K3_; ubase += N_;
    }
    agg_a[(size_t)cl * N_ + n] = Ap;
    agg_b[(size_t)cl * N_ + n] = Bc;
}

// --------- scan phase 2 (small path): chunk-prefix with inter-stripe carry --
__global__ void scan_phase2s(const float* __restrict__ agg_a,
                             const float* __restrict__ agg_b,
                             float* __restrict__ pref, float* __restrict__ carry,
                             int bidx, int use_carry)
{
    const int n = blockIdx.x * 256 + threadIdx.x;
    float z = use_carry ? carry[bidx * N_ + n] : 0.f;
    size_t idx = n;
    for (int c = 0; c < CPS_; ++c) {
        pref[idx] = z;
        z = fmaf(agg_a[idx], z, agg_b[idx]);
        idx += N_;
    }
    carry[bidx * N_ + n] = z;
}

// --------- scan phase 2 (chains): independent per-batch chains, z0 = 0 ---
__global__ void scan_phase2b(const float* __restrict__ agg_a,
                             const float* __restrict__ agg_b,
                             float* __restrict__ pref, int cpb)
{
    const int n = blockIdx.x * 256 + threadIdx.x;
    const int chain = blockIdx.y;
    size_t idx = (size_t)chain * cpb * N_ + n;
    float z = 0.f;
    for (int c = 0; c < cpb; ++c) {
        pref[idx] = z;
        z = fmaf(agg_a[idx], z, agg_b[idx]);
        idx += N_;
    }
}

// --------- scan phase 3: replay with chunk prefix, write y_hat bf16 ---------
template<class TR>
__global__ __launch_bounds__(256) void scan_phase3(
    const TR* __restrict__ rawS, const float* __restrict__ usS,
    const float* __restrict__ bp, const float* __restrict__ dbias,
    const float* __restrict__ alog, const float* __restrict__ lgam,
    const float* __restrict__ inv_sin, const float* __restrict__ pref,
    unsigned short* __restrict__ yh)
{
    const int gid = blockIdx.x * 256 + threadIdx.x;
    const int n   = gid & (N_ - 1);
    const int cl  = gid >> 10;

    const float alpha = fast_sp(alog[n]);
    const float db    = dbias[n];
    const float bpd   = bp[n];
    const float bpb   = bp[N_ + n];
    const float bpc   = bp[2*N_ + n];
    const float sgain = __expf(lgam[0]) * inv_sin[0];

    float z = pref[(size_t)cl * N_ + n];
    size_t base  = (size_t)(cl * CL_) * K3_ + n;
    size_t ubase = (size_t)(cl * CL_) * N_  + n;
    #pragma unroll 4
    for (int j = 0; j < CL_; ++j) {
        float dr = ldr(rawS, base)        + bpd;
        float br = ldr(rawS, base + N_)   + bpb;
        float cr = ldr(rawS, base + 2*N_) + bpc;
        float uv = usS[ubase];
        float a, bu, cv;
        abc_math(dr, br, cr, uv, alpha, db, sgain, &a, &bu, &cv);
        yh[ubase] = f2bf(cv * z);
        z = fmaf(a, z, bu);
        base += K3_; ubase += N_;
    }
}

// =====================================================================
extern "C" void kernel_launch(void* const* d_in, const int* in_sizes, int n_in,
                              void* d_out, int out_size, void* d_ws, size_t ws_size,
                              hipStream_t stream)
{
    (void)in_sizes; (void)n_in;
    const float* u     = (const float*)d_in[0];
    const float* W_in  = (const float*)d_in[1];
    const float* W_out = (const float*)d_in[2];
    const float* Wp    = (const float*)d_in[3];
    const float* bp    = (const float*)d_in[4];
    const float* alog  = (const float*)d_in[5];
    const float* dbias = (const float*)d_in[6];
    const float* lgam  = (const float*)d_in[7];
    float* y = (float*)d_out;

    if (ws_size < (size_t)REQ_FLOATS * sizeof(float)) {
        zero_out<<<(out_size + 255) / 256, dim3(256), 0, stream>>>(y, out_size);
        return;
    }
    const bool mega = ws_size >= (size_t)MREQ_FLOATS * sizeof(float);
    const bool big  = !mega && ws_size >= (size_t)BREQ_FLOATS * sizeof(float);

    float* ws = (float*)d_ws;
    const dim3 blk(256);
    const int BIG = 1 << 30;

    // path-dependent layout
    size_t oRAW, oUSS, oWCAT, oWOUTB, oAGA, oAGB, oPRE, oV0, oW1, oW2, oSCAL;
    if (mega) {
        oRAW = MOFF_RAWB; oUSS = MOFF_USS; oWCAT = MOFF_WCAT; oWOUTB = MOFF_WOUTB;
        oAGA = MOFF_AGA; oAGB = MOFF_AGB; oPRE = MOFF_PRE;
        oV0 = MOFF_V0; oW1 = MOFF_W1; oW2 = MOFF_W2; oSCAL = MOFF_SCAL;
    } else if (big) {
        oRAW = BOFF_RAWS; oUSS = BOFF_USS; oWCAT = BOFF_WCAT; oWOUTB = BOFF_WOUTB;
        oAGA = BOFF_AGA; oAGB = BOFF_AGB; oPRE = BOFF_PRE;
        oV0 = BOFF_V0; oW1 = BOFF_W1; oW2 = BOFF_W2; oSCAL = BOFF_SCAL;
    } else {
        oRAW = OFF_RAWS; oUSS = OFF_USS; oWCAT = OFF_WCAT; oWOUTB = OFF_WOUTB;
        oAGA = OFF_AGA; oAGB = OFF_AGB; oPRE = OFF_PRE;
        oV0 = OFF_V0; oW1 = OFF_W1; oW2 = OFF_W2; oSCAL = OFF_SCAL;
    }

    float*          usS   = ws + oUSS;
    unsigned short* Wcat  = (unsigned short*)(ws + oWCAT);
    unsigned short* Woutb = (unsigned short*)(ws + oWOUTB);
    float* agg_a = ws + oAGA;
    float* agg_b = ws + oAGB;
    float* pref  = ws + oPRE;
    float* carry = ws + OFF_CARRY;                       // small path only
    float* v0    = ws + oV0;
    float* w1    = ws + oW1;
    float* w2    = ws + oW2;
    float* scal  = ws + oSCAL;
    // sigma-phase aliases over the raw region (live only before stripes)
    float*          G0   = ws + oRAW;
    unsigned short* hiW  = (unsigned short*)(ws + oRAW + 2*MEG_);
    unsigned short* loW  = (unsigned short*)(ws + oRAW + 3*MEG_);
    unsigned short* SbfA = (unsigned short*)usS;
    unsigned short* SbfB = SbfA + 2*MEG_;
    // mega-only buffers
    unsigned short* uall = (unsigned short*)(ws + MOFF_UALL);
    unsigned short* yhM  = (unsigned short*)(ws + MOFF_YH);
    unsigned short* rawB = (unsigned short*)(ws + MOFF_RAWB);

    if (mega)
        cvt_weights<<<16384, blk, 0, stream>>>(W_in, Wp, W_out, Wcat, Woutb,
                                               hiW, loW, u, uall, 4194304);
    else
        cvt_weights<<<5120, blk, 0, stream>>>(W_in, Wp, W_out, Wcat, Woutb,
                                              hiW, loW, nullptr, nullptr, 0);

    // ---- spectral norms: split-bf16 MFMA gram (z=2), 6 bf16 squarings,
    //      fp32 Rayleigh quotient on the MFMA-accurate G0. ----
    gram_bf16x2<<<dim3(16, 16, 2), blk, 0, stream>>>(hiW, loW, G0, SbfA);
    unsigned short* Sc = SbfA;
    unsigned short* Sn = SbfB;
    for (int r = 0; r < 6; ++r) {
        gemm64_t<true><<<dim3(16, 16, 2), blk, 0, stream>>>(
            Sc, Sc, (float*)Sn, 1024, 1024, MEG_, MEG_, MEG_ / 2, nullptr, 0);
        unsigned short* t = Sc; Sc = Sn; Sn = t;
    }
    pick_col<<<2, blk, 0, stream>>>(Sc, v0);
    matvec_z<<<dim3(256, 2), blk, 0, stream>>>(G0, v0, w1);
    matvec_z<<<dim3(256, 2), blk, 0, stream>>>(G0, w1, w2);
    rq_scale<<<2, blk, 0, stream>>>(w1, w2, scal);   // scal[0]=inv_in, scal[1]=inv_out

    if (mega) {
        // ---- whole problem at once: 4 independent batch chains, no carry.
        // rawS stored bf16 (96 MiB); usS fp32. ----
        gemm_bf16<false, true><<<dim3(32, 128), blk, 0, stream>>>(
            uall, Wcat, Wcat + (size_t)1024 * 1024, usS, (float*)rawB,
            1024, N_, K3_, 1024, nullptr, 0);
        scan_phase1<<<4096, blk, 0, stream>>>(rawB, usS, bp, dbias, alog,
                                              lgam, scal, agg_a, agg_b);
        scan_phase2b<<<dim3(4, B_), blk, 0, stream>>>(agg_a, agg_b, pref, MCPB_);
        scan_phase3<<<4096, blk, 0, stream>>>(rawB, usS, bp, dbias, alog,
                                              lgam, scal, pref, yhM);
        gemm_bf16<false, false><<<dim3(8, 128), blk, 0, stream>>>(
            yhM, Woutb, nullptr, y, nullptr,
            1024, 1024, 0, BIG, scal + 1, 1);
    } else if (big) {
        float*          rawS = ws + oRAW;
        unsigned short* ubf  = (unsigned short*)(ws + BOFF_UBF);
        for (int s = 0; s < BNSTRIPE_; ++s) {
            const int r0 = s * BSROWS_;
            cvt_u<<<32768, blk, 0, stream>>>(u + (size_t)r0 * DD_, ubf);
            gemm_bf16<false, false><<<dim3(32, 64), blk, 0, stream>>>(
                ubf, Wcat, Wcat + (size_t)1024 * 1024, usS, rawS,
                1024, N_, K3_, 1024, nullptr, 0);
            scan_phase1<<<2048, blk, 0, stream>>>(rawS, usS, bp, dbias, alog,
                                                  lgam, scal, agg_a, agg_b);
            scan_phase2b<<<dim3(4, 2), blk, 0, stream>>>(agg_a, agg_b, pref, BCPB_);
            scan_phase3<<<2048, blk, 0, stream>>>(rawS, usS, bp, dbias, alog,
                                                  lgam, scal, pref, ubf);
            gemm64_t<false><<<dim3(16, 128, 1), blk, 0, stream>>>(
                ubf, Woutb, y + (size_t)r0 * N_, 1024, 1024,
                0, 0, 0, scal + 1, 1);
        }
    } else {
        float*          rawS = ws + oRAW;
        unsigned short* ubf  = (unsigned short*)(ws + OFF_UBF);
        for (int s = 0; s < NSTRIPE_; ++s) {
            const int r0 = s * SROWS_;
            cvt_u<<<8192, blk, 0, stream>>>(u + (size_t)r0 * DD_, ubf);
            gemm_bf16<false, false><<<dim3(32, 16), blk, 0, stream>>>(
                ubf, Wcat, Wcat + (size_t)1024 * 1024, usS, rawS,
                1024, N_, K3_, 1024, nullptr, 0);
            scan_phase1<<<512, blk, 0, stream>>>(rawS, usS, bp, dbias, alog,
                                                 lgam, scal, agg_a, agg_b);
            scan_phase2s<<<4, blk, 0, stream>>>(agg_a, agg_b, pref, carry,
                                                s >> 1, s & 1);
            scan_phase3<<<512, blk, 0, stream>>>(rawS, usS, bp, dbias, alog,
                                                 lgam, scal, pref, ubf);
            gemm64_t<false><<<dim3(16, 32, 1), blk, 0, stream>>>(
                ubf, Woutb, y + (size_t)r0 * N_, 1024, 1024,
                0, 0, 0, scal + 1, 1);
        }
    }
}